// Round 7
// baseline (434.610 us; speedup 1.0000x reference)
//
#include <hip/hip_runtime.h>
#include <hip/hip_bf16.h>
#include <hip/hip_fp16.h>
#include <hip/hip_fp8.h>
#include <cstdint>
#include <cstddef>

#define INDIM 256
#define NEG 0.2f

typedef __attribute__((ext_vector_type(8))) short short8v;
typedef __attribute__((ext_vector_type(4))) float f32x4;

__device__ __forceinline__ unsigned short f2bf(float x) {
  __hip_bfloat16 b = __float2bfloat16(x);
  return __builtin_bit_cast(unsigned short, b);
}

__device__ __forceinline__ unsigned char f2fp8(float v) {
  return (unsigned char)__hip_cvt_float_to_fp8(v, __HIP_SATFINITE, __HIP_E4M3);
}

__device__ __forceinline__ float2 fp8x2f(unsigned short u) {
  __half2_raw hr = __hip_cvt_fp8x2_to_halfraw2((__hip_fp8x2_storage_t)u, __HIP_E4M3);
  __half2 h = *reinterpret_cast<__half2*>(&hr);
  return __half22float2(h);
}

__device__ __forceinline__ float lrelu(float v) { return v > 0.f ? v : NEG * v; }

// ---------------- W pre-transpose to bf16: Wt[c][k] = bf16(W[k][c]) ----------------
__global__ void wprep_kernel(const float* __restrict__ W, __hip_bfloat16* __restrict__ Wt,
                             int K, int NC, int total) {
  int idx = blockIdx.x * blockDim.x + threadIdx.x;
  if (idx >= total) return;
  int k = idx / NC, c = idx - k * NC;
  Wt[(size_t)c * K + k] = __float2bfloat16(W[idx]);
}

// ---------------- MFMA GEMM over 2N batched rows: rows < Nsplit from A0, else A1 ----------
// tile 64x128, 4 waves (2x2), wave tile 32x64 = 2x4 fragments of 16x16, BK=32
// writes f32 Y + fp8(e4m3) Yc
template<int K, bool ABF16>
__global__ __launch_bounds__(256) void mfma_gemm(const void* __restrict__ A0,
                                                 const void* __restrict__ A1, int Nsplit,
                                                 const __hip_bfloat16* __restrict__ Wt,
                                                 float* __restrict__ Y,
                                                 unsigned char* __restrict__ Yc,
                                                 int M, int NC) {
  __shared__ short As[64][40];
  __shared__ short Bs[128][40];
  const int tid = threadIdx.x;
  const int row0 = blockIdx.x * 64;
  const int col0 = blockIdx.y * 128;
  const int l = tid & 63, w = tid >> 6;
  const int wr = w >> 1, wc = w & 1;
  const int lr = l & 15, lk = (l >> 4) * 8;

  f32x4 acc[2][4];
#pragma unroll
  for (int m = 0; m < 2; ++m)
#pragma unroll
    for (int n = 0; n < 4; ++n) acc[m][n] = {0.f, 0.f, 0.f, 0.f};

  for (int k0 = 0; k0 < K; k0 += 32) {
    __syncthreads();
    {  // stage A: 64 rows x 32 k
      int r = tid >> 2, kq = (tid & 3) * 8;
      int gr = row0 + r;
      short8v av = {0, 0, 0, 0, 0, 0, 0, 0};
      if (gr < M) {
        const void* Ab = (gr < Nsplit) ? A0 : A1;
        int lrow = (gr < Nsplit) ? gr : gr - Nsplit;
        if (ABF16) {
          av = *(const short8v*)((const short*)Ab + (size_t)lrow * K + k0 + kq);
        } else {
          const float* ap = (const float*)Ab + (size_t)lrow * K + k0 + kq;
          float4 u = *(const float4*)ap;
          float4 v = *(const float4*)(ap + 4);
          av = short8v{(short)f2bf(u.x), (short)f2bf(u.y), (short)f2bf(u.z), (short)f2bf(u.w),
                       (short)f2bf(v.x), (short)f2bf(v.y), (short)f2bf(v.z), (short)f2bf(v.w)};
        }
      }
      *(short8v*)&As[r][kq] = av;
    }
    {  // stage B: 128 cols x 32 k (Wt row-major [NC][K])
      int c = tid >> 1, kq = (tid & 1) * 8;
      const short* wp = (const short*)Wt + (size_t)(col0 + c) * K + k0 + kq;
      *(short8v*)&Bs[c][kq]      = *(const short8v*)wp;
      *(short8v*)&Bs[c][kq + 16] = *(const short8v*)(wp + 16);
    }
    __syncthreads();
    short8v a[2], b[4];
#pragma unroll
    for (int m = 0; m < 2; ++m) a[m] = *(short8v*)&As[wr * 32 + m * 16 + lr][lk];
#pragma unroll
    for (int n = 0; n < 4; ++n) b[n] = *(short8v*)&Bs[wc * 64 + n * 16 + lr][lk];
#pragma unroll
    for (int m = 0; m < 2; ++m)
#pragma unroll
      for (int n = 0; n < 4; ++n)
        acc[m][n] = __builtin_amdgcn_mfma_f32_16x16x32_bf16(a[m], b[n], acc[m][n], 0, 0, 0);
  }
  // epilogue: C/D layout col=lane&15, row=(lane>>4)*4+q
#pragma unroll
  for (int m = 0; m < 2; ++m) {
    int rbase = row0 + wr * 32 + m * 16 + (l >> 4) * 4;
#pragma unroll
    for (int n = 0; n < 4; ++n) {
      int col = col0 + wc * 64 + n * 16 + lr;
#pragma unroll
      for (int q = 0; q < 4; ++q) {
        int row = rbase + q;
        if (row < M) {
          float v = acc[m][n][q];
          Y[(size_t)row * NC + col] = v;
          Yc[(size_t)row * NC + col] = f2fp8(v);
        }
      }
    }
  }
}

// ---------------- attention dots: one wave per (node2,head); node2 in [0,2N) ----------------
__global__ __launch_bounds__(256) void sd_kernel(const float* __restrict__ H,
                                                 const float* __restrict__ As,
                                                 const float* __restrict__ Ad,
                                                 float* __restrict__ S, float* __restrict__ D,
                                                 int NB, int NH) {
  int w = blockIdx.x * 4 + (threadIdx.x >> 6);
  if (w >= NB) return;
  int lane = threadIdx.x & 63;
  int h = w % NH;
  float2 hv = reinterpret_cast<const float2*>(H + (size_t)w * 128)[lane];
  float2 as = reinterpret_cast<const float2*>(As + h * 128)[lane];
  float2 ad = reinterpret_cast<const float2*>(Ad + h * 128)[lane];
  float vs = hv.x * as.x + hv.y * as.y;
  float vd = hv.x * ad.x + hv.y * ad.y;
#pragma unroll
  for (int o = 32; o; o >>= 1) { vs += __shfl_down(vs, o); vd += __shfl_down(vd, o); }
  if (lane == 0) { S[w] = vs; D[w] = vd; }
}

// ---------------- CSR build over 2N virtual nodes (both branches) ----------------
__global__ void deg_kernel(const int* __restrict__ ed1, const int* __restrict__ ed2,
                           int E, int Etot, int N, int* __restrict__ deg) {
  int idx = blockIdx.x * blockDim.x + threadIdx.x;
  if (idx >= 2 * Etot) return;
  int br = idx >= Etot;
  int el = idx - br * Etot;
  const int* ed = br ? ed2 : ed1;
  int dn = ((el < E) ? ed[el] : (el - E)) + br * N;
  atomicAdd(&deg[dn], 1);
}

__global__ __launch_bounds__(1024) void scan_kernel(const int* __restrict__ deg,
                                                    int* __restrict__ rowptr,
                                                    int* __restrict__ cursor, int n) {
  __shared__ int wsum[16];
  __shared__ int carry_s;
  int tid = threadIdx.x;
  int lane = tid & 63, wid = tid >> 6;
  if (tid == 0) { carry_s = 0; rowptr[0] = 0; }
  __syncthreads();
  for (int base = 0; base < n; base += 1024) {
    int i = base + tid;
    int v = (i < n) ? deg[i] : 0;
    int x = v;
#pragma unroll
    for (int o = 1; o < 64; o <<= 1) {
      int t = __shfl_up(x, o);
      if (lane >= o) x += t;
    }
    if (lane == 63) wsum[wid] = x;
    __syncthreads();
    if (wid == 0) {
      int wv = (lane < 16) ? wsum[lane] : 0;
#pragma unroll
      for (int o = 1; o < 16; o <<= 1) {
        int t = __shfl_up(wv, o);
        if (lane >= o) wv += t;
      }
      if (lane < 16) wsum[lane] = wv;
    }
    __syncthreads();
    int incl = carry_s + (wid ? wsum[wid - 1] : 0) + x;
    if (i < n) { rowptr[i + 1] = incl; cursor[i] = incl - v; }
    __syncthreads();
    if (tid == 1023) carry_s = incl;
    __syncthreads();
  }
}

__global__ void fill_kernel(const int* __restrict__ es1, const int* __restrict__ ed1,
                            const int* __restrict__ es2, const int* __restrict__ ed2,
                            int E, int Etot, int N, int* __restrict__ cursor,
                            int* __restrict__ csr_src) {
  int idx = blockIdx.x * blockDim.x + threadIdx.x;
  if (idx >= 2 * Etot) return;
  int br = idx >= Etot;
  int el = idx - br * Etot;
  const int* es = br ? es2 : es1;
  const int* ed = br ? ed2 : ed1;
  int sn, dn;
  if (el < E) { sn = es[el]; dn = ed[el]; } else { sn = dn = el - E; }
  sn += br * N; dn += br * N;
  int pos = atomicAdd(&cursor[dn], 1);
  csr_src[pos] = sn;
}

// ---------------- agg1: SINGLE-PASS unnormalized aggregate + inline denom, fp8 gathers ----
// 192 threads, 1 virtual node per block, thread j -> cols 2j,2j+1 (ushort = fp8x2 load)
__global__ __launch_bounds__(192) void agg1_kernel(const unsigned char* __restrict__ h1c,
                                                   const float* __restrict__ S,
                                                   const float* __restrict__ D,
                                                   const int* __restrict__ rowptr,
                                                   const int* __restrict__ csr_src,
                                                   const float* __restrict__ b1,
                                                   __hip_bfloat16* __restrict__ e1b,
                                                   float* __restrict__ invden) {
  __shared__ int lsrc[192];
  __shared__ float la[3][192];
  __shared__ float red[3][3];
  __shared__ float inv_s[3];
  const unsigned short* H2 = reinterpret_cast<const unsigned short*>(h1c);
  int n = blockIdx.x;
  int j = threadIdx.x;           // 0..191 -> cols 2j, 2j+1
  int wid = j >> 6, lane = j & 63;
  int p0 = rowptr[n], p1 = rowptr[n + 1];
  float d0 = D[n * 3], d1 = D[n * 3 + 1], d2 = D[n * 3 + 2];

  float dp0 = 0.f, dp1 = 0.f, dp2 = 0.f;
  float acc0 = 0.f, acc1 = 0.f;
  for (int base = p0; base < p1; base += 192) {
    int cnt = min(192, p1 - base);
    __syncthreads();
    if (j < cnt) {
      int sn = csr_src[base + j];
      lsrc[j] = sn;
      float e0 = __expf(lrelu(S[sn * 3] + d0));
      float e1 = __expf(lrelu(S[sn * 3 + 1] + d1));
      float e2 = __expf(lrelu(S[sn * 3 + 2] + d2));
      la[0][j] = e0; la[1][j] = e1; la[2][j] = e2;
      dp0 += e0; dp1 += e1; dp2 += e2;
    }
    __syncthreads();
    int i = 0;
    for (; i + 8 <= cnt; i += 8) {
      float av[8];
      unsigned short hv[8];
#pragma unroll
      for (int u = 0; u < 8; ++u) {
        int sn = lsrc[i + u];
        av[u] = la[wid][i + u];
        hv[u] = H2[(size_t)sn * 192 + j];
      }
#pragma unroll
      for (int u = 0; u < 8; ++u) {
        float2 f = fp8x2f(hv[u]);
        acc0 = fmaf(av[u], f.x, acc0);
        acc1 = fmaf(av[u], f.y, acc1);
      }
    }
    for (; i < cnt; ++i) {
      int sn = lsrc[i];
      float a = la[wid][i];
      float2 f = fp8x2f(H2[(size_t)sn * 192 + j]);
      acc0 = fmaf(a, f.x, acc0);
      acc1 = fmaf(a, f.y, acc1);
    }
  }
  // block-reduce the exp partials
#pragma unroll
  for (int o = 32; o; o >>= 1) {
    dp0 += __shfl_down(dp0, o); dp1 += __shfl_down(dp1, o); dp2 += __shfl_down(dp2, o);
  }
  if (lane == 0) { red[wid][0] = dp0; red[wid][1] = dp1; red[wid][2] = dp2; }
  __syncthreads();
  if (j == 0) {
    inv_s[0] = 1.f / (red[0][0] + red[1][0] + red[2][0]);
    inv_s[1] = 1.f / (red[0][1] + red[1][1] + red[2][1]);
    inv_s[2] = 1.f / (red[0][2] + red[1][2] + red[2][2]);
  }
  __syncthreads();
  float inv = inv_s[wid];
  int c0 = 2 * j;
  float v0 = acc0 * inv + b1[c0];
  float v1 = acc1 * inv + b1[c0 + 1];
  __hip_bfloat162 ov;
  ov.x = __float2bfloat16(v0 > 0.f ? v0 : 0.f);
  ov.y = __float2bfloat16(v1 > 0.f ? v1 : 0.f);
  reinterpret_cast<__hip_bfloat162*>(e1b)[(size_t)n * 192 + j] = ov;
  if (j < 3) invden[n * 3 + j] = inv_s[j];
}

// ---------------- alpha: edge-major, coalesced writes into d_out ----------------
__global__ void alpha_kernel(const float* __restrict__ S, const float* __restrict__ D,
                             const float* __restrict__ invden,
                             const int* __restrict__ es1, const int* __restrict__ ed1,
                             const int* __restrict__ es2, const int* __restrict__ ed2,
                             int E, int Etot, int N, float* __restrict__ out) {
  int idx = blockIdx.x * blockDim.x + threadIdx.x;
  if (idx >= 2 * Etot) return;
  int br = idx >= Etot;
  int el = idx - br * Etot;
  const int* es = br ? es2 : es1;
  const int* ed = br ? ed2 : ed1;
  int sn, dn;
  if (el < E) { sn = es[el]; dn = ed[el]; } else { sn = dn = el - E; }
  sn += br * N; dn += br * N;
  float* ao = out + 1 + (size_t)br * Etot * 3 + (size_t)el * 3;
#pragma unroll
  for (int h = 0; h < 3; ++h) {
    float v = lrelu(S[sn * 3 + h] + D[dn * 3 + h]);
    ao[h] = __expf(v) * invden[dn * 3 + h];
  }
}

// ---------------- agg2: SINGLE-PASS, 64 threads per virtual node, fp8 gathers ------------
__global__ __launch_bounds__(64) void agg2_kernel(const unsigned char* __restrict__ h2c,
                                                  const float* __restrict__ S,
                                                  const float* __restrict__ D,
                                                  const int* __restrict__ rowptr,
                                                  const int* __restrict__ csr_src,
                                                  const float* __restrict__ b2,
                                                  float* __restrict__ e2out) {
  __shared__ int lsrc[256];
  __shared__ float la[256];
  const unsigned short* H2 = reinterpret_cast<const unsigned short*>(h2c);
  int n = blockIdx.x;
  int c = threadIdx.x;           // 0..63 -> cols 2c, 2c+1
  int p0 = rowptr[n], p1 = rowptr[n + 1];
  float dn_v = D[n];

  float dpart = 0.f;
  float acc0 = 0.f, acc1 = 0.f;
  for (int base = p0; base < p1; base += 256) {
    int cnt = min(256, p1 - base);
    __syncthreads();
    for (int i = c; i < cnt; i += 64) {
      int sn = csr_src[base + i];
      lsrc[i] = sn;
      float ex = __expf(lrelu(S[sn] + dn_v));
      la[i] = ex;
      dpart += ex;
    }
    __syncthreads();
    int i = 0;
    for (; i + 8 <= cnt; i += 8) {
      float av[8];
      unsigned short hv[8];
#pragma unroll
      for (int u = 0; u < 8; ++u) {
        int sn = lsrc[i + u];
        av[u] = la[i + u];
        hv[u] = H2[(size_t)sn * 64 + c];
      }
#pragma unroll
      for (int u = 0; u < 8; ++u) {
        float2 f = fp8x2f(hv[u]);
        acc0 = fmaf(av[u], f.x, acc0);
        acc1 = fmaf(av[u], f.y, acc1);
      }
    }
    for (; i < cnt; ++i) {
      float a = la[i];
      float2 f = fp8x2f(H2[(size_t)lsrc[i] * 64 + c]);
      acc0 = fmaf(a, f.x, acc0);
      acc1 = fmaf(a, f.y, acc1);
    }
  }
#pragma unroll
  for (int o = 32; o; o >>= 1) dpart += __shfl_down(dpart, o);
  float invden = 1.f / __shfl(dpart, 0);
  int c0 = 2 * c;
  e2out[(size_t)n * 128 + c0]     = acc0 * invden + b2[c0];
  e2out[(size_t)n * 128 + c0 + 1] = acc1 * invden + b2[c0 + 1];
}

// ---------------- pooling: node_attn == 1 exactly; both halves = column mean --------------
__global__ __launch_bounds__(128) void pool_kernel(const float* __restrict__ e2,
                                                   float* __restrict__ g, int N, float invN) {
  int c = threadIdx.x;
  int br = blockIdx.y;
  int r0 = br * N + blockIdx.x * 128;
  int r1 = min(r0 + 128, br * N + N);
  float acc = 0.f;
  for (int n = r0; n < r1; ++n) acc += e2[(size_t)n * 128 + c];
  acc *= invN;
  float* gb = g + (size_t)br * 256;
  atomicAdd(&gb[c], acc);
  atomicAdd(&gb[128 + c], acc);
}

__global__ __launch_bounds__(256) void sim_kernel(const float* __restrict__ g1,
                                                  const float* __restrict__ g2,
                                                  float* __restrict__ out) {
  int t = threadIdx.x;
  float a = g1[t], b = g2[t];
  __shared__ float sd[256], s1[256], s2[256];
  sd[t] = a * b; s1[t] = a * a; s2[t] = b * b;
  __syncthreads();
  for (int ofs = 128; ofs; ofs >>= 1) {
    if (t < ofs) { sd[t] += sd[t + ofs]; s1[t] += s1[t + ofs]; s2[t] += s2[t + ofs]; }
    __syncthreads();
  }
  if (t == 0) {
    float n1 = fmaxf(sqrtf(s1[0]), 1e-8f);
    float n2 = fmaxf(sqrtf(s2[0]), 1e-8f);
    out[0] = sd[0] / (n1 * n2);
  }
}

// ---------------- host ----------------
extern "C" void kernel_launch(void* const* d_in, const int* in_sizes, int n_in,
                              void* d_out, int out_size, void* d_ws, size_t ws_size,
                              hipStream_t stream) {
  const int N = in_sizes[0] / INDIM;
  const int E = in_sizes[1] / 2;
  const int Etot = E + N;
  const int N2 = 2 * N;

  const float* x1  = (const float*)d_in[0];
  const int*   ei1 = (const int*)d_in[1];
  const float* x2  = (const float*)d_in[2];
  const int*   ei2 = (const int*)d_in[3];
  const float* W1  = (const float*)d_in[4];
  const float* as1 = (const float*)d_in[5];
  const float* ad1 = (const float*)d_in[6];
  const float* b1  = (const float*)d_in[7];
  const float* W2  = (const float*)d_in[8];
  const float* as2 = (const float*)d_in[9];
  const float* ad2 = (const float*)d_in[10];
  const float* b2  = (const float*)d_in[11];
  float* out = (float*)d_out;
  const int* es1 = ei1, *ed1 = ei1 + E;
  const int* es2 = ei2, *ed2 = ei2 + E;

  char* p = (char*)d_ws;
  auto alloc = [&](size_t bytes) -> char* {
    char* q = p;
    p += (bytes + 255) & ~(size_t)255;
    return q;
  };
  float* h1          = (float*)alloc((size_t)N2 * 384 * 4);
  unsigned char* h1c = (unsigned char*)alloc((size_t)N2 * 384);
  __hip_bfloat16* e1b = (__hip_bfloat16*)alloc((size_t)N2 * 384 * 2);
  float* h2          = (float*)alloc((size_t)N2 * 128 * 4);
  unsigned char* h2c = (unsigned char*)alloc((size_t)N2 * 128);
  float* e2          = (float*)alloc((size_t)N2 * 128 * 4);
  __hip_bfloat16* W1t = (__hip_bfloat16*)alloc((size_t)256 * 384 * 2);
  __hip_bfloat16* W2t = (__hip_bfloat16*)alloc((size_t)384 * 128 * 2);
  float* s1v  = (float*)alloc((size_t)N2 * 3 * 4);
  float* d1v  = (float*)alloc((size_t)N2 * 3 * 4);
  float* s2v  = (float*)alloc((size_t)N2 * 4);
  float* d2v  = (float*)alloc((size_t)N2 * 4);
  float* idn  = (float*)alloc((size_t)N2 * 3 * 4);
  float* g    = (float*)alloc(512 * 4);
  int* deg     = (int*)alloc((size_t)N2 * 4);
  int* rowptr  = (int*)alloc((size_t)(N2 + 1) * 4);
  int* cursor  = (int*)alloc((size_t)N2 * 4);
  int* csr_src = (int*)alloc((size_t)2 * Etot * 4);

  const int EB = 256;
  const int egrid2 = (2 * Etot + EB - 1) / EB;
  const int gmx = (N2 + 63) / 64;

  hipMemsetAsync(g, 0, 512 * 4, stream);
  hipMemsetAsync(deg, 0, (size_t)N2 * 4, stream);
  wprep_kernel<<<(256 * 384 + 255) / 256, 256, 0, stream>>>(W1, W1t, 256, 384, 256 * 384);
  wprep_kernel<<<(384 * 128 + 255) / 256, 256, 0, stream>>>(W2, W2t, 384, 128, 384 * 128);

  deg_kernel<<<egrid2, EB, 0, stream>>>(ed1, ed2, E, Etot, N, deg);
  mfma_gemm<256, false><<<dim3(gmx, 3), 256, 0, stream>>>(x1, x2, N, W1t, h1, h1c, N2, 384);
  sd_kernel<<<(N2 * 3 + 3) / 4, 256, 0, stream>>>(h1, as1, ad1, s1v, d1v, N2 * 3, 3);
  scan_kernel<<<1, 1024, 0, stream>>>(deg, rowptr, cursor, N2);
  fill_kernel<<<egrid2, EB, 0, stream>>>(es1, ed1, es2, ed2, E, Etot, N, cursor, csr_src);

  agg1_kernel<<<N2, 192, 0, stream>>>(h1c, s1v, d1v, rowptr, csr_src, b1, e1b, idn);
  alpha_kernel<<<egrid2, EB, 0, stream>>>(s1v, d1v, idn, es1, ed1, es2, ed2, E, Etot, N, out);

  mfma_gemm<384, true><<<dim3(gmx, 1), 256, 0, stream>>>(e1b, e1b, N2, W2t, h2, h2c, N2, 128);
  sd_kernel<<<(N2 + 3) / 4, 256, 0, stream>>>(h2, as2, ad2, s2v, d2v, N2, 1);
  agg2_kernel<<<N2, 64, 0, stream>>>(h2c, s2v, d2v, rowptr, csr_src, b2, e2);

  pool_kernel<<<dim3((N + 127) / 128, 2), 128, 0, stream>>>(e2, g, N, 1.f / (float)N);
  sim_kernel<<<1, 256, 0, stream>>>(g, g + 256, out);
}

// Round 8
// 264.376 us; speedup vs baseline: 1.6439x; 1.6439x over previous
//
#include <hip/hip_runtime.h>
#include <hip/hip_bf16.h>
#include <cstdint>
#include <cstddef>

#define INDIM 256
#define NEG 0.2f

typedef __attribute__((ext_vector_type(8))) short short8v;
typedef __attribute__((ext_vector_type(4))) float f32x4;
typedef __attribute__((ext_vector_type(2))) float f32x2;

__device__ __forceinline__ unsigned short f2bf(float x) {
  __hip_bfloat16 b = __float2bfloat16(x);
  return __builtin_bit_cast(unsigned short, b);
}

// native gfx950 fp8 (OCP E4M3) converts — single VALU instruction each
__device__ __forceinline__ unsigned char f2fp8(float v) {
  int packed = __builtin_amdgcn_cvt_pk_fp8_f32(v, v, 0, false);
  return (unsigned char)(packed & 0xff);
}

__device__ __forceinline__ f32x2 fp8x2f(unsigned short u) {
  return __builtin_amdgcn_cvt_pk_f32_fp8((int)u, false);
}

__device__ __forceinline__ float lrelu(float v) { return v > 0.f ? v : NEG * v; }

// ---------------- W pre-transpose to bf16: Wt[c][k] = bf16(W[k][c]) ----------------
__global__ void wprep_kernel(const float* __restrict__ W, __hip_bfloat16* __restrict__ Wt,
                             int K, int NC, int total) {
  int idx = blockIdx.x * blockDim.x + threadIdx.x;
  if (idx >= total) return;
  int k = idx / NC, c = idx - k * NC;
  Wt[(size_t)c * K + k] = __float2bfloat16(W[idx]);
}

// ---------------- MFMA GEMM over 2N batched rows: rows < Nsplit from A0, else A1 ----------
// tile 64x128, 4 waves (2x2), wave tile 32x64 = 2x4 fragments of 16x16, BK=32
// writes f32 Y + fp8(e4m3) Yc
template<int K, bool ABF16>
__global__ __launch_bounds__(256) void mfma_gemm(const void* __restrict__ A0,
                                                 const void* __restrict__ A1, int Nsplit,
                                                 const __hip_bfloat16* __restrict__ Wt,
                                                 float* __restrict__ Y,
                                                 unsigned char* __restrict__ Yc,
                                                 int M, int NC) {
  __shared__ short As[64][40];
  __shared__ short Bs[128][40];
  const int tid = threadIdx.x;
  const int row0 = blockIdx.x * 64;
  const int col0 = blockIdx.y * 128;
  const int l = tid & 63, w = tid >> 6;
  const int wr = w >> 1, wc = w & 1;
  const int lr = l & 15, lk = (l >> 4) * 8;

  f32x4 acc[2][4];
#pragma unroll
  for (int m = 0; m < 2; ++m)
#pragma unroll
    for (int n = 0; n < 4; ++n) acc[m][n] = {0.f, 0.f, 0.f, 0.f};

  for (int k0 = 0; k0 < K; k0 += 32) {
    __syncthreads();
    {  // stage A: 64 rows x 32 k
      int r = tid >> 2, kq = (tid & 3) * 8;
      int gr = row0 + r;
      short8v av = {0, 0, 0, 0, 0, 0, 0, 0};
      if (gr < M) {
        const void* Ab = (gr < Nsplit) ? A0 : A1;
        int lrow = (gr < Nsplit) ? gr : gr - Nsplit;
        if (ABF16) {
          av = *(const short8v*)((const short*)Ab + (size_t)lrow * K + k0 + kq);
        } else {
          const float* ap = (const float*)Ab + (size_t)lrow * K + k0 + kq;
          float4 u = *(const float4*)ap;
          float4 v = *(const float4*)(ap + 4);
          av = short8v{(short)f2bf(u.x), (short)f2bf(u.y), (short)f2bf(u.z), (short)f2bf(u.w),
                       (short)f2bf(v.x), (short)f2bf(v.y), (short)f2bf(v.z), (short)f2bf(v.w)};
        }
      }
      *(short8v*)&As[r][kq] = av;
    }
    {  // stage B: 128 cols x 32 k (Wt row-major [NC][K])
      int c = tid >> 1, kq = (tid & 1) * 8;
      const short* wp = (const short*)Wt + (size_t)(col0 + c) * K + k0 + kq;
      *(short8v*)&Bs[c][kq]      = *(const short8v*)wp;
      *(short8v*)&Bs[c][kq + 16] = *(const short8v*)(wp + 16);
    }
    __syncthreads();
    short8v a[2], b[4];
#pragma unroll
    for (int m = 0; m < 2; ++m) a[m] = *(short8v*)&As[wr * 32 + m * 16 + lr][lk];
#pragma unroll
    for (int n = 0; n < 4; ++n) b[n] = *(short8v*)&Bs[wc * 64 + n * 16 + lr][lk];
#pragma unroll
    for (int m = 0; m < 2; ++m)
#pragma unroll
      for (int n = 0; n < 4; ++n)
        acc[m][n] = __builtin_amdgcn_mfma_f32_16x16x32_bf16(a[m], b[n], acc[m][n], 0, 0, 0);
  }
  // epilogue: C/D layout col=lane&15, row=(lane>>4)*4+q
#pragma unroll
  for (int m = 0; m < 2; ++m) {
    int rbase = row0 + wr * 32 + m * 16 + (l >> 4) * 4;
#pragma unroll
    for (int n = 0; n < 4; ++n) {
      int col = col0 + wc * 64 + n * 16 + lr;
#pragma unroll
      for (int q = 0; q < 4; ++q) {
        int row = rbase + q;
        if (row < M) {
          float v = acc[m][n][q];
          Y[(size_t)row * NC + col] = v;
          Yc[(size_t)row * NC + col] = f2fp8(v);
        }
      }
    }
  }
}

// ---------------- attention dots: one wave per (node2,head); node2 in [0,2N) ----------------
__global__ __launch_bounds__(256) void sd_kernel(const float* __restrict__ H,
                                                 const float* __restrict__ As,
                                                 const float* __restrict__ Ad,
                                                 float* __restrict__ S, float* __restrict__ D,
                                                 int NB, int NH) {
  int w = blockIdx.x * 4 + (threadIdx.x >> 6);
  if (w >= NB) return;
  int lane = threadIdx.x & 63;
  int h = w % NH;
  float2 hv = reinterpret_cast<const float2*>(H + (size_t)w * 128)[lane];
  float2 as = reinterpret_cast<const float2*>(As + h * 128)[lane];
  float2 ad = reinterpret_cast<const float2*>(Ad + h * 128)[lane];
  float vs = hv.x * as.x + hv.y * as.y;
  float vd = hv.x * ad.x + hv.y * ad.y;
#pragma unroll
  for (int o = 32; o; o >>= 1) { vs += __shfl_down(vs, o); vd += __shfl_down(vd, o); }
  if (lane == 0) { S[w] = vs; D[w] = vd; }
}

// ---------------- CSR build over 2N virtual nodes (both branches) ----------------
__global__ void deg_kernel(const int* __restrict__ ed1, const int* __restrict__ ed2,
                           int E, int Etot, int N, int* __restrict__ deg) {
  int idx = blockIdx.x * blockDim.x + threadIdx.x;
  if (idx >= 2 * Etot) return;
  int br = idx >= Etot;
  int el = idx - br * Etot;
  const int* ed = br ? ed2 : ed1;
  int dn = ((el < E) ? ed[el] : (el - E)) + br * N;
  atomicAdd(&deg[dn], 1);
}

__global__ __launch_bounds__(1024) void scan_kernel(const int* __restrict__ deg,
                                                    int* __restrict__ rowptr,
                                                    int* __restrict__ cursor, int n) {
  __shared__ int wsum[16];
  __shared__ int carry_s;
  int tid = threadIdx.x;
  int lane = tid & 63, wid = tid >> 6;
  if (tid == 0) { carry_s = 0; rowptr[0] = 0; }
  __syncthreads();
  for (int base = 0; base < n; base += 1024) {
    int i = base + tid;
    int v = (i < n) ? deg[i] : 0;
    int x = v;
#pragma unroll
    for (int o = 1; o < 64; o <<= 1) {
      int t = __shfl_up(x, o);
      if (lane >= o) x += t;
    }
    if (lane == 63) wsum[wid] = x;
    __syncthreads();
    if (wid == 0) {
      int wv = (lane < 16) ? wsum[lane] : 0;
#pragma unroll
      for (int o = 1; o < 16; o <<= 1) {
        int t = __shfl_up(wv, o);
        if (lane >= o) wv += t;
      }
      if (lane < 16) wsum[lane] = wv;
    }
    __syncthreads();
    int incl = carry_s + (wid ? wsum[wid - 1] : 0) + x;
    if (i < n) { rowptr[i + 1] = incl; cursor[i] = incl - v; }
    __syncthreads();
    if (tid == 1023) carry_s = incl;
    __syncthreads();
  }
}

__global__ void fill_kernel(const int* __restrict__ es1, const int* __restrict__ ed1,
                            const int* __restrict__ es2, const int* __restrict__ ed2,
                            int E, int Etot, int N, int* __restrict__ cursor,
                            int* __restrict__ csr_src) {
  int idx = blockIdx.x * blockDim.x + threadIdx.x;
  if (idx >= 2 * Etot) return;
  int br = idx >= Etot;
  int el = idx - br * Etot;
  const int* es = br ? es2 : es1;
  const int* ed = br ? ed2 : ed1;
  int sn, dn;
  if (el < E) { sn = es[el]; dn = ed[el]; } else { sn = dn = el - E; }
  sn += br * N; dn += br * N;
  int pos = atomicAdd(&cursor[dn], 1);
  csr_src[pos] = sn;
}

// ---------------- agg1: SINGLE-PASS unnormalized aggregate + inline denom, fp8 gathers ----
// 192 threads, 1 virtual node per block, thread j -> cols 2j,2j+1 (ushort = fp8x2 load)
__global__ __launch_bounds__(192) void agg1_kernel(const unsigned char* __restrict__ h1c,
                                                   const float* __restrict__ S,
                                                   const float* __restrict__ D,
                                                   const int* __restrict__ rowptr,
                                                   const int* __restrict__ csr_src,
                                                   const float* __restrict__ b1,
                                                   __hip_bfloat16* __restrict__ e1b,
                                                   float* __restrict__ invden) {
  __shared__ int lsrc[192];
  __shared__ float la[3][192];
  __shared__ float red[3][3];
  __shared__ float inv_s[3];
  const unsigned short* H2 = reinterpret_cast<const unsigned short*>(h1c);
  int n = blockIdx.x;
  int j = threadIdx.x;           // 0..191 -> cols 2j, 2j+1
  int wid = j >> 6, lane = j & 63;
  int p0 = rowptr[n], p1 = rowptr[n + 1];
  float d0 = D[n * 3], d1 = D[n * 3 + 1], d2 = D[n * 3 + 2];

  float dp0 = 0.f, dp1 = 0.f, dp2 = 0.f;
  float acc0 = 0.f, acc1 = 0.f;
  for (int base = p0; base < p1; base += 192) {
    int cnt = min(192, p1 - base);
    __syncthreads();
    if (j < cnt) {
      int sn = csr_src[base + j];
      lsrc[j] = sn;
      float e0 = __expf(lrelu(S[sn * 3] + d0));
      float e1 = __expf(lrelu(S[sn * 3 + 1] + d1));
      float e2 = __expf(lrelu(S[sn * 3 + 2] + d2));
      la[0][j] = e0; la[1][j] = e1; la[2][j] = e2;
      dp0 += e0; dp1 += e1; dp2 += e2;
    }
    __syncthreads();
    int i = 0;
    for (; i + 8 <= cnt; i += 8) {
      float av[8];
      unsigned short hv[8];
#pragma unroll
      for (int u = 0; u < 8; ++u) {
        int sn = lsrc[i + u];
        av[u] = la[wid][i + u];
        hv[u] = H2[(size_t)sn * 192 + j];
      }
#pragma unroll
      for (int u = 0; u < 8; ++u) {
        f32x2 f = fp8x2f(hv[u]);
        acc0 = fmaf(av[u], f.x, acc0);
        acc1 = fmaf(av[u], f.y, acc1);
      }
    }
    for (; i < cnt; ++i) {
      int sn = lsrc[i];
      float a = la[wid][i];
      f32x2 f = fp8x2f(H2[(size_t)sn * 192 + j]);
      acc0 = fmaf(a, f.x, acc0);
      acc1 = fmaf(a, f.y, acc1);
    }
  }
  // block-reduce the exp partials
#pragma unroll
  for (int o = 32; o; o >>= 1) {
    dp0 += __shfl_down(dp0, o); dp1 += __shfl_down(dp1, o); dp2 += __shfl_down(dp2, o);
  }
  if (lane == 0) { red[wid][0] = dp0; red[wid][1] = dp1; red[wid][2] = dp2; }
  __syncthreads();
  if (j == 0) {
    inv_s[0] = 1.f / (red[0][0] + red[1][0] + red[2][0]);
    inv_s[1] = 1.f / (red[0][1] + red[1][1] + red[2][1]);
    inv_s[2] = 1.f / (red[0][2] + red[1][2] + red[2][2]);
  }
  __syncthreads();
  float inv = inv_s[wid];
  int c0 = 2 * j;
  float v0 = acc0 * inv + b1[c0];
  float v1 = acc1 * inv + b1[c0 + 1];
  __hip_bfloat162 ov;
  ov.x = __float2bfloat16(v0 > 0.f ? v0 : 0.f);
  ov.y = __float2bfloat16(v1 > 0.f ? v1 : 0.f);
  reinterpret_cast<__hip_bfloat162*>(e1b)[(size_t)n * 192 + j] = ov;
  if (j < 3) invden[n * 3 + j] = inv_s[j];
}

// ---------------- alpha: edge-major, coalesced writes into d_out ----------------
__global__ void alpha_kernel(const float* __restrict__ S, const float* __restrict__ D,
                             const float* __restrict__ invden,
                             const int* __restrict__ es1, const int* __restrict__ ed1,
                             const int* __restrict__ es2, const int* __restrict__ ed2,
                             int E, int Etot, int N, float* __restrict__ out) {
  int idx = blockIdx.x * blockDim.x + threadIdx.x;
  if (idx >= 2 * Etot) return;
  int br = idx >= Etot;
  int el = idx - br * Etot;
  const int* es = br ? es2 : es1;
  const int* ed = br ? ed2 : ed1;
  int sn, dn;
  if (el < E) { sn = es[el]; dn = ed[el]; } else { sn = dn = el - E; }
  sn += br * N; dn += br * N;
  float* ao = out + 1 + (size_t)br * Etot * 3 + (size_t)el * 3;
#pragma unroll
  for (int h = 0; h < 3; ++h) {
    float v = lrelu(S[sn * 3 + h] + D[dn * 3 + h]);
    ao[h] = __expf(v) * invden[dn * 3 + h];
  }
}

// ---------------- agg2: SINGLE-PASS, 64 threads per virtual node, fp8 gathers ------------
__global__ __launch_bounds__(64) void agg2_kernel(const unsigned char* __restrict__ h2c,
                                                  const float* __restrict__ S,
                                                  const float* __restrict__ D,
                                                  const int* __restrict__ rowptr,
                                                  const int* __restrict__ csr_src,
                                                  const float* __restrict__ b2,
                                                  float* __restrict__ e2out) {
  __shared__ int lsrc[256];
  __shared__ float la[256];
  const unsigned short* H2 = reinterpret_cast<const unsigned short*>(h2c);
  int n = blockIdx.x;
  int c = threadIdx.x;           // 0..63 -> cols 2c, 2c+1
  int p0 = rowptr[n], p1 = rowptr[n + 1];
  float dn_v = D[n];

  float dpart = 0.f;
  float acc0 = 0.f, acc1 = 0.f;
  for (int base = p0; base < p1; base += 256) {
    int cnt = min(256, p1 - base);
    __syncthreads();
    for (int i = c; i < cnt; i += 64) {
      int sn = csr_src[base + i];
      lsrc[i] = sn;
      float ex = __expf(lrelu(S[sn] + dn_v));
      la[i] = ex;
      dpart += ex;
    }
    __syncthreads();
    int i = 0;
    for (; i + 8 <= cnt; i += 8) {
      float av[8];
      unsigned short hv[8];
#pragma unroll
      for (int u = 0; u < 8; ++u) {
        int sn = lsrc[i + u];
        av[u] = la[i + u];
        hv[u] = H2[(size_t)sn * 64 + c];
      }
#pragma unroll
      for (int u = 0; u < 8; ++u) {
        f32x2 f = fp8x2f(hv[u]);
        acc0 = fmaf(av[u], f.x, acc0);
        acc1 = fmaf(av[u], f.y, acc1);
      }
    }
    for (; i < cnt; ++i) {
      float a = la[i];
      f32x2 f = fp8x2f(H2[(size_t)lsrc[i] * 64 + c]);
      acc0 = fmaf(a, f.x, acc0);
      acc1 = fmaf(a, f.y, acc1);
    }
  }
#pragma unroll
  for (int o = 32; o; o >>= 1) dpart += __shfl_down(dpart, o);
  float invden = 1.f / __shfl(dpart, 0);
  int c0 = 2 * c;
  e2out[(size_t)n * 128 + c0]     = acc0 * invden + b2[c0];
  e2out[(size_t)n * 128 + c0 + 1] = acc1 * invden + b2[c0 + 1];
}

// ---------------- pooling: node_attn == 1 exactly; both halves = column mean --------------
__global__ __launch_bounds__(128) void pool_kernel(const float* __restrict__ e2,
                                                   float* __restrict__ g, int N, float invN) {
  int c = threadIdx.x;
  int br = blockIdx.y;
  int r0 = br * N + blockIdx.x * 128;
  int r1 = min(r0 + 128, br * N + N);
  float acc = 0.f;
  for (int n = r0; n < r1; ++n) acc += e2[(size_t)n * 128 + c];
  acc *= invN;
  float* gb = g + (size_t)br * 256;
  atomicAdd(&gb[c], acc);
  atomicAdd(&gb[128 + c], acc);
}

__global__ __launch_bounds__(256) void sim_kernel(const float* __restrict__ g1,
                                                  const float* __restrict__ g2,
                                                  float* __restrict__ out) {
  int t = threadIdx.x;
  float a = g1[t], b = g2[t];
  __shared__ float sd[256], s1[256], s2[256];
  sd[t] = a * b; s1[t] = a * a; s2[t] = b * b;
  __syncthreads();
  for (int ofs = 128; ofs; ofs >>= 1) {
    if (t < ofs) { sd[t] += sd[t + ofs]; s1[t] += s1[t + ofs]; s2[t] += s2[t + ofs]; }
    __syncthreads();
  }
  if (t == 0) {
    float n1 = fmaxf(sqrtf(s1[0]), 1e-8f);
    float n2 = fmaxf(sqrtf(s2[0]), 1e-8f);
    out[0] = sd[0] / (n1 * n2);
  }
}

// ---------------- host ----------------
extern "C" void kernel_launch(void* const* d_in, const int* in_sizes, int n_in,
                              void* d_out, int out_size, void* d_ws, size_t ws_size,
                              hipStream_t stream) {
  const int N = in_sizes[0] / INDIM;
  const int E = in_sizes[1] / 2;
  const int Etot = E + N;
  const int N2 = 2 * N;

  const float* x1  = (const float*)d_in[0];
  const int*   ei1 = (const int*)d_in[1];
  const float* x2  = (const float*)d_in[2];
  const int*   ei2 = (const int*)d_in[3];
  const float* W1  = (const float*)d_in[4];
  const float* as1 = (const float*)d_in[5];
  const float* ad1 = (const float*)d_in[6];
  const float* b1  = (const float*)d_in[7];
  const float* W2  = (const float*)d_in[8];
  const float* as2 = (const float*)d_in[9];
  const float* ad2 = (const float*)d_in[10];
  const float* b2  = (const float*)d_in[11];
  float* out = (float*)d_out;
  const int* es1 = ei1, *ed1 = ei1 + E;
  const int* es2 = ei2, *ed2 = ei2 + E;

  char* p = (char*)d_ws;
  auto alloc = [&](size_t bytes) -> char* {
    char* q = p;
    p += (bytes + 255) & ~(size_t)255;
    return q;
  };
  float* h1          = (float*)alloc((size_t)N2 * 384 * 4);
  unsigned char* h1c = (unsigned char*)alloc((size_t)N2 * 384);
  __hip_bfloat16* e1b = (__hip_bfloat16*)alloc((size_t)N2 * 384 * 2);
  float* h2          = (float*)alloc((size_t)N2 * 128 * 4);
  unsigned char* h2c = (unsigned char*)alloc((size_t)N2 * 128);
  float* e2          = (float*)alloc((size_t)N2 * 128 * 4);
  __hip_bfloat16* W1t = (__hip_bfloat16*)alloc((size_t)256 * 384 * 2);
  __hip_bfloat16* W2t = (__hip_bfloat16*)alloc((size_t)384 * 128 * 2);
  float* s1v  = (float*)alloc((size_t)N2 * 3 * 4);
  float* d1v  = (float*)alloc((size_t)N2 * 3 * 4);
  float* s2v  = (float*)alloc((size_t)N2 * 4);
  float* d2v  = (float*)alloc((size_t)N2 * 4);
  float* idn  = (float*)alloc((size_t)N2 * 3 * 4);
  float* g    = (float*)alloc(512 * 4);
  int* deg     = (int*)alloc((size_t)N2 * 4);
  int* rowptr  = (int*)alloc((size_t)(N2 + 1) * 4);
  int* cursor  = (int*)alloc((size_t)N2 * 4);
  int* csr_src = (int*)alloc((size_t)2 * Etot * 4);

  const int EB = 256;
  const int egrid2 = (2 * Etot + EB - 1) / EB;
  const int gmx = (N2 + 63) / 64;

  hipMemsetAsync(g, 0, 512 * 4, stream);
  hipMemsetAsync(deg, 0, (size_t)N2 * 4, stream);
  wprep_kernel<<<(256 * 384 + 255) / 256, 256, 0, stream>>>(W1, W1t, 256, 384, 256 * 384);
  wprep_kernel<<<(384 * 128 + 255) / 256, 256, 0, stream>>>(W2, W2t, 384, 128, 384 * 128);

  deg_kernel<<<egrid2, EB, 0, stream>>>(ed1, ed2, E, Etot, N, deg);
  mfma_gemm<256, false><<<dim3(gmx, 3), 256, 0, stream>>>(x1, x2, N, W1t, h1, h1c, N2, 384);
  sd_kernel<<<(N2 * 3 + 3) / 4, 256, 0, stream>>>(h1, as1, ad1, s1v, d1v, N2 * 3, 3);
  scan_kernel<<<1, 1024, 0, stream>>>(deg, rowptr, cursor, N2);
  fill_kernel<<<egrid2, EB, 0, stream>>>(es1, ed1, es2, ed2, E, Etot, N, cursor, csr_src);

  agg1_kernel<<<N2, 192, 0, stream>>>(h1c, s1v, d1v, rowptr, csr_src, b1, e1b, idn);
  alpha_kernel<<<egrid2, EB, 0, stream>>>(s1v, d1v, idn, es1, ed1, es2, ed2, E, Etot, N, out);

  mfma_gemm<384, true><<<dim3(gmx, 1), 256, 0, stream>>>(e1b, e1b, N2, W2t, h2, h2c, N2, 128);
  sd_kernel<<<(N2 + 3) / 4, 256, 0, stream>>>(h2, as2, ad2, s2v, d2v, N2, 1);
  agg2_kernel<<<N2, 64, 0, stream>>>(h2c, s2v, d2v, rowptr, csr_src, b2, e2);

  pool_kernel<<<dim3((N + 127) / 128, 2), 128, 0, stream>>>(e2, g, N, 1.f / (float)N);
  sim_kernel<<<1, 256, 0, stream>>>(g, g + 256, out);
}

// Round 9
// 262.060 us; speedup vs baseline: 1.6584x; 1.0088x over previous
//
#include <hip/hip_runtime.h>
#include <hip/hip_bf16.h>
#include <cstdint>
#include <cstddef>

#define INDIM 256
#define NEG 0.2f

typedef __attribute__((ext_vector_type(8))) short short8v;
typedef __attribute__((ext_vector_type(4))) float f32x4;
typedef __attribute__((ext_vector_type(2))) float f32x2;

__device__ __forceinline__ unsigned short f2bf(float x) {
  __hip_bfloat16 b = __float2bfloat16(x);
  return __builtin_bit_cast(unsigned short, b);
}

// native gfx950 fp8 (OCP E4M3) converts — single VALU instruction each
__device__ __forceinline__ unsigned char f2fp8(float v) {
  int packed = __builtin_amdgcn_cvt_pk_fp8_f32(v, v, 0, false);
  return (unsigned char)(packed & 0xff);
}

__device__ __forceinline__ float lrelu(float v) { return v > 0.f ? v : NEG * v; }

// ---------------- W pre-transpose to bf16: Wt[c][k] = bf16(W[k][c]) ----------------
__global__ void wprep_kernel(const float* __restrict__ W, __hip_bfloat16* __restrict__ Wt,
                             int K, int NC, int total) {
  int idx = blockIdx.x * blockDim.x + threadIdx.x;
  if (idx >= total) return;
  int k = idx / NC, c = idx - k * NC;
  Wt[(size_t)c * K + k] = __float2bfloat16(W[idx]);
}

// ---------------- MFMA GEMM over 2N batched rows: rows < Nsplit from A0, else A1 ----------
// tile 64x128, 4 waves (2x2), wave tile 32x64 = 2x4 fragments of 16x16, BK=32
// writes f32 Y + fp8(e4m3) Yc
template<int K, bool ABF16>
__global__ __launch_bounds__(256) void mfma_gemm(const void* __restrict__ A0,
                                                 const void* __restrict__ A1, int Nsplit,
                                                 const __hip_bfloat16* __restrict__ Wt,
                                                 float* __restrict__ Y,
                                                 unsigned char* __restrict__ Yc,
                                                 int M, int NC) {
  __shared__ short As[64][40];
  __shared__ short Bs[128][40];
  const int tid = threadIdx.x;
  const int row0 = blockIdx.x * 64;
  const int col0 = blockIdx.y * 128;
  const int l = tid & 63, w = tid >> 6;
  const int wr = w >> 1, wc = w & 1;
  const int lr = l & 15, lk = (l >> 4) * 8;

  f32x4 acc[2][4];
#pragma unroll
  for (int m = 0; m < 2; ++m)
#pragma unroll
    for (int n = 0; n < 4; ++n) acc[m][n] = {0.f, 0.f, 0.f, 0.f};

  for (int k0 = 0; k0 < K; k0 += 32) {
    __syncthreads();
    {  // stage A: 64 rows x 32 k
      int r = tid >> 2, kq = (tid & 3) * 8;
      int gr = row0 + r;
      short8v av = {0, 0, 0, 0, 0, 0, 0, 0};
      if (gr < M) {
        const void* Ab = (gr < Nsplit) ? A0 : A1;
        int lrow = (gr < Nsplit) ? gr : gr - Nsplit;
        if (ABF16) {
          av = *(const short8v*)((const short*)Ab + (size_t)lrow * K + k0 + kq);
        } else {
          const float* ap = (const float*)Ab + (size_t)lrow * K + k0 + kq;
          float4 u = *(const float4*)ap;
          float4 v = *(const float4*)(ap + 4);
          av = short8v{(short)f2bf(u.x), (short)f2bf(u.y), (short)f2bf(u.z), (short)f2bf(u.w),
                       (short)f2bf(v.x), (short)f2bf(v.y), (short)f2bf(v.z), (short)f2bf(v.w)};
        }
      }
      *(short8v*)&As[r][kq] = av;
    }
    {  // stage B: 128 cols x 32 k (Wt row-major [NC][K])
      int c = tid >> 1, kq = (tid & 1) * 8;
      const short* wp = (const short*)Wt + (size_t)(col0 + c) * K + k0 + kq;
      *(short8v*)&Bs[c][kq]      = *(const short8v*)wp;
      *(short8v*)&Bs[c][kq + 16] = *(const short8v*)(wp + 16);
    }
    __syncthreads();
    short8v a[2], b[4];
#pragma unroll
    for (int m = 0; m < 2; ++m) a[m] = *(short8v*)&As[wr * 32 + m * 16 + lr][lk];
#pragma unroll
    for (int n = 0; n < 4; ++n) b[n] = *(short8v*)&Bs[wc * 64 + n * 16 + lr][lk];
#pragma unroll
    for (int m = 0; m < 2; ++m)
#pragma unroll
      for (int n = 0; n < 4; ++n)
        acc[m][n] = __builtin_amdgcn_mfma_f32_16x16x32_bf16(a[m], b[n], acc[m][n], 0, 0, 0);
  }
  // epilogue: C/D layout col=lane&15, row=(lane>>4)*4+q
#pragma unroll
  for (int m = 0; m < 2; ++m) {
    int rbase = row0 + wr * 32 + m * 16 + (l >> 4) * 4;
#pragma unroll
    for (int n = 0; n < 4; ++n) {
      int col = col0 + wc * 64 + n * 16 + lr;
#pragma unroll
      for (int q = 0; q < 4; ++q) {
        int row = rbase + q;
        if (row < M) {
          float v = acc[m][n][q];
          Y[(size_t)row * NC + col] = v;
          Yc[(size_t)row * NC + col] = f2fp8(v);
        }
      }
    }
  }
}

// ---------------- attention dots: one wave per (node2,head); node2 in [0,2N) ----------------
__global__ __launch_bounds__(256) void sd_kernel(const float* __restrict__ H,
                                                 const float* __restrict__ As,
                                                 const float* __restrict__ Ad,
                                                 float* __restrict__ S, float* __restrict__ D,
                                                 int NB, int NH) {
  int w = blockIdx.x * 4 + (threadIdx.x >> 6);
  if (w >= NB) return;
  int lane = threadIdx.x & 63;
  int h = w % NH;
  float2 hv = reinterpret_cast<const float2*>(H + (size_t)w * 128)[lane];
  float2 as = reinterpret_cast<const float2*>(As + h * 128)[lane];
  float2 ad = reinterpret_cast<const float2*>(Ad + h * 128)[lane];
  float vs = hv.x * as.x + hv.y * as.y;
  float vd = hv.x * ad.x + hv.y * ad.y;
#pragma unroll
  for (int o = 32; o; o >>= 1) { vs += __shfl_down(vs, o); vd += __shfl_down(vd, o); }
  if (lane == 0) { S[w] = vs; D[w] = vd; }
}

// ---------------- CSR build over 2N virtual nodes (both branches) ----------------
__global__ void deg_kernel(const int* __restrict__ ed1, const int* __restrict__ ed2,
                           int E, int Etot, int N, int* __restrict__ deg) {
  int idx = blockIdx.x * blockDim.x + threadIdx.x;
  if (idx >= 2 * Etot) return;
  int br = idx >= Etot;
  int el = idx - br * Etot;
  const int* ed = br ? ed2 : ed1;
  int dn = ((el < E) ? ed[el] : (el - E)) + br * N;
  atomicAdd(&deg[dn], 1);
}

__global__ __launch_bounds__(1024) void scan_kernel(const int* __restrict__ deg,
                                                    int* __restrict__ rowptr,
                                                    int* __restrict__ cursor, int n) {
  __shared__ int wsum[16];
  __shared__ int carry_s;
  int tid = threadIdx.x;
  int lane = tid & 63, wid = tid >> 6;
  if (tid == 0) { carry_s = 0; rowptr[0] = 0; }
  __syncthreads();
  for (int base = 0; base < n; base += 1024) {
    int i = base + tid;
    int v = (i < n) ? deg[i] : 0;
    int x = v;
#pragma unroll
    for (int o = 1; o < 64; o <<= 1) {
      int t = __shfl_up(x, o);
      if (lane >= o) x += t;
    }
    if (lane == 63) wsum[wid] = x;
    __syncthreads();
    if (wid == 0) {
      int wv = (lane < 16) ? wsum[lane] : 0;
#pragma unroll
      for (int o = 1; o < 16; o <<= 1) {
        int t = __shfl_up(wv, o);
        if (lane >= o) wv += t;
      }
      if (lane < 16) wsum[lane] = wv;
    }
    __syncthreads();
    int incl = carry_s + (wid ? wsum[wid - 1] : 0) + x;
    if (i < n) { rowptr[i + 1] = incl; cursor[i] = incl - v; }
    __syncthreads();
    if (tid == 1023) carry_s = incl;
    __syncthreads();
  }
}

__global__ void fill_kernel(const int* __restrict__ es1, const int* __restrict__ ed1,
                            const int* __restrict__ es2, const int* __restrict__ ed2,
                            int E, int Etot, int N, int* __restrict__ cursor,
                            int* __restrict__ csr_src) {
  int idx = blockIdx.x * blockDim.x + threadIdx.x;
  if (idx >= 2 * Etot) return;
  int br = idx >= Etot;
  int el = idx - br * Etot;
  const int* es = br ? es2 : es1;
  const int* ed = br ? ed2 : ed1;
  int sn, dn;
  if (el < E) { sn = es[el]; dn = ed[el]; } else { sn = dn = el - E; }
  sn += br * N; dn += br * N;
  int pos = atomicAdd(&cursor[dn], 1);
  csr_src[pos] = sn;
}

// ---------------- agg1: single-pass aggregate + inline denom, dword fp8 gathers -----------
// 192 threads = 2 edge-halves x 96 col-groups (4 cols each). Halves process even/odd edges;
// cross-half reduce via reused LDS.
__global__ __launch_bounds__(192) void agg1_kernel(const unsigned char* __restrict__ h1c,
                                                   const float* __restrict__ S,
                                                   const float* __restrict__ D,
                                                   const int* __restrict__ rowptr,
                                                   const int* __restrict__ csr_src,
                                                   const float* __restrict__ b1,
                                                   __hip_bfloat16* __restrict__ e1b,
                                                   float* __restrict__ invden) {
  __shared__ int lsrc[192];
  __shared__ float la[3][192];
  __shared__ float red[3][3];
  __shared__ float inv_s[3];
  const unsigned int* H4 = reinterpret_cast<const unsigned int*>(h1c);
  int n = blockIdx.x;
  int j = threadIdx.x;
  int wid = j >> 6, lane = j & 63;
  int half = (j >= 96) ? 1 : 0;
  int t = j - half * 96;         // col group: cols 4t..4t+3
  int head = t >> 5;             // 4t/128
  int p0 = rowptr[n], p1 = rowptr[n + 1];
  float d0 = D[n * 3], d1 = D[n * 3 + 1], d2 = D[n * 3 + 2];

  float dp0 = 0.f, dp1 = 0.f, dp2 = 0.f;
  float acc[4] = {0.f, 0.f, 0.f, 0.f};
  for (int base = p0; base < p1; base += 192) {
    int cnt = min(192, p1 - base);
    __syncthreads();
    if (j < cnt) {
      int sn = csr_src[base + j];
      lsrc[j] = sn;
      float e0 = __expf(lrelu(S[sn * 3] + d0));
      float e1 = __expf(lrelu(S[sn * 3 + 1] + d1));
      float e2 = __expf(lrelu(S[sn * 3 + 2] + d2));
      la[0][j] = e0; la[1][j] = e1; la[2][j] = e2;
      dp0 += e0; dp1 += e1; dp2 += e2;
    }
    __syncthreads();
    int i = half;
    for (; i + 14 < cnt; i += 16) {
      unsigned int hv[8];
      float av[8];
#pragma unroll
      for (int u = 0; u < 8; ++u) {
        int e = i + 2 * u;
        int sn = lsrc[e];
        av[u] = la[head][e];
        hv[u] = H4[(size_t)sn * 96 + t];
      }
#pragma unroll
      for (int u = 0; u < 8; ++u) {
        f32x2 f0 = __builtin_amdgcn_cvt_pk_f32_fp8((int)hv[u], false);
        f32x2 f1 = __builtin_amdgcn_cvt_pk_f32_fp8((int)hv[u], true);
        acc[0] = fmaf(av[u], f0.x, acc[0]);
        acc[1] = fmaf(av[u], f0.y, acc[1]);
        acc[2] = fmaf(av[u], f1.x, acc[2]);
        acc[3] = fmaf(av[u], f1.y, acc[3]);
      }
    }
    for (; i < cnt; i += 2) {
      int sn = lsrc[i];
      float a = la[head][i];
      unsigned int hv = H4[(size_t)sn * 96 + t];
      f32x2 f0 = __builtin_amdgcn_cvt_pk_f32_fp8((int)hv, false);
      f32x2 f1 = __builtin_amdgcn_cvt_pk_f32_fp8((int)hv, true);
      acc[0] = fmaf(a, f0.x, acc[0]);
      acc[1] = fmaf(a, f0.y, acc[1]);
      acc[2] = fmaf(a, f1.x, acc[2]);
      acc[3] = fmaf(a, f1.y, acc[3]);
    }
  }
  // cross-half reduce (reuse la storage)
  __syncthreads();
  float* racc = &la[0][0];       // 96*4 floats
  if (half == 1) {
    racc[t * 4 + 0] = acc[0]; racc[t * 4 + 1] = acc[1];
    racc[t * 4 + 2] = acc[2]; racc[t * 4 + 3] = acc[3];
  }
  __syncthreads();
  if (half == 0) {
    acc[0] += racc[t * 4 + 0]; acc[1] += racc[t * 4 + 1];
    acc[2] += racc[t * 4 + 2]; acc[3] += racc[t * 4 + 3];
  }
  // block-reduce the exp partials
#pragma unroll
  for (int o = 32; o; o >>= 1) {
    dp0 += __shfl_down(dp0, o); dp1 += __shfl_down(dp1, o); dp2 += __shfl_down(dp2, o);
  }
  if (lane == 0) { red[wid][0] = dp0; red[wid][1] = dp1; red[wid][2] = dp2; }
  __syncthreads();
  if (j == 0) {
    inv_s[0] = 1.f / (red[0][0] + red[1][0] + red[2][0]);
    inv_s[1] = 1.f / (red[0][1] + red[1][1] + red[2][1]);
    inv_s[2] = 1.f / (red[0][2] + red[1][2] + red[2][2]);
  }
  __syncthreads();
  if (half == 0) {
    float inv = inv_s[head];
    float4 bb = *reinterpret_cast<const float4*>(b1 + 4 * t);
    float v0 = acc[0] * inv + bb.x;
    float v1 = acc[1] * inv + bb.y;
    float v2 = acc[2] * inv + bb.z;
    float v3 = acc[3] * inv + bb.w;
    v0 = v0 > 0.f ? v0 : 0.f; v1 = v1 > 0.f ? v1 : 0.f;
    v2 = v2 > 0.f ? v2 : 0.f; v3 = v3 > 0.f ? v3 : 0.f;
    uint2 st;
    st.x = (unsigned int)f2bf(v0) | ((unsigned int)f2bf(v1) << 16);
    st.y = (unsigned int)f2bf(v2) | ((unsigned int)f2bf(v3) << 16);
    *reinterpret_cast<uint2*>(reinterpret_cast<unsigned short*>(e1b) + (size_t)n * 384 + 4 * t) = st;
  }
  if (j < 3) invden[n * 3 + j] = inv_s[j];
}

// ---------------- alpha: edge-major, coalesced writes into d_out ----------------
__global__ void alpha_kernel(const float* __restrict__ S, const float* __restrict__ D,
                             const float* __restrict__ invden,
                             const int* __restrict__ es1, const int* __restrict__ ed1,
                             const int* __restrict__ es2, const int* __restrict__ ed2,
                             int E, int Etot, int N, float* __restrict__ out) {
  int idx = blockIdx.x * blockDim.x + threadIdx.x;
  if (idx >= 2 * Etot) return;
  int br = idx >= Etot;
  int el = idx - br * Etot;
  const int* es = br ? es2 : es1;
  const int* ed = br ? ed2 : ed1;
  int sn, dn;
  if (el < E) { sn = es[el]; dn = ed[el]; } else { sn = dn = el - E; }
  sn += br * N; dn += br * N;
  float* ao = out + 1 + (size_t)br * Etot * 3 + (size_t)el * 3;
#pragma unroll
  for (int h = 0; h < 3; ++h) {
    float v = lrelu(S[sn * 3 + h] + D[dn * 3 + h]);
    ao[h] = __expf(v) * invden[dn * 3 + h];
  }
}

// ---------------- agg2: single-pass, 1 wave = 2 edge-halves x 32 col-groups ---------------
__global__ __launch_bounds__(64) void agg2_kernel(const unsigned char* __restrict__ h2c,
                                                  const float* __restrict__ S,
                                                  const float* __restrict__ D,
                                                  const int* __restrict__ rowptr,
                                                  const int* __restrict__ csr_src,
                                                  const float* __restrict__ b2,
                                                  float* __restrict__ e2out) {
  __shared__ int lsrc[256];
  __shared__ float la[256];
  const unsigned int* H4 = reinterpret_cast<const unsigned int*>(h2c);
  int n = blockIdx.x;
  int lane = threadIdx.x;
  int half = lane >> 5, t = lane & 31;   // cols 4t..4t+3
  int p0 = rowptr[n], p1 = rowptr[n + 1];
  float dn_v = D[n];

  float dpart = 0.f;
  float acc[4] = {0.f, 0.f, 0.f, 0.f};
  for (int base = p0; base < p1; base += 256) {
    int cnt = min(256, p1 - base);
    __syncthreads();
    for (int i = lane; i < cnt; i += 64) {
      int sn = csr_src[base + i];
      lsrc[i] = sn;
      float ex = __expf(lrelu(S[sn] + dn_v));
      la[i] = ex;
      dpart += ex;
    }
    __syncthreads();
    int i = half;
    for (; i + 14 < cnt; i += 16) {
      unsigned int hv[8];
      float av[8];
#pragma unroll
      for (int u = 0; u < 8; ++u) {
        int e = i + 2 * u;
        int sn = lsrc[e];
        av[u] = la[e];
        hv[u] = H4[(size_t)sn * 32 + t];
      }
#pragma unroll
      for (int u = 0; u < 8; ++u) {
        f32x2 f0 = __builtin_amdgcn_cvt_pk_f32_fp8((int)hv[u], false);
        f32x2 f1 = __builtin_amdgcn_cvt_pk_f32_fp8((int)hv[u], true);
        acc[0] = fmaf(av[u], f0.x, acc[0]);
        acc[1] = fmaf(av[u], f0.y, acc[1]);
        acc[2] = fmaf(av[u], f1.x, acc[2]);
        acc[3] = fmaf(av[u], f1.y, acc[3]);
      }
    }
    for (; i < cnt; i += 2) {
      int sn = lsrc[i];
      float a = la[i];
      unsigned int hv = H4[(size_t)sn * 32 + t];
      f32x2 f0 = __builtin_amdgcn_cvt_pk_f32_fp8((int)hv, false);
      f32x2 f1 = __builtin_amdgcn_cvt_pk_f32_fp8((int)hv, true);
      acc[0] = fmaf(a, f0.x, acc[0]);
      acc[1] = fmaf(a, f0.y, acc[1]);
      acc[2] = fmaf(a, f1.x, acc[2]);
      acc[3] = fmaf(a, f1.y, acc[3]);
    }
  }
  // cross-half reduce via shuffle (lane ^ 32)
#pragma unroll
  for (int k = 0; k < 4; ++k) acc[k] += __shfl_xor(acc[k], 32);
#pragma unroll
  for (int o = 32; o; o >>= 1) dpart += __shfl_down(dpart, o);
  float invden = 1.f / __shfl(dpart, 0);
  if (half == 0) {
    float4 bb = *reinterpret_cast<const float4*>(b2 + 4 * t);
    float4 ov;
    ov.x = acc[0] * invden + bb.x;
    ov.y = acc[1] * invden + bb.y;
    ov.z = acc[2] * invden + bb.z;
    ov.w = acc[3] * invden + bb.w;
    *reinterpret_cast<float4*>(e2out + (size_t)n * 128 + 4 * t) = ov;
  }
}

// ---------------- pooling: node_attn == 1 exactly; both halves = column mean --------------
__global__ __launch_bounds__(128) void pool_kernel(const float* __restrict__ e2,
                                                   float* __restrict__ g, int N, float invN) {
  int c = threadIdx.x;
  int br = blockIdx.y;
  int r0 = br * N + blockIdx.x * 128;
  int r1 = min(r0 + 128, br * N + N);
  float acc = 0.f;
  for (int n = r0; n < r1; ++n) acc += e2[(size_t)n * 128 + c];
  acc *= invN;
  float* gb = g + (size_t)br * 256;
  atomicAdd(&gb[c], acc);
  atomicAdd(&gb[128 + c], acc);
}

__global__ __launch_bounds__(256) void sim_kernel(const float* __restrict__ g1,
                                                  const float* __restrict__ g2,
                                                  float* __restrict__ out) {
  int t = threadIdx.x;
  float a = g1[t], b = g2[t];
  __shared__ float sd[256], s1[256], s2[256];
  sd[t] = a * b; s1[t] = a * a; s2[t] = b * b;
  __syncthreads();
  for (int ofs = 128; ofs; ofs >>= 1) {
    if (t < ofs) { sd[t] += sd[t + ofs]; s1[t] += s1[t + ofs]; s2[t] += s2[t + ofs]; }
    __syncthreads();
  }
  if (t == 0) {
    float n1 = fmaxf(sqrtf(s1[0]), 1e-8f);
    float n2 = fmaxf(sqrtf(s2[0]), 1e-8f);
    out[0] = sd[0] / (n1 * n2);
  }
}

// ---------------- host ----------------
extern "C" void kernel_launch(void* const* d_in, const int* in_sizes, int n_in,
                              void* d_out, int out_size, void* d_ws, size_t ws_size,
                              hipStream_t stream) {
  const int N = in_sizes[0] / INDIM;
  const int E = in_sizes[1] / 2;
  const int Etot = E + N;
  const int N2 = 2 * N;

  const float* x1  = (const float*)d_in[0];
  const int*   ei1 = (const int*)d_in[1];
  const float* x2  = (const float*)d_in[2];
  const int*   ei2 = (const int*)d_in[3];
  const float* W1  = (const float*)d_in[4];
  const float* as1 = (const float*)d_in[5];
  const float* ad1 = (const float*)d_in[6];
  const float* b1  = (const float*)d_in[7];
  const float* W2  = (const float*)d_in[8];
  const float* as2 = (const float*)d_in[9];
  const float* ad2 = (const float*)d_in[10];
  const float* b2  = (const float*)d_in[11];
  float* out = (float*)d_out;
  const int* es1 = ei1, *ed1 = ei1 + E;
  const int* es2 = ei2, *ed2 = ei2 + E;

  char* p = (char*)d_ws;
  auto alloc = [&](size_t bytes) -> char* {
    char* q = p;
    p += (bytes + 255) & ~(size_t)255;
    return q;
  };
  float* h1          = (float*)alloc((size_t)N2 * 384 * 4);
  unsigned char* h1c = (unsigned char*)alloc((size_t)N2 * 384);
  __hip_bfloat16* e1b = (__hip_bfloat16*)alloc((size_t)N2 * 384 * 2);
  float* h2          = (float*)alloc((size_t)N2 * 128 * 4);
  unsigned char* h2c = (unsigned char*)alloc((size_t)N2 * 128);
  float* e2          = (float*)alloc((size_t)N2 * 128 * 4);
  __hip_bfloat16* W1t = (__hip_bfloat16*)alloc((size_t)256 * 384 * 2);
  __hip_bfloat16* W2t = (__hip_bfloat16*)alloc((size_t)384 * 128 * 2);
  float* s1v  = (float*)alloc((size_t)N2 * 3 * 4);
  float* d1v  = (float*)alloc((size_t)N2 * 3 * 4);
  float* s2v  = (float*)alloc((size_t)N2 * 4);
  float* d2v  = (float*)alloc((size_t)N2 * 4);
  float* idn  = (float*)alloc((size_t)N2 * 3 * 4);
  float* g    = (float*)alloc(512 * 4);
  int* deg     = (int*)alloc((size_t)N2 * 4);
  int* rowptr  = (int*)alloc((size_t)(N2 + 1) * 4);
  int* cursor  = (int*)alloc((size_t)N2 * 4);
  int* csr_src = (int*)alloc((size_t)2 * Etot * 4);

  const int EB = 256;
  const int egrid2 = (2 * Etot + EB - 1) / EB;
  const int gmx = (N2 + 63) / 64;

  hipMemsetAsync(g, 0, 512 * 4, stream);
  hipMemsetAsync(deg, 0, (size_t)N2 * 4, stream);
  wprep_kernel<<<(256 * 384 + 255) / 256, 256, 0, stream>>>(W1, W1t, 256, 384, 256 * 384);
  wprep_kernel<<<(384 * 128 + 255) / 256, 256, 0, stream>>>(W2, W2t, 384, 128, 384 * 128);

  deg_kernel<<<egrid2, EB, 0, stream>>>(ed1, ed2, E, Etot, N, deg);
  mfma_gemm<256, false><<<dim3(gmx, 3), 256, 0, stream>>>(x1, x2, N, W1t, h1, h1c, N2, 384);
  sd_kernel<<<(N2 * 3 + 3) / 4, 256, 0, stream>>>(h1, as1, ad1, s1v, d1v, N2 * 3, 3);
  scan_kernel<<<1, 1024, 0, stream>>>(deg, rowptr, cursor, N2);
  fill_kernel<<<egrid2, EB, 0, stream>>>(es1, ed1, es2, ed2, E, Etot, N, cursor, csr_src);

  agg1_kernel<<<N2, 192, 0, stream>>>(h1c, s1v, d1v, rowptr, csr_src, b1, e1b, idn);
  alpha_kernel<<<egrid2, EB, 0, stream>>>(s1v, d1v, idn, es1, ed1, es2, ed2, E, Etot, N, out);

  mfma_gemm<384, true><<<dim3(gmx, 1), 256, 0, stream>>>(e1b, e1b, N2, W2t, h2, h2c, N2, 128);
  sd_kernel<<<(N2 + 3) / 4, 256, 0, stream>>>(h2, as2, ad2, s2v, d2v, N2, 1);
  agg2_kernel<<<N2, 64, 0, stream>>>(h2c, s2v, d2v, rowptr, csr_src, b2, e2);

  pool_kernel<<<dim3((N + 127) / 128, 2), 128, 0, stream>>>(e2, g, N, 1.f / (float)N);
  sim_kernel<<<1, 256, 0, stream>>>(g, g + 256, out);
}

// Round 10
// 261.907 us; speedup vs baseline: 1.6594x; 1.0006x over previous
//
#include <hip/hip_runtime.h>
#include <hip/hip_bf16.h>
#include <cstdint>
#include <cstddef>

#define INDIM 256
#define NEG 0.2f

typedef __attribute__((ext_vector_type(8))) short short8v;
typedef __attribute__((ext_vector_type(4))) float f32x4;
typedef __attribute__((ext_vector_type(2))) float f32x2;

__device__ __forceinline__ unsigned short f2bf(float x) {
  __hip_bfloat16 b = __float2bfloat16(x);
  return __builtin_bit_cast(unsigned short, b);
}

// native gfx950 fp8 (OCP E4M3) converts — single VALU instruction each
__device__ __forceinline__ unsigned char f2fp8(float v) {
  int packed = __builtin_amdgcn_cvt_pk_fp8_f32(v, v, 0, false);
  return (unsigned char)(packed & 0xff);
}

__device__ __forceinline__ float lrelu(float v) { return v > 0.f ? v : NEG * v; }

// ---------------- W pre-transpose to bf16 (both weights, one dispatch) --------------------
__global__ void wprep_kernel(const float* __restrict__ W1, __hip_bfloat16* __restrict__ W1t,
                             const float* __restrict__ W2, __hip_bfloat16* __restrict__ W2t) {
  int idx = blockIdx.x * blockDim.x + threadIdx.x;
  const int T1 = 256 * 384;
  if (idx < T1) {
    int k = idx / 384, c = idx - k * 384;
    W1t[(size_t)c * 256 + k] = __float2bfloat16(W1[idx]);
  } else {
    int i = idx - T1;
    if (i < 384 * 128) {
      int k = i / 128, c = i - k * 128;
      W2t[(size_t)c * 384 + k] = __float2bfloat16(W2[i]);
    }
  }
}

// ---------------- MFMA GEMM over 2N batched rows: rows < Nsplit from A0, else A1 ----------
// tile 64x128, 4 waves (2x2), wave tile 32x64 = 2x4 fragments of 16x16, BK=32
// writes f32 Y + fp8(e4m3) Yc
template<int K, bool ABF16>
__global__ __launch_bounds__(256) void mfma_gemm(const void* __restrict__ A0,
                                                 const void* __restrict__ A1, int Nsplit,
                                                 const __hip_bfloat16* __restrict__ Wt,
                                                 float* __restrict__ Y,
                                                 unsigned char* __restrict__ Yc,
                                                 int M, int NC) {
  __shared__ short As[64][40];
  __shared__ short Bs[128][40];
  const int tid = threadIdx.x;
  const int row0 = blockIdx.x * 64;
  const int col0 = blockIdx.y * 128;
  const int l = tid & 63, w = tid >> 6;
  const int wr = w >> 1, wc = w & 1;
  const int lr = l & 15, lk = (l >> 4) * 8;

  f32x4 acc[2][4];
#pragma unroll
  for (int m = 0; m < 2; ++m)
#pragma unroll
    for (int n = 0; n < 4; ++n) acc[m][n] = {0.f, 0.f, 0.f, 0.f};

  for (int k0 = 0; k0 < K; k0 += 32) {
    __syncthreads();
    {  // stage A: 64 rows x 32 k
      int r = tid >> 2, kq = (tid & 3) * 8;
      int gr = row0 + r;
      short8v av = {0, 0, 0, 0, 0, 0, 0, 0};
      if (gr < M) {
        const void* Ab = (gr < Nsplit) ? A0 : A1;
        int lrow = (gr < Nsplit) ? gr : gr - Nsplit;
        if (ABF16) {
          av = *(const short8v*)((const short*)Ab + (size_t)lrow * K + k0 + kq);
        } else {
          const float* ap = (const float*)Ab + (size_t)lrow * K + k0 + kq;
          float4 u = *(const float4*)ap;
          float4 v = *(const float4*)(ap + 4);
          av = short8v{(short)f2bf(u.x), (short)f2bf(u.y), (short)f2bf(u.z), (short)f2bf(u.w),
                       (short)f2bf(v.x), (short)f2bf(v.y), (short)f2bf(v.z), (short)f2bf(v.w)};
        }
      }
      *(short8v*)&As[r][kq] = av;
    }
    {  // stage B: 128 cols x 32 k (Wt row-major [NC][K])
      int c = tid >> 1, kq = (tid & 1) * 8;
      const short* wp = (const short*)Wt + (size_t)(col0 + c) * K + k0 + kq;
      *(short8v*)&Bs[c][kq]      = *(const short8v*)wp;
      *(short8v*)&Bs[c][kq + 16] = *(const short8v*)(wp + 16);
    }
    __syncthreads();
    short8v a[2], b[4];
#pragma unroll
    for (int m = 0; m < 2; ++m) a[m] = *(short8v*)&As[wr * 32 + m * 16 + lr][lk];
#pragma unroll
    for (int n = 0; n < 4; ++n) b[n] = *(short8v*)&Bs[wc * 64 + n * 16 + lr][lk];
#pragma unroll
    for (int m = 0; m < 2; ++m)
#pragma unroll
      for (int n = 0; n < 4; ++n)
        acc[m][n] = __builtin_amdgcn_mfma_f32_16x16x32_bf16(a[m], b[n], acc[m][n], 0, 0, 0);
  }
  // epilogue: C/D layout col=lane&15, row=(lane>>4)*4+q
#pragma unroll
  for (int m = 0; m < 2; ++m) {
    int rbase = row0 + wr * 32 + m * 16 + (l >> 4) * 4;
#pragma unroll
    for (int n = 0; n < 4; ++n) {
      int col = col0 + wc * 64 + n * 16 + lr;
#pragma unroll
      for (int q = 0; q < 4; ++q) {
        int row = rbase + q;
        if (row < M) {
          float v = acc[m][n][q];
          Y[(size_t)row * NC + col] = v;
          Yc[(size_t)row * NC + col] = f2fp8(v);
        }
      }
    }
  }
}

// ---------------- attention dots: one wave per (node2,head); node2 in [0,2N) ----------------
__global__ __launch_bounds__(256) void sd_kernel(const float* __restrict__ H,
                                                 const float* __restrict__ As,
                                                 const float* __restrict__ Ad,
                                                 float* __restrict__ S, float* __restrict__ D,
                                                 int NB, int NH) {
  int w = blockIdx.x * 4 + (threadIdx.x >> 6);
  if (w >= NB) return;
  int lane = threadIdx.x & 63;
  int h = w % NH;
  float2 hv = reinterpret_cast<const float2*>(H + (size_t)w * 128)[lane];
  float2 as = reinterpret_cast<const float2*>(As + h * 128)[lane];
  float2 ad = reinterpret_cast<const float2*>(Ad + h * 128)[lane];
  float vs = hv.x * as.x + hv.y * as.y;
  float vd = hv.x * ad.x + hv.y * ad.y;
#pragma unroll
  for (int o = 32; o; o >>= 1) { vs += __shfl_down(vs, o); vd += __shfl_down(vd, o); }
  if (lane == 0) { S[w] = vs; D[w] = vd; }
}

// ---------------- CSR build over 2N virtual nodes (both branches) ----------------
__global__ void deg_kernel(const int* __restrict__ ed1, const int* __restrict__ ed2,
                           int E, int Etot, int N, int* __restrict__ deg) {
  int idx = blockIdx.x * blockDim.x + threadIdx.x;
  if (idx >= 2 * Etot) return;
  int br = idx >= Etot;
  int el = idx - br * Etot;
  const int* ed = br ? ed2 : ed1;
  int dn = ((el < E) ? ed[el] : (el - E)) + br * N;
  atomicAdd(&deg[dn], 1);
}

// scan: thread-serial 20 elements + one block scan (n <= 20480)
__global__ __launch_bounds__(1024) void scan_kernel(const int* __restrict__ deg,
                                                    int* __restrict__ rowptr,
                                                    int* __restrict__ cursor, int n) {
  __shared__ int wsum[16];
  int t = threadIdx.x, lane = t & 63, wid = t >> 6;
  int start = t * 20;
  int v[20];
  int s = 0;
#pragma unroll
  for (int k = 0; k < 20; ++k) {
    int i = start + k;
    int d = (i < n) ? deg[i] : 0;
    s += d;
    v[k] = s;                    // inclusive local prefix
  }
  int x = s;
#pragma unroll
  for (int o = 1; o < 64; o <<= 1) {
    int tm = __shfl_up(x, o);
    if (lane >= o) x += tm;
  }
  if (lane == 63) wsum[wid] = x;
  __syncthreads();
  if (wid == 0) {
    int wv = (lane < 16) ? wsum[lane] : 0;
#pragma unroll
    for (int o = 1; o < 16; o <<= 1) {
      int tm = __shfl_up(wv, o);
      if (lane >= o) wv += tm;
    }
    if (lane < 16) wsum[lane] = wv;
  }
  __syncthreads();
  int excl = (x - s) + (wid ? wsum[wid - 1] : 0);
  if (t == 0) rowptr[0] = 0;
#pragma unroll
  for (int k = 0; k < 20; ++k) {
    int i = start + k;
    if (i < n) {
      rowptr[i + 1] = excl + v[k];
      cursor[i] = excl + (k ? v[k - 1] : 0);
    }
  }
}

// fill: CSR fill + per-edge exp weights (3 heads) + eid, all edge-parallel
__global__ void fill_kernel(const int* __restrict__ es1, const int* __restrict__ ed1,
                            const int* __restrict__ es2, const int* __restrict__ ed2,
                            const float* __restrict__ S1, const float* __restrict__ D1,
                            int E, int Etot, int N, int* __restrict__ cursor,
                            int* __restrict__ csr_src, int* __restrict__ csr_dst,
                            float4* __restrict__ w4) {
  int idx = blockIdx.x * blockDim.x + threadIdx.x;
  if (idx >= 2 * Etot) return;
  int br = idx >= Etot;
  int el = idx - br * Etot;
  const int* es = br ? es2 : es1;
  const int* ed = br ? ed2 : ed1;
  int sn, dn;
  if (el < E) { sn = es[el]; dn = ed[el]; } else { sn = dn = el - E; }
  sn += br * N; dn += br * N;
  int pos = atomicAdd(&cursor[dn], 1);
  csr_src[pos] = sn;
  csr_dst[pos] = dn;
  float4 w;
  w.x = __expf(lrelu(S1[sn * 3]     + D1[dn * 3]));
  w.y = __expf(lrelu(S1[sn * 3 + 1] + D1[dn * 3 + 1]));
  w.z = __expf(lrelu(S1[sn * 3 + 2] + D1[dn * 3 + 2]));
  w.w = __int_as_float(br * Etot + el);
  w4[pos] = w;
}

// w2prep: per-CSR-position layer-2 exp weights, edge-parallel
__global__ void w2prep_kernel(const int* __restrict__ csr_src, const int* __restrict__ csr_dst,
                              const float* __restrict__ S2, const float* __restrict__ D2,
                              int total, float* __restrict__ w2) {
  int pos = blockIdx.x * blockDim.x + threadIdx.x;
  if (pos >= total) return;
  w2[pos] = __expf(lrelu(S2[csr_src[pos]] + D2[csr_dst[pos]]));
}

// ---------------- agg1: single-pass aggregate + denom + alpha tail, dword fp8 gathers -----
// 192 threads = 2 edge-halves x 96 col-groups (4 cols each).
__global__ __launch_bounds__(192) void agg1_kernel(const unsigned char* __restrict__ h1c,
                                                   const int* __restrict__ rowptr,
                                                   const int* __restrict__ csr_src,
                                                   const float4* __restrict__ w4,
                                                   const float* __restrict__ b1,
                                                   __hip_bfloat16* __restrict__ e1b,
                                                   float* __restrict__ out) {
  __shared__ int lsrc[192];
  __shared__ float la[3][192];
  __shared__ float red[3][3];
  __shared__ float inv_s[3];
  const unsigned int* H4 = reinterpret_cast<const unsigned int*>(h1c);
  int n = blockIdx.x;
  int j = threadIdx.x;
  int wid = j >> 6, lane = j & 63;
  int half = (j >= 96) ? 1 : 0;
  int t = j - half * 96;         // col group: cols 4t..4t+3
  int head = t >> 5;             // 4t/128
  int p0 = rowptr[n], p1 = rowptr[n + 1];

  float dp0 = 0.f, dp1 = 0.f, dp2 = 0.f;
  float acc[4] = {0.f, 0.f, 0.f, 0.f};
  for (int base = p0; base < p1; base += 192) {
    int cnt = min(192, p1 - base);
    __syncthreads();
    if (j < cnt) {
      lsrc[j] = csr_src[base + j];
      float4 w = w4[base + j];
      la[0][j] = w.x; la[1][j] = w.y; la[2][j] = w.z;
      dp0 += w.x; dp1 += w.y; dp2 += w.z;
    }
    __syncthreads();
    int i = half;
    for (; i + 14 < cnt; i += 16) {
      unsigned int hv[8];
      float av[8];
#pragma unroll
      for (int u = 0; u < 8; ++u) {
        int e = i + 2 * u;
        int sn = lsrc[e];
        av[u] = la[head][e];
        hv[u] = H4[(size_t)sn * 96 + t];
      }
#pragma unroll
      for (int u = 0; u < 8; ++u) {
        f32x2 f0 = __builtin_amdgcn_cvt_pk_f32_fp8((int)hv[u], false);
        f32x2 f1 = __builtin_amdgcn_cvt_pk_f32_fp8((int)hv[u], true);
        acc[0] = fmaf(av[u], f0.x, acc[0]);
        acc[1] = fmaf(av[u], f0.y, acc[1]);
        acc[2] = fmaf(av[u], f1.x, acc[2]);
        acc[3] = fmaf(av[u], f1.y, acc[3]);
      }
    }
    for (; i < cnt; i += 2) {
      int sn = lsrc[i];
      float a = la[head][i];
      unsigned int hv = H4[(size_t)sn * 96 + t];
      f32x2 f0 = __builtin_amdgcn_cvt_pk_f32_fp8((int)hv, false);
      f32x2 f1 = __builtin_amdgcn_cvt_pk_f32_fp8((int)hv, true);
      acc[0] = fmaf(a, f0.x, acc[0]);
      acc[1] = fmaf(a, f0.y, acc[1]);
      acc[2] = fmaf(a, f1.x, acc[2]);
      acc[3] = fmaf(a, f1.y, acc[3]);
    }
  }
  // cross-half reduce (reuse la storage)
  __syncthreads();
  float* racc = &la[0][0];       // 96*4 floats
  if (half == 1) {
    racc[t * 4 + 0] = acc[0]; racc[t * 4 + 1] = acc[1];
    racc[t * 4 + 2] = acc[2]; racc[t * 4 + 3] = acc[3];
  }
  __syncthreads();
  if (half == 0) {
    acc[0] += racc[t * 4 + 0]; acc[1] += racc[t * 4 + 1];
    acc[2] += racc[t * 4 + 2]; acc[3] += racc[t * 4 + 3];
  }
  // block-reduce the exp partials
#pragma unroll
  for (int o = 32; o; o >>= 1) {
    dp0 += __shfl_down(dp0, o); dp1 += __shfl_down(dp1, o); dp2 += __shfl_down(dp2, o);
  }
  if (lane == 0) { red[wid][0] = dp0; red[wid][1] = dp1; red[wid][2] = dp2; }
  __syncthreads();
  if (j == 0) {
    inv_s[0] = 1.f / (red[0][0] + red[1][0] + red[2][0]);
    inv_s[1] = 1.f / (red[0][1] + red[1][1] + red[2][1]);
    inv_s[2] = 1.f / (red[0][2] + red[1][2] + red[2][2]);
  }
  __syncthreads();
  float i0 = inv_s[0], i1 = inv_s[1], i2 = inv_s[2];
  if (half == 0) {
    float inv = inv_s[head];
    float4 bb = *reinterpret_cast<const float4*>(b1 + 4 * t);
    float v0 = acc[0] * inv + bb.x;
    float v1 = acc[1] * inv + bb.y;
    float v2 = acc[2] * inv + bb.z;
    float v3 = acc[3] * inv + bb.w;
    v0 = v0 > 0.f ? v0 : 0.f; v1 = v1 > 0.f ? v1 : 0.f;
    v2 = v2 > 0.f ? v2 : 0.f; v3 = v3 > 0.f ? v3 : 0.f;
    uint2 st;
    st.x = (unsigned int)f2bf(v0) | ((unsigned int)f2bf(v1) << 16);
    st.y = (unsigned int)f2bf(v2) | ((unsigned int)f2bf(v3) << 16);
    *reinterpret_cast<uint2*>(reinterpret_cast<unsigned short*>(e1b) + (size_t)n * 384 + 4 * t) = st;
  }
  // alpha tail: coalesced w4 re-read (L2-hot), scattered fire-and-forget writes
  for (int p = p0 + j; p < p1; p += 192) {
    float4 w = w4[p];
    int eid = __float_as_int(w.w);
    float* ao = out + 1 + (size_t)eid * 3;
    ao[0] = w.x * i0;
    ao[1] = w.y * i1;
    ao[2] = w.z * i2;
  }
}

// ---------------- agg2: single-pass, 1 wave = 2 edge-halves x 32 col-groups ---------------
__global__ __launch_bounds__(64) void agg2_kernel(const unsigned char* __restrict__ h2c,
                                                  const float* __restrict__ w2,
                                                  const int* __restrict__ rowptr,
                                                  const int* __restrict__ csr_src,
                                                  const float* __restrict__ b2,
                                                  float* __restrict__ e2out) {
  __shared__ int lsrc[256];
  __shared__ float la[256];
  const unsigned int* H4 = reinterpret_cast<const unsigned int*>(h2c);
  int n = blockIdx.x;
  int lane = threadIdx.x;
  int half = lane >> 5, t = lane & 31;   // cols 4t..4t+3
  int p0 = rowptr[n], p1 = rowptr[n + 1];

  float dpart = 0.f;
  float acc[4] = {0.f, 0.f, 0.f, 0.f};
  for (int base = p0; base < p1; base += 256) {
    int cnt = min(256, p1 - base);
    __syncthreads();
    for (int i = lane; i < cnt; i += 64) {
      lsrc[i] = csr_src[base + i];
      float ex = w2[base + i];
      la[i] = ex;
      dpart += ex;
    }
    __syncthreads();
    int i = half;
    for (; i + 14 < cnt; i += 16) {
      unsigned int hv[8];
      float av[8];
#pragma unroll
      for (int u = 0; u < 8; ++u) {
        int e = i + 2 * u;
        int sn = lsrc[e];
        av[u] = la[e];
        hv[u] = H4[(size_t)sn * 32 + t];
      }
#pragma unroll
      for (int u = 0; u < 8; ++u) {
        f32x2 f0 = __builtin_amdgcn_cvt_pk_f32_fp8((int)hv[u], false);
        f32x2 f1 = __builtin_amdgcn_cvt_pk_f32_fp8((int)hv[u], true);
        acc[0] = fmaf(av[u], f0.x, acc[0]);
        acc[1] = fmaf(av[u], f0.y, acc[1]);
        acc[2] = fmaf(av[u], f1.x, acc[2]);
        acc[3] = fmaf(av[u], f1.y, acc[3]);
      }
    }
    for (; i < cnt; i += 2) {
      int sn = lsrc[i];
      float a = la[i];
      unsigned int hv = H4[(size_t)sn * 32 + t];
      f32x2 f0 = __builtin_amdgcn_cvt_pk_f32_fp8((int)hv, false);
      f32x2 f1 = __builtin_amdgcn_cvt_pk_f32_fp8((int)hv, true);
      acc[0] = fmaf(a, f0.x, acc[0]);
      acc[1] = fmaf(a, f0.y, acc[1]);
      acc[2] = fmaf(a, f1.x, acc[2]);
      acc[3] = fmaf(a, f1.y, acc[3]);
    }
  }
  // cross-half reduce via shuffle (lane ^ 32)
#pragma unroll
  for (int k = 0; k < 4; ++k) acc[k] += __shfl_xor(acc[k], 32);
#pragma unroll
  for (int o = 32; o; o >>= 1) dpart += __shfl_down(dpart, o);
  float invden = 1.f / __shfl(dpart, 0);
  if (half == 0) {
    float4 bb = *reinterpret_cast<const float4*>(b2 + 4 * t);
    float4 ov;
    ov.x = acc[0] * invden + bb.x;
    ov.y = acc[1] * invden + bb.y;
    ov.z = acc[2] * invden + bb.z;
    ov.w = acc[3] * invden + bb.w;
    *reinterpret_cast<float4*>(e2out + (size_t)n * 128 + 4 * t) = ov;
  }
}

// ---------------- pooling: node_attn == 1 exactly; both halves = column mean --------------
__global__ __launch_bounds__(128) void pool_kernel(const float* __restrict__ e2,
                                                   float* __restrict__ g, int N, float invN) {
  int c = threadIdx.x;
  int br = blockIdx.y;
  int r0 = br * N + blockIdx.x * 128;
  int r1 = min(r0 + 128, br * N + N);
  float acc = 0.f;
  for (int n = r0; n < r1; ++n) acc += e2[(size_t)n * 128 + c];
  acc *= invN;
  float* gb = g + (size_t)br * 256;
  atomicAdd(&gb[c], acc);
  atomicAdd(&gb[128 + c], acc);
}

__global__ __launch_bounds__(256) void sim_kernel(const float* __restrict__ g1,
                                                  const float* __restrict__ g2,
                                                  float* __restrict__ out) {
  int t = threadIdx.x;
  float a = g1[t], b = g2[t];
  __shared__ float sd[256], s1[256], s2[256];
  sd[t] = a * b; s1[t] = a * a; s2[t] = b * b;
  __syncthreads();
  for (int ofs = 128; ofs; ofs >>= 1) {
    if (t < ofs) { sd[t] += sd[t + ofs]; s1[t] += s1[t + ofs]; s2[t] += s2[t + ofs]; }
    __syncthreads();
  }
  if (t == 0) {
    float n1 = fmaxf(sqrtf(s1[0]), 1e-8f);
    float n2 = fmaxf(sqrtf(s2[0]), 1e-8f);
    out[0] = sd[0] / (n1 * n2);
  }
}

// ---------------- host ----------------
extern "C" void kernel_launch(void* const* d_in, const int* in_sizes, int n_in,
                              void* d_out, int out_size, void* d_ws, size_t ws_size,
                              hipStream_t stream) {
  const int N = in_sizes[0] / INDIM;
  const int E = in_sizes[1] / 2;
  const int Etot = E + N;
  const int N2 = 2 * N;

  const float* x1  = (const float*)d_in[0];
  const int*   ei1 = (const int*)d_in[1];
  const float* x2  = (const float*)d_in[2];
  const int*   ei2 = (const int*)d_in[3];
  const float* W1  = (const float*)d_in[4];
  const float* as1 = (const float*)d_in[5];
  const float* ad1 = (const float*)d_in[6];
  const float* b1  = (const float*)d_in[7];
  const float* W2  = (const float*)d_in[8];
  const float* as2 = (const float*)d_in[9];
  const float* ad2 = (const float*)d_in[10];
  const float* b2  = (const float*)d_in[11];
  float* out = (float*)d_out;
  const int* es1 = ei1, *ed1 = ei1 + E;
  const int* es2 = ei2, *ed2 = ei2 + E;

  char* p = (char*)d_ws;
  auto alloc = [&](size_t bytes) -> char* {
    char* q = p;
    p += (bytes + 255) & ~(size_t)255;
    return q;
  };
  float* h1          = (float*)alloc((size_t)N2 * 384 * 4);
  unsigned char* h1c = (unsigned char*)alloc((size_t)N2 * 384);
  __hip_bfloat16* e1b = (__hip_bfloat16*)alloc((size_t)N2 * 384 * 2);
  float* h2          = (float*)alloc((size_t)N2 * 128 * 4);
  unsigned char* h2c = (unsigned char*)alloc((size_t)N2 * 128);
  float* e2          = (float*)alloc((size_t)N2 * 128 * 4);
  __hip_bfloat16* W1t = (__hip_bfloat16*)alloc((size_t)256 * 384 * 2);
  __hip_bfloat16* W2t = (__hip_bfloat16*)alloc((size_t)384 * 128 * 2);
  float* s1v  = (float*)alloc((size_t)N2 * 3 * 4);
  float* d1v  = (float*)alloc((size_t)N2 * 3 * 4);
  float* s2v  = (float*)alloc((size_t)N2 * 4);
  float* d2v  = (float*)alloc((size_t)N2 * 4);
  float* g    = (float*)alloc(512 * 4);
  int* deg     = (int*)alloc((size_t)N2 * 4);
  int* rowptr  = (int*)alloc((size_t)(N2 + 1) * 4);
  int* cursor  = (int*)alloc((size_t)N2 * 4);
  int* csr_src = (int*)alloc((size_t)2 * Etot * 4);
  int* csr_dst = (int*)alloc((size_t)2 * Etot * 4);
  float4* w4   = (float4*)alloc((size_t)2 * Etot * 16);
  float* w2    = (float*)alloc((size_t)2 * Etot * 4);

  const int EB = 256;
  const int egrid2 = (2 * Etot + EB - 1) / EB;
  const int gmx = (N2 + 63) / 64;

  hipMemsetAsync(g, 0, 512 * 4, stream);
  hipMemsetAsync(deg, 0, (size_t)N2 * 4, stream);
  wprep_kernel<<<(256 * 384 + 384 * 128 + 255) / 256, 256, 0, stream>>>(W1, W1t, W2, W2t);

  deg_kernel<<<egrid2, EB, 0, stream>>>(ed1, ed2, E, Etot, N, deg);
  mfma_gemm<256, false><<<dim3(gmx, 3), 256, 0, stream>>>(x1, x2, N, W1t, h1, h1c, N2, 384);
  sd_kernel<<<(N2 * 3 + 3) / 4, 256, 0, stream>>>(h1, as1, ad1, s1v, d1v, N2 * 3, 3);
  scan_kernel<<<1, 1024, 0, stream>>>(deg, rowptr, cursor, N2);
  fill_kernel<<<egrid2, EB, 0, stream>>>(es1, ed1, es2, ed2, s1v, d1v, E, Etot, N,
                                         cursor, csr_src, csr_dst, w4);

  agg1_kernel<<<N2, 192, 0, stream>>>(h1c, rowptr, csr_src, w4, b1, e1b, out);

  mfma_gemm<384, true><<<dim3(gmx, 1), 256, 0, stream>>>(e1b, e1b, N2, W2t, h2, h2c, N2, 128);
  sd_kernel<<<(N2 + 3) / 4, 256, 0, stream>>>(h2, as2, ad2, s2v, d2v, N2, 1);
  w2prep_kernel<<<egrid2, EB, 0, stream>>>(csr_src, csr_dst, s2v, d2v, 2 * Etot, w2);
  agg2_kernel<<<N2, 64, 0, stream>>>(h2c, w2, rowptr, csr_src, b2, e2);

  pool_kernel<<<dim3((N + 127) / 128, 2), 128, 0, stream>>>(e2, g, N, 1.f / (float)N);
  sim_kernel<<<1, 256, 0, stream>>>(g, g + 256, out);
}

// Round 11
// 248.910 us; speedup vs baseline: 1.7461x; 1.0522x over previous
//
#include <hip/hip_runtime.h>
#include <hip/hip_bf16.h>
#include <cstdint>
#include <cstddef>

#define INDIM 256
#define NEG 0.2f

typedef __attribute__((ext_vector_type(8))) short short8v;
typedef __attribute__((ext_vector_type(4))) float f32x4;
typedef __attribute__((ext_vector_type(2))) float f32x2;

__device__ __forceinline__ unsigned short f2bf(float x) {
  __hip_bfloat16 b = __float2bfloat16(x);
  return __builtin_bit_cast(unsigned short, b);
}

// native gfx950 fp8 (OCP E4M3) converts — single VALU instruction each
__device__ __forceinline__ unsigned char f2fp8(float v) {
  int packed = __builtin_amdgcn_cvt_pk_fp8_f32(v, v, 0, false);
  return (unsigned char)(packed & 0xff);
}

__device__ __forceinline__ float lrelu(float v) { return v > 0.f ? v : NEG * v; }

// ---------------- W pre-transpose to bf16 (both weights, one dispatch) --------------------
__global__ void wprep_kernel(const float* __restrict__ W1, __hip_bfloat16* __restrict__ W1t,
                             const float* __restrict__ W2, __hip_bfloat16* __restrict__ W2t) {
  int idx = blockIdx.x * blockDim.x + threadIdx.x;
  const int T1 = 256 * 384;
  if (idx < T1) {
    int k = idx / 384, c = idx - k * 384;
    W1t[(size_t)c * 256 + k] = __float2bfloat16(W1[idx]);
  } else {
    int i = idx - T1;
    if (i < 384 * 128) {
      int k = i / 128, c = i - k * 128;
      W2t[(size_t)c * 384 + k] = __float2bfloat16(W2[i]);
    }
  }
}

// ---------------- MFMA GEMM over 2N batched rows + FUSED attention dots ------------------
// tile 64x128, 4 waves (2x2), wave tile 32x64 = 2x4 fragments of 16x16, BK=32
// writes fp8(e4m3) Yc and per-row S,D dots (s = h.att_s, d = h.att_d) for head blockIdx.y.
template<int K, bool ABF16, int NH>
__global__ __launch_bounds__(256) void mfma_gemm(const void* __restrict__ A0,
                                                 const void* __restrict__ A1, int Nsplit,
                                                 const __hip_bfloat16* __restrict__ Wt,
                                                 const float* __restrict__ att_s,
                                                 const float* __restrict__ att_d,
                                                 unsigned char* __restrict__ Yc,
                                                 float* __restrict__ So,
                                                 float* __restrict__ Do,
                                                 int M, int NC) {
  __shared__ short As[64][40];
  __shared__ short Bs[128][40];
  __shared__ float sred[2][64];
  const int tid = threadIdx.x;
  const int row0 = blockIdx.x * 64;
  const int col0 = blockIdx.y * 128;
  const int l = tid & 63, w = tid >> 6;
  const int wr = w >> 1, wc = w & 1;
  const int lr = l & 15, lk = (l >> 4) * 8;

  f32x4 acc[2][4];
#pragma unroll
  for (int m = 0; m < 2; ++m)
#pragma unroll
    for (int n = 0; n < 4; ++n) acc[m][n] = {0.f, 0.f, 0.f, 0.f};

  for (int k0 = 0; k0 < K; k0 += 32) {
    __syncthreads();
    {  // stage A: 64 rows x 32 k
      int r = tid >> 2, kq = (tid & 3) * 8;
      int gr = row0 + r;
      short8v av = {0, 0, 0, 0, 0, 0, 0, 0};
      if (gr < M) {
        const void* Ab = (gr < Nsplit) ? A0 : A1;
        int lrow = (gr < Nsplit) ? gr : gr - Nsplit;
        if (ABF16) {
          av = *(const short8v*)((const short*)Ab + (size_t)lrow * K + k0 + kq);
        } else {
          const float* ap = (const float*)Ab + (size_t)lrow * K + k0 + kq;
          float4 u = *(const float4*)ap;
          float4 v = *(const float4*)(ap + 4);
          av = short8v{(short)f2bf(u.x), (short)f2bf(u.y), (short)f2bf(u.z), (short)f2bf(u.w),
                       (short)f2bf(v.x), (short)f2bf(v.y), (short)f2bf(v.z), (short)f2bf(v.w)};
        }
      }
      *(short8v*)&As[r][kq] = av;
    }
    {  // stage B: 128 cols x 32 k (Wt row-major [NC][K])
      int c = tid >> 1, kq = (tid & 1) * 8;
      const short* wp = (const short*)Wt + (size_t)(col0 + c) * K + k0 + kq;
      *(short8v*)&Bs[c][kq]      = *(const short8v*)wp;
      *(short8v*)&Bs[c][kq + 16] = *(const short8v*)(wp + 16);
    }
    __syncthreads();
    short8v a[2], b[4];
#pragma unroll
    for (int m = 0; m < 2; ++m) a[m] = *(short8v*)&As[wr * 32 + m * 16 + lr][lk];
#pragma unroll
    for (int n = 0; n < 4; ++n) b[n] = *(short8v*)&Bs[wc * 64 + n * 16 + lr][lk];
#pragma unroll
    for (int m = 0; m < 2; ++m)
#pragma unroll
      for (int n = 0; n < 4; ++n)
        acc[m][n] = __builtin_amdgcn_mfma_f32_16x16x32_bf16(a[m], b[n], acc[m][n], 0, 0, 0);
  }
  // epilogue: C/D layout col=lane&15, row=(lane>>4)*4+q — fp8 store
#pragma unroll
  for (int m = 0; m < 2; ++m) {
    int rbase = row0 + wr * 32 + m * 16 + (l >> 4) * 4;
#pragma unroll
    for (int n = 0; n < 4; ++n) {
      int col = col0 + wc * 64 + n * 16 + lr;
#pragma unroll
      for (int q = 0; q < 4; ++q) {
        int row = rbase + q;
        if (row < M) Yc[(size_t)row * NC + col] = f2fp8(acc[m][n][q]);
      }
    }
  }
  // fused attention dots
  float asv[4], adv[4];
#pragma unroll
  for (int n = 0; n < 4; ++n) {
    int col = col0 + wc * 64 + n * 16 + lr;
    asv[n] = att_s[col];
    adv[n] = att_d[col];
  }
  float ps[2][4], pd[2][4];
#pragma unroll
  for (int m = 0; m < 2; ++m)
#pragma unroll
    for (int q = 0; q < 4; ++q) {
      float s = 0.f, d = 0.f;
#pragma unroll
      for (int n = 0; n < 4; ++n) {
        s = fmaf(acc[m][n][q], asv[n], s);
        d = fmaf(acc[m][n][q], adv[n], d);
      }
      ps[m][q] = s; pd[m][q] = d;
    }
#pragma unroll
  for (int o = 1; o < 16; o <<= 1) {
#pragma unroll
    for (int m = 0; m < 2; ++m)
#pragma unroll
      for (int q = 0; q < 4; ++q) {
        ps[m][q] += __shfl_xor(ps[m][q], o);
        pd[m][q] += __shfl_xor(pd[m][q], o);
      }
  }
  __syncthreads();
  if (wc == 1 && lr == 0) {
#pragma unroll
    for (int m = 0; m < 2; ++m)
#pragma unroll
      for (int q = 0; q < 4; ++q) {
        int rl = wr * 32 + m * 16 + (l >> 4) * 4 + q;
        sred[0][rl] = ps[m][q];
        sred[1][rl] = pd[m][q];
      }
  }
  __syncthreads();
  if (wc == 0 && lr == 0) {
#pragma unroll
    for (int m = 0; m < 2; ++m)
#pragma unroll
      for (int q = 0; q < 4; ++q) {
        int rl = wr * 32 + m * 16 + (l >> 4) * 4 + q;
        int row = row0 + rl;
        if (row < M) {
          So[(size_t)row * NH + blockIdx.y] = ps[m][q] + sred[0][rl];
          Do[(size_t)row * NH + blockIdx.y] = pd[m][q] + sred[1][rl];
        }
      }
  }
}

// ---------------- CSR build over 2N virtual nodes (both branches) ----------------
__global__ void deg_kernel(const int* __restrict__ ed1, const int* __restrict__ ed2,
                           int E, int Etot, int N, int* __restrict__ deg) {
  int idx = blockIdx.x * blockDim.x + threadIdx.x;
  if (idx >= 2 * Etot) return;
  int br = idx >= Etot;
  int el = idx - br * Etot;
  const int* ed = br ? ed2 : ed1;
  int dn = ((el < E) ? ed[el] : (el - E)) + br * N;
  atomicAdd(&deg[dn], 1);
}

// scan: thread-serial 20 elements + one block scan (n <= 20480)
__global__ __launch_bounds__(1024) void scan_kernel(const int* __restrict__ deg,
                                                    int* __restrict__ rowptr,
                                                    int* __restrict__ cursor, int n) {
  __shared__ int wsum[16];
  int t = threadIdx.x, lane = t & 63, wid = t >> 6;
  int start = t * 20;
  int v[20];
  int s = 0;
#pragma unroll
  for (int k = 0; k < 20; ++k) {
    int i = start + k;
    int d = (i < n) ? deg[i] : 0;
    s += d;
    v[k] = s;                    // inclusive local prefix
  }
  int x = s;
#pragma unroll
  for (int o = 1; o < 64; o <<= 1) {
    int tm = __shfl_up(x, o);
    if (lane >= o) x += tm;
  }
  if (lane == 63) wsum[wid] = x;
  __syncthreads();
  if (wid == 0) {
    int wv = (lane < 16) ? wsum[lane] : 0;
#pragma unroll
    for (int o = 1; o < 16; o <<= 1) {
      int tm = __shfl_up(wv, o);
      if (lane >= o) wv += tm;
    }
    if (lane < 16) wsum[lane] = wv;
  }
  __syncthreads();
  int excl = (x - s) + (wid ? wsum[wid - 1] : 0);
  if (t == 0) rowptr[0] = 0;
#pragma unroll
  for (int k = 0; k < 20; ++k) {
    int i = start + k;
    if (i < n) {
      rowptr[i + 1] = excl + v[k];
      cursor[i] = excl + (k ? v[k - 1] : 0);
    }
  }
}

// fill: CSR fill + per-edge exp weights (3 heads) + eid, all edge-parallel
__global__ void fill_kernel(const int* __restrict__ es1, const int* __restrict__ ed1,
                            const int* __restrict__ es2, const int* __restrict__ ed2,
                            const float* __restrict__ S1, const float* __restrict__ D1,
                            int E, int Etot, int N, int* __restrict__ cursor,
                            int* __restrict__ csr_src, int* __restrict__ csr_dst,
                            float4* __restrict__ w4) {
  int idx = blockIdx.x * blockDim.x + threadIdx.x;
  if (idx >= 2 * Etot) return;
  int br = idx >= Etot;
  int el = idx - br * Etot;
  const int* es = br ? es2 : es1;
  const int* ed = br ? ed2 : ed1;
  int sn, dn;
  if (el < E) { sn = es[el]; dn = ed[el]; } else { sn = dn = el - E; }
  sn += br * N; dn += br * N;
  int pos = atomicAdd(&cursor[dn], 1);
  csr_src[pos] = sn;
  csr_dst[pos] = dn;
  float4 w;
  w.x = __expf(lrelu(S1[sn * 3]     + D1[dn * 3]));
  w.y = __expf(lrelu(S1[sn * 3 + 1] + D1[dn * 3 + 1]));
  w.z = __expf(lrelu(S1[sn * 3 + 2] + D1[dn * 3 + 2]));
  w.w = __int_as_float(br * Etot + el);
  w4[pos] = w;
}

// w2prep: per-CSR-position layer-2 exp weights, edge-parallel
__global__ void w2prep_kernel(const int* __restrict__ csr_src, const int* __restrict__ csr_dst,
                              const float* __restrict__ S2, const float* __restrict__ D2,
                              int total, float* __restrict__ w2) {
  int pos = blockIdx.x * blockDim.x + threadIdx.x;
  if (pos >= total) return;
  w2[pos] = __expf(lrelu(S2[csr_src[pos]] + D2[csr_dst[pos]]));
}

// ---------------- agg1: single-pass aggregate + denom + alpha tail, dword fp8 gathers -----
// 192 threads = 2 edge-halves x 96 col-groups (4 cols each).
__global__ __launch_bounds__(192) void agg1_kernel(const unsigned char* __restrict__ h1c,
                                                   const int* __restrict__ rowptr,
                                                   const int* __restrict__ csr_src,
                                                   const float4* __restrict__ w4,
                                                   const float* __restrict__ b1,
                                                   __hip_bfloat16* __restrict__ e1b,
                                                   float* __restrict__ out) {
  __shared__ int lsrc[192];
  __shared__ float la[3][192];
  __shared__ float red[3][3];
  __shared__ float inv_s[3];
  const unsigned int* H4 = reinterpret_cast<const unsigned int*>(h1c);
  int n = blockIdx.x;
  int j = threadIdx.x;
  int wid = j >> 6, lane = j & 63;
  int half = (j >= 96) ? 1 : 0;
  int t = j - half * 96;         // col group: cols 4t..4t+3
  int head = t >> 5;             // 4t/128
  int p0 = rowptr[n], p1 = rowptr[n + 1];

  float dp0 = 0.f, dp1 = 0.f, dp2 = 0.f;
  float acc[4] = {0.f, 0.f, 0.f, 0.f};
  for (int base = p0; base < p1; base += 192) {
    int cnt = min(192, p1 - base);
    __syncthreads();
    if (j < cnt) {
      lsrc[j] = csr_src[base + j];
      float4 w = w4[base + j];
      la[0][j] = w.x; la[1][j] = w.y; la[2][j] = w.z;
      dp0 += w.x; dp1 += w.y; dp2 += w.z;
    }
    __syncthreads();
    int i = half;
    for (; i + 14 < cnt; i += 16) {
      unsigned int hv[8];
      float av[8];
#pragma unroll
      for (int u = 0; u < 8; ++u) {
        int e = i + 2 * u;
        int sn = lsrc[e];
        av[u] = la[head][e];
        hv[u] = H4[(size_t)sn * 96 + t];
      }
#pragma unroll
      for (int u = 0; u < 8; ++u) {
        f32x2 f0 = __builtin_amdgcn_cvt_pk_f32_fp8((int)hv[u], false);
        f32x2 f1 = __builtin_amdgcn_cvt_pk_f32_fp8((int)hv[u], true);
        acc[0] = fmaf(av[u], f0.x, acc[0]);
        acc[1] = fmaf(av[u], f0.y, acc[1]);
        acc[2] = fmaf(av[u], f1.x, acc[2]);
        acc[3] = fmaf(av[u], f1.y, acc[3]);
      }
    }
    for (; i < cnt; i += 2) {
      int sn = lsrc[i];
      float a = la[head][i];
      unsigned int hv = H4[(size_t)sn * 96 + t];
      f32x2 f0 = __builtin_amdgcn_cvt_pk_f32_fp8((int)hv, false);
      f32x2 f1 = __builtin_amdgcn_cvt_pk_f32_fp8((int)hv, true);
      acc[0] = fmaf(a, f0.x, acc[0]);
      acc[1] = fmaf(a, f0.y, acc[1]);
      acc[2] = fmaf(a, f1.x, acc[2]);
      acc[3] = fmaf(a, f1.y, acc[3]);
    }
  }
  // cross-half reduce (reuse la storage)
  __syncthreads();
  float* racc = &la[0][0];       // 96*4 floats
  if (half == 1) {
    racc[t * 4 + 0] = acc[0]; racc[t * 4 + 1] = acc[1];
    racc[t * 4 + 2] = acc[2]; racc[t * 4 + 3] = acc[3];
  }
  __syncthreads();
  if (half == 0) {
    acc[0] += racc[t * 4 + 0]; acc[1] += racc[t * 4 + 1];
    acc[2] += racc[t * 4 + 2]; acc[3] += racc[t * 4 + 3];
  }
  // block-reduce the exp partials
#pragma unroll
  for (int o = 32; o; o >>= 1) {
    dp0 += __shfl_down(dp0, o); dp1 += __shfl_down(dp1, o); dp2 += __shfl_down(dp2, o);
  }
  if (lane == 0) { red[wid][0] = dp0; red[wid][1] = dp1; red[wid][2] = dp2; }
  __syncthreads();
  if (j == 0) {
    inv_s[0] = 1.f / (red[0][0] + red[1][0] + red[2][0]);
    inv_s[1] = 1.f / (red[0][1] + red[1][1] + red[2][1]);
    inv_s[2] = 1.f / (red[0][2] + red[1][2] + red[2][2]);
  }
  __syncthreads();
  float i0 = inv_s[0], i1 = inv_s[1], i2 = inv_s[2];
  if (half == 0) {
    float inv = inv_s[head];
    float4 bb = *reinterpret_cast<const float4*>(b1 + 4 * t);
    float v0 = acc[0] * inv + bb.x;
    float v1 = acc[1] * inv + bb.y;
    float v2 = acc[2] * inv + bb.z;
    float v3 = acc[3] * inv + bb.w;
    v0 = v0 > 0.f ? v0 : 0.f; v1 = v1 > 0.f ? v1 : 0.f;
    v2 = v2 > 0.f ? v2 : 0.f; v3 = v3 > 0.f ? v3 : 0.f;
    uint2 st;
    st.x = (unsigned int)f2bf(v0) | ((unsigned int)f2bf(v1) << 16);
    st.y = (unsigned int)f2bf(v2) | ((unsigned int)f2bf(v3) << 16);
    *reinterpret_cast<uint2*>(reinterpret_cast<unsigned short*>(e1b) + (size_t)n * 384 + 4 * t) = st;
  }
  // alpha tail: coalesced w4 re-read (L2-hot), scattered fire-and-forget writes
  for (int p = p0 + j; p < p1; p += 192) {
    float4 w = w4[p];
    int eid = __float_as_int(w.w);
    float* ao = out + 1 + (size_t)eid * 3;
    ao[0] = w.x * i0;
    ao[1] = w.y * i1;
    ao[2] = w.z * i2;
  }
}

// ---------------- agg2: 2 nodes per block, wave-private staging (no barriers) -------------
__global__ __launch_bounds__(128) void agg2_kernel(const unsigned char* __restrict__ h2c,
                                                   const float* __restrict__ w2,
                                                   const int* __restrict__ rowptr,
                                                   const int* __restrict__ csr_src,
                                                   const float* __restrict__ b2,
                                                   float* __restrict__ e2out, int N2) {
  __shared__ int lsrc[2][256];
  __shared__ float la[2][256];
  const unsigned int* H4 = reinterpret_cast<const unsigned int*>(h2c);
  int wv = threadIdx.x >> 6;
  int n = blockIdx.x * 2 + wv;
  if (n >= N2) return;
  int lane = threadIdx.x & 63;
  int half = lane >> 5, t = lane & 31;   // cols 4t..4t+3
  int p0 = rowptr[n], p1 = rowptr[n + 1];

  float dpart = 0.f;
  float acc[4] = {0.f, 0.f, 0.f, 0.f};
  for (int base = p0; base < p1; base += 256) {
    int cnt = min(256, p1 - base);
    for (int i = lane; i < cnt; i += 64) {
      lsrc[wv][i] = csr_src[base + i];
      float ex = w2[base + i];
      la[wv][i] = ex;
      dpart += ex;
    }
    // wave-private LDS: same-wave RAW ordering is guaranteed via compiler waitcnt
    int i = half;
    for (; i + 14 < cnt; i += 16) {
      unsigned int hv[8];
      float av[8];
#pragma unroll
      for (int u = 0; u < 8; ++u) {
        int e = i + 2 * u;
        int sn = lsrc[wv][e];
        av[u] = la[wv][e];
        hv[u] = H4[(size_t)sn * 32 + t];
      }
#pragma unroll
      for (int u = 0; u < 8; ++u) {
        f32x2 f0 = __builtin_amdgcn_cvt_pk_f32_fp8((int)hv[u], false);
        f32x2 f1 = __builtin_amdgcn_cvt_pk_f32_fp8((int)hv[u], true);
        acc[0] = fmaf(av[u], f0.x, acc[0]);
        acc[1] = fmaf(av[u], f0.y, acc[1]);
        acc[2] = fmaf(av[u], f1.x, acc[2]);
        acc[3] = fmaf(av[u], f1.y, acc[3]);
      }
    }
    for (; i < cnt; i += 2) {
      int sn = lsrc[wv][i];
      float a = la[wv][i];
      unsigned int hv = H4[(size_t)sn * 32 + t];
      f32x2 f0 = __builtin_amdgcn_cvt_pk_f32_fp8((int)hv, false);
      f32x2 f1 = __builtin_amdgcn_cvt_pk_f32_fp8((int)hv, true);
      acc[0] = fmaf(a, f0.x, acc[0]);
      acc[1] = fmaf(a, f0.y, acc[1]);
      acc[2] = fmaf(a, f1.x, acc[2]);
      acc[3] = fmaf(a, f1.y, acc[3]);
    }
  }
  // cross-half reduce via shuffle (lane ^ 32)
#pragma unroll
  for (int k = 0; k < 4; ++k) acc[k] += __shfl_xor(acc[k], 32);
#pragma unroll
  for (int o = 32; o; o >>= 1) dpart += __shfl_down(dpart, o);
  float invden = 1.f / __shfl(dpart, 0);
  if (half == 0) {
    float4 bb = *reinterpret_cast<const float4*>(b2 + 4 * t);
    float4 ov;
    ov.x = acc[0] * invden + bb.x;
    ov.y = acc[1] * invden + bb.y;
    ov.z = acc[2] * invden + bb.z;
    ov.w = acc[3] * invden + bb.w;
    *reinterpret_cast<float4*>(e2out + (size_t)n * 128 + 4 * t) = ov;
  }
}

// ---------------- pooling: g[br] = column mean of e2 (both pooled halves identical) -------
__global__ __launch_bounds__(128) void pool_kernel(const float* __restrict__ e2,
                                                   float* __restrict__ g, int N, float invN) {
  int c = threadIdx.x;
  int br = blockIdx.y;
  int r0 = br * N + blockIdx.x * 128;
  int r1 = min(r0 + 128, br * N + N);
  float acc = 0.f;
  for (int n = r0; n < r1; ++n) acc += e2[(size_t)n * 128 + c];
  atomicAdd(&g[br * 128 + c], acc * invN);
}

// cos([m;m],[m';m']) == cos(m,m') — reduce 128 dims
__global__ __launch_bounds__(128) void sim_kernel(const float* __restrict__ g1,
                                                  const float* __restrict__ g2,
                                                  float* __restrict__ out) {
  int t = threadIdx.x;
  float a = g1[t], b = g2[t];
  __shared__ float sd[128], s1[128], s2[128];
  sd[t] = a * b; s1[t] = a * a; s2[t] = b * b;
  __syncthreads();
  for (int ofs = 64; ofs; ofs >>= 1) {
    if (t < ofs) { sd[t] += sd[t + ofs]; s1[t] += s1[t + ofs]; s2[t] += s2[t + ofs]; }
    __syncthreads();
  }
  if (t == 0) {
    float n1 = fmaxf(sqrtf(s1[0]), 1e-8f);
    float n2 = fmaxf(sqrtf(s2[0]), 1e-8f);
    out[0] = sd[0] / (n1 * n2);
  }
}

// ---------------- host ----------------
extern "C" void kernel_launch(void* const* d_in, const int* in_sizes, int n_in,
                              void* d_out, int out_size, void* d_ws, size_t ws_size,
                              hipStream_t stream) {
  const int N = in_sizes[0] / INDIM;
  const int E = in_sizes[1] / 2;
  const int Etot = E + N;
  const int N2 = 2 * N;

  const float* x1  = (const float*)d_in[0];
  const int*   ei1 = (const int*)d_in[1];
  const float* x2  = (const float*)d_in[2];
  const int*   ei2 = (const int*)d_in[3];
  const float* W1  = (const float*)d_in[4];
  const float* as1 = (const float*)d_in[5];
  const float* ad1 = (const float*)d_in[6];
  const float* b1  = (const float*)d_in[7];
  const float* W2  = (const float*)d_in[8];
  const float* as2 = (const float*)d_in[9];
  const float* ad2 = (const float*)d_in[10];
  const float* b2  = (const float*)d_in[11];
  float* out = (float*)d_out;
  const int* es1 = ei1, *ed1 = ei1 + E;
  const int* es2 = ei2, *ed2 = ei2 + E;

  char* p = (char*)d_ws;
  auto alloc = [&](size_t bytes) -> char* {
    char* q = p;
    p += (bytes + 255) & ~(size_t)255;
    return q;
  };
  unsigned char* h1c = (unsigned char*)alloc((size_t)N2 * 384);
  __hip_bfloat16* e1b = (__hip_bfloat16*)alloc((size_t)N2 * 384 * 2);
  unsigned char* h2c = (unsigned char*)alloc((size_t)N2 * 128);
  float* e2          = (float*)alloc((size_t)N2 * 128 * 4);
  __hip_bfloat16* W1t = (__hip_bfloat16*)alloc((size_t)256 * 384 * 2);
  __hip_bfloat16* W2t = (__hip_bfloat16*)alloc((size_t)384 * 128 * 2);
  float* s1v  = (float*)alloc((size_t)N2 * 3 * 4);
  float* d1v  = (float*)alloc((size_t)N2 * 3 * 4);
  float* s2v  = (float*)alloc((size_t)N2 * 4);
  float* d2v  = (float*)alloc((size_t)N2 * 4);
  float* g    = (float*)alloc(256 * 4);
  int* deg     = (int*)alloc((size_t)N2 * 4);
  int* rowptr  = (int*)alloc((size_t)(N2 + 1) * 4);
  int* cursor  = (int*)alloc((size_t)N2 * 4);
  int* csr_src = (int*)alloc((size_t)2 * Etot * 4);
  int* csr_dst = (int*)alloc((size_t)2 * Etot * 4);
  float4* w4   = (float4*)alloc((size_t)2 * Etot * 16);
  float* w2    = (float*)alloc((size_t)2 * Etot * 4);

  const int EB = 256;
  const int egrid2 = (2 * Etot + EB - 1) / EB;
  const int gmx = (N2 + 63) / 64;

  hipMemsetAsync(g, 0, 256 * 4, stream);
  hipMemsetAsync(deg, 0, (size_t)N2 * 4, stream);
  wprep_kernel<<<(256 * 384 + 384 * 128 + 255) / 256, 256, 0, stream>>>(W1, W1t, W2, W2t);

  deg_kernel<<<egrid2, EB, 0, stream>>>(ed1, ed2, E, Etot, N, deg);
  mfma_gemm<256, false, 3><<<dim3(gmx, 3), 256, 0, stream>>>(x1, x2, N, W1t, as1, ad1,
                                                             h1c, s1v, d1v, N2, 384);
  scan_kernel<<<1, 1024, 0, stream>>>(deg, rowptr, cursor, N2);
  fill_kernel<<<egrid2, EB, 0, stream>>>(es1, ed1, es2, ed2, s1v, d1v, E, Etot, N,
                                         cursor, csr_src, csr_dst, w4);

  agg1_kernel<<<N2, 192, 0, stream>>>(h1c, rowptr, csr_src, w4, b1, e1b, out);

  mfma_gemm<384, true, 1><<<dim3(gmx, 1), 256, 0, stream>>>(e1b, e1b, N2, W2t, as2, ad2,
                                                            h2c, s2v, d2v, N2, 128);
  w2prep_kernel<<<egrid2, EB, 0, stream>>>(csr_src, csr_dst, s2v, d2v, 2 * Etot, w2);
  agg2_kernel<<<(N2 + 1) / 2, 128, 0, stream>>>(h2c, w2, rowptr, csr_src, b2, e2, N2);

  pool_kernel<<<dim3((N + 127) / 128, 2), 128, 0, stream>>>(e2, g, N, 1.f / (float)N);
  sim_kernel<<<1, 128, 0, stream>>>(g, g + 128, out);
}

// Round 12
// 247.495 us; speedup vs baseline: 1.7560x; 1.0057x over previous
//
#include <hip/hip_runtime.h>
#include <hip/hip_bf16.h>
#include <cstdint>
#include <cstddef>

#define INDIM 256
#define NEG 0.2f

typedef __attribute__((ext_vector_type(8))) short short8v;
typedef __attribute__((ext_vector_type(4))) float f32x4;
typedef __attribute__((ext_vector_type(2))) float f32x2;

__device__ __forceinline__ unsigned short f2bf(float x) {
  __hip_bfloat16 b = __float2bfloat16(x);
  return __builtin_bit_cast(unsigned short, b);
}

// native gfx950 fp8 (OCP E4M3) converts — single VALU instruction each
__device__ __forceinline__ unsigned char f2fp8(float v) {
  int packed = __builtin_amdgcn_cvt_pk_fp8_f32(v, v, 0, false);
  return (unsigned char)(packed & 0xff);
}

__device__ __forceinline__ float lrelu(float v) { return v > 0.f ? v : NEG * v; }

// ---------------- W pre-transpose to bf16 (both weights, one dispatch) --------------------
__global__ void wprep_kernel(const float* __restrict__ W1, __hip_bfloat16* __restrict__ W1t,
                             const float* __restrict__ W2, __hip_bfloat16* __restrict__ W2t) {
  int idx = blockIdx.x * blockDim.x + threadIdx.x;
  const int T1 = 256 * 384;
  if (idx < T1) {
    int k = idx / 384, c = idx - k * 384;
    W1t[(size_t)c * 256 + k] = __float2bfloat16(W1[idx]);
  } else {
    int i = idx - T1;
    if (i < 384 * 128) {
      int k = i / 128, c = i - k * 128;
      W2t[(size_t)c * 384 + k] = __float2bfloat16(W2[i]);
    }
  }
}

// ---------------- MFMA GEMM over 2N batched rows + FUSED attention dots ------------------
// tile 64x128, 4 waves (2x2), wave tile 32x64 = 2x4 fragments of 16x16, BK=32
// writes fp8(e4m3) Yc and per-row S,D dots (s = h.att_s, d = h.att_d) for head blockIdx.y.
template<int K, bool ABF16, int NH>
__global__ __launch_bounds__(256) void mfma_gemm(const void* __restrict__ A0,
                                                 const void* __restrict__ A1, int Nsplit,
                                                 const __hip_bfloat16* __restrict__ Wt,
                                                 const float* __restrict__ att_s,
                                                 const float* __restrict__ att_d,
                                                 unsigned char* __restrict__ Yc,
                                                 float* __restrict__ So,
                                                 float* __restrict__ Do,
                                                 int M, int NC) {
  __shared__ short As[64][40];
  __shared__ short Bs[128][40];
  __shared__ float sred[2][64];
  const int tid = threadIdx.x;
  const int row0 = blockIdx.x * 64;
  const int col0 = blockIdx.y * 128;
  const int l = tid & 63, w = tid >> 6;
  const int wr = w >> 1, wc = w & 1;
  const int lr = l & 15, lk = (l >> 4) * 8;

  f32x4 acc[2][4];
#pragma unroll
  for (int m = 0; m < 2; ++m)
#pragma unroll
    for (int n = 0; n < 4; ++n) acc[m][n] = {0.f, 0.f, 0.f, 0.f};

  for (int k0 = 0; k0 < K; k0 += 32) {
    __syncthreads();
    {  // stage A: 64 rows x 32 k
      int r = tid >> 2, kq = (tid & 3) * 8;
      int gr = row0 + r;
      short8v av = {0, 0, 0, 0, 0, 0, 0, 0};
      if (gr < M) {
        const void* Ab = (gr < Nsplit) ? A0 : A1;
        int lrow = (gr < Nsplit) ? gr : gr - Nsplit;
        if (ABF16) {
          av = *(const short8v*)((const short*)Ab + (size_t)lrow * K + k0 + kq);
        } else {
          const float* ap = (const float*)Ab + (size_t)lrow * K + k0 + kq;
          float4 u = *(const float4*)ap;
          float4 v = *(const float4*)(ap + 4);
          av = short8v{(short)f2bf(u.x), (short)f2bf(u.y), (short)f2bf(u.z), (short)f2bf(u.w),
                       (short)f2bf(v.x), (short)f2bf(v.y), (short)f2bf(v.z), (short)f2bf(v.w)};
        }
      }
      *(short8v*)&As[r][kq] = av;
    }
    {  // stage B: 128 cols x 32 k (Wt row-major [NC][K])
      int c = tid >> 1, kq = (tid & 1) * 8;
      const short* wp = (const short*)Wt + (size_t)(col0 + c) * K + k0 + kq;
      *(short8v*)&Bs[c][kq]      = *(const short8v*)wp;
      *(short8v*)&Bs[c][kq + 16] = *(const short8v*)(wp + 16);
    }
    __syncthreads();
    short8v a[2], b[4];
#pragma unroll
    for (int m = 0; m < 2; ++m) a[m] = *(short8v*)&As[wr * 32 + m * 16 + lr][lk];
#pragma unroll
    for (int n = 0; n < 4; ++n) b[n] = *(short8v*)&Bs[wc * 64 + n * 16 + lr][lk];
#pragma unroll
    for (int m = 0; m < 2; ++m)
#pragma unroll
      for (int n = 0; n < 4; ++n)
        acc[m][n] = __builtin_amdgcn_mfma_f32_16x16x32_bf16(a[m], b[n], acc[m][n], 0, 0, 0);
  }
  // epilogue: C/D layout col=lane&15, row=(lane>>4)*4+q — fp8 store
#pragma unroll
  for (int m = 0; m < 2; ++m) {
    int rbase = row0 + wr * 32 + m * 16 + (l >> 4) * 4;
#pragma unroll
    for (int n = 0; n < 4; ++n) {
      int col = col0 + wc * 64 + n * 16 + lr;
#pragma unroll
      for (int q = 0; q < 4; ++q) {
        int row = rbase + q;
        if (row < M) Yc[(size_t)row * NC + col] = f2fp8(acc[m][n][q]);
      }
    }
  }
  // fused attention dots
  float asv[4], adv[4];
#pragma unroll
  for (int n = 0; n < 4; ++n) {
    int col = col0 + wc * 64 + n * 16 + lr;
    asv[n] = att_s[col];
    adv[n] = att_d[col];
  }
  float ps[2][4], pd[2][4];
#pragma unroll
  for (int m = 0; m < 2; ++m)
#pragma unroll
    for (int q = 0; q < 4; ++q) {
      float s = 0.f, d = 0.f;
#pragma unroll
      for (int n = 0; n < 4; ++n) {
        s = fmaf(acc[m][n][q], asv[n], s);
        d = fmaf(acc[m][n][q], adv[n], d);
      }
      ps[m][q] = s; pd[m][q] = d;
    }
#pragma unroll
  for (int o = 1; o < 16; o <<= 1) {
#pragma unroll
    for (int m = 0; m < 2; ++m)
#pragma unroll
      for (int q = 0; q < 4; ++q) {
        ps[m][q] += __shfl_xor(ps[m][q], o);
        pd[m][q] += __shfl_xor(pd[m][q], o);
      }
  }
  __syncthreads();
  if (wc == 1 && lr == 0) {
#pragma unroll
    for (int m = 0; m < 2; ++m)
#pragma unroll
      for (int q = 0; q < 4; ++q) {
        int rl = wr * 32 + m * 16 + (l >> 4) * 4 + q;
        sred[0][rl] = ps[m][q];
        sred[1][rl] = pd[m][q];
      }
  }
  __syncthreads();
  if (wc == 0 && lr == 0) {
#pragma unroll
    for (int m = 0; m < 2; ++m)
#pragma unroll
      for (int q = 0; q < 4; ++q) {
        int rl = wr * 32 + m * 16 + (l >> 4) * 4 + q;
        int row = row0 + rl;
        if (row < M) {
          So[(size_t)row * NH + blockIdx.y] = ps[m][q] + sred[0][rl];
          Do[(size_t)row * NH + blockIdx.y] = pd[m][q] + sred[1][rl];
        }
      }
  }
}

// ---------------- CSR build over 2N virtual nodes (both branches) ----------------
__global__ void deg_kernel(const int* __restrict__ ed1, const int* __restrict__ ed2,
                           int E, int Etot, int N, int* __restrict__ deg) {
  int idx = blockIdx.x * blockDim.x + threadIdx.x;
  if (idx >= 2 * Etot) return;
  int br = idx >= Etot;
  int el = idx - br * Etot;
  const int* ed = br ? ed2 : ed1;
  int dn = ((el < E) ? ed[el] : (el - E)) + br * N;
  atomicAdd(&deg[dn], 1);
}

// scan: thread-serial 20 elements + one block scan (n <= 20480)
__global__ __launch_bounds__(1024) void scan_kernel(const int* __restrict__ deg,
                                                    int* __restrict__ rowptr,
                                                    int* __restrict__ cursor, int n) {
  __shared__ int wsum[16];
  int t = threadIdx.x, lane = t & 63, wid = t >> 6;
  int start = t * 20;
  int v[20];
  int s = 0;
#pragma unroll
  for (int k = 0; k < 20; ++k) {
    int i = start + k;
    int d = (i < n) ? deg[i] : 0;
    s += d;
    v[k] = s;                    // inclusive local prefix
  }
  int x = s;
#pragma unroll
  for (int o = 1; o < 64; o <<= 1) {
    int tm = __shfl_up(x, o);
    if (lane >= o) x += tm;
  }
  if (lane == 63) wsum[wid] = x;
  __syncthreads();
  if (wid == 0) {
    int wv = (lane < 16) ? wsum[lane] : 0;
#pragma unroll
    for (int o = 1; o < 16; o <<= 1) {
      int tm = __shfl_up(wv, o);
      if (lane >= o) wv += tm;
    }
    if (lane < 16) wsum[lane] = wv;
  }
  __syncthreads();
  int excl = (x - s) + (wid ? wsum[wid - 1] : 0);
  if (t == 0) rowptr[0] = 0;
#pragma unroll
  for (int k = 0; k < 20; ++k) {
    int i = start + k;
    if (i < n) {
      rowptr[i + 1] = excl + v[k];
      cursor[i] = excl + (k ? v[k - 1] : 0);
    }
  }
}

// fill: minimal scatter — only csr_src (4 B/edge)
__global__ void fill_kernel(const int* __restrict__ es1, const int* __restrict__ ed1,
                            const int* __restrict__ es2, const int* __restrict__ ed2,
                            int E, int Etot, int N, int* __restrict__ cursor,
                            int* __restrict__ csr_src) {
  int idx = blockIdx.x * blockDim.x + threadIdx.x;
  if (idx >= 2 * Etot) return;
  int br = idx >= Etot;
  int el = idx - br * Etot;
  const int* es = br ? es2 : es1;
  const int* ed = br ? ed2 : ed1;
  int sn, dn;
  if (el < E) { sn = es[el]; dn = ed[el]; } else { sn = dn = el - E; }
  sn += br * N; dn += br * N;
  int pos = atomicAdd(&cursor[dn], 1);
  csr_src[pos] = sn;
}

// ---------------- agg1: single-pass aggregate + inline denom, dword fp8 gathers -----------
// 192 threads = 2 edge-halves x 96 col-groups (4 cols each); stage computes exp from S/D.
__global__ __launch_bounds__(192) void agg1_kernel(const unsigned char* __restrict__ h1c,
                                                   const float* __restrict__ S,
                                                   const float* __restrict__ D,
                                                   const int* __restrict__ rowptr,
                                                   const int* __restrict__ csr_src,
                                                   const float* __restrict__ b1,
                                                   __hip_bfloat16* __restrict__ e1b,
                                                   float* __restrict__ invden) {
  __shared__ int lsrc[192];
  __shared__ float la[3][192];
  __shared__ float red[3][3];
  __shared__ float inv_s[3];
  const unsigned int* H4 = reinterpret_cast<const unsigned int*>(h1c);
  int n = blockIdx.x;
  int j = threadIdx.x;
  int wid = j >> 6, lane = j & 63;
  int half = (j >= 96) ? 1 : 0;
  int t = j - half * 96;         // col group: cols 4t..4t+3
  int head = t >> 5;             // 4t/128
  int p0 = rowptr[n], p1 = rowptr[n + 1];
  float d0 = D[n * 3], d1 = D[n * 3 + 1], d2 = D[n * 3 + 2];

  float dp0 = 0.f, dp1 = 0.f, dp2 = 0.f;
  float acc[4] = {0.f, 0.f, 0.f, 0.f};
  for (int base = p0; base < p1; base += 192) {
    int cnt = min(192, p1 - base);
    __syncthreads();
    if (j < cnt) {
      int sn = csr_src[base + j];
      lsrc[j] = sn;
      float e0 = __expf(lrelu(S[sn * 3] + d0));
      float e1 = __expf(lrelu(S[sn * 3 + 1] + d1));
      float e2 = __expf(lrelu(S[sn * 3 + 2] + d2));
      la[0][j] = e0; la[1][j] = e1; la[2][j] = e2;
      dp0 += e0; dp1 += e1; dp2 += e2;
    }
    __syncthreads();
    int i = half;
    for (; i + 14 < cnt; i += 16) {
      unsigned int hv[8];
      float av[8];
#pragma unroll
      for (int u = 0; u < 8; ++u) {
        int e = i + 2 * u;
        int sn = lsrc[e];
        av[u] = la[head][e];
        hv[u] = H4[(size_t)sn * 96 + t];
      }
#pragma unroll
      for (int u = 0; u < 8; ++u) {
        f32x2 f0 = __builtin_amdgcn_cvt_pk_f32_fp8((int)hv[u], false);
        f32x2 f1 = __builtin_amdgcn_cvt_pk_f32_fp8((int)hv[u], true);
        acc[0] = fmaf(av[u], f0.x, acc[0]);
        acc[1] = fmaf(av[u], f0.y, acc[1]);
        acc[2] = fmaf(av[u], f1.x, acc[2]);
        acc[3] = fmaf(av[u], f1.y, acc[3]);
      }
    }
    for (; i < cnt; i += 2) {
      int sn = lsrc[i];
      float a = la[head][i];
      unsigned int hv = H4[(size_t)sn * 96 + t];
      f32x2 f0 = __builtin_amdgcn_cvt_pk_f32_fp8((int)hv, false);
      f32x2 f1 = __builtin_amdgcn_cvt_pk_f32_fp8((int)hv, true);
      acc[0] = fmaf(a, f0.x, acc[0]);
      acc[1] = fmaf(a, f0.y, acc[1]);
      acc[2] = fmaf(a, f1.x, acc[2]);
      acc[3] = fmaf(a, f1.y, acc[3]);
    }
  }
  // cross-half reduce (reuse la storage)
  __syncthreads();
  float* racc = &la[0][0];       // 96*4 floats
  if (half == 1) {
    racc[t * 4 + 0] = acc[0]; racc[t * 4 + 1] = acc[1];
    racc[t * 4 + 2] = acc[2]; racc[t * 4 + 3] = acc[3];
  }
  __syncthreads();
  if (half == 0) {
    acc[0] += racc[t * 4 + 0]; acc[1] += racc[t * 4 + 1];
    acc[2] += racc[t * 4 + 2]; acc[3] += racc[t * 4 + 3];
  }
  // block-reduce the exp partials
#pragma unroll
  for (int o = 32; o; o >>= 1) {
    dp0 += __shfl_down(dp0, o); dp1 += __shfl_down(dp1, o); dp2 += __shfl_down(dp2, o);
  }
  if (lane == 0) { red[wid][0] = dp0; red[wid][1] = dp1; red[wid][2] = dp2; }
  __syncthreads();
  if (j == 0) {
    inv_s[0] = 1.f / (red[0][0] + red[1][0] + red[2][0]);
    inv_s[1] = 1.f / (red[0][1] + red[1][1] + red[2][1]);
    inv_s[2] = 1.f / (red[0][2] + red[1][2] + red[2][2]);
  }
  __syncthreads();
  if (half == 0) {
    float inv = inv_s[head];
    float4 bb = *reinterpret_cast<const float4*>(b1 + 4 * t);
    float v0 = acc[0] * inv + bb.x;
    float v1 = acc[1] * inv + bb.y;
    float v2 = acc[2] * inv + bb.z;
    float v3 = acc[3] * inv + bb.w;
    v0 = v0 > 0.f ? v0 : 0.f; v1 = v1 > 0.f ? v1 : 0.f;
    v2 = v2 > 0.f ? v2 : 0.f; v3 = v3 > 0.f ? v3 : 0.f;
    uint2 st;
    st.x = (unsigned int)f2bf(v0) | ((unsigned int)f2bf(v1) << 16);
    st.y = (unsigned int)f2bf(v2) | ((unsigned int)f2bf(v3) << 16);
    *reinterpret_cast<uint2*>(reinterpret_cast<unsigned short*>(e1b) + (size_t)n * 384 + 4 * t) = st;
  }
  if (j < 3) invden[n * 3 + j] = inv_s[j];
}

// ---------------- alpha: edge-major, coalesced reads + writes; small gathers --------------
__global__ void alpha_kernel(const float* __restrict__ S, const float* __restrict__ D,
                             const float* __restrict__ invden,
                             const int* __restrict__ es1, const int* __restrict__ ed1,
                             const int* __restrict__ es2, const int* __restrict__ ed2,
                             int E, int Etot, int N, float* __restrict__ out) {
  int idx = blockIdx.x * blockDim.x + threadIdx.x;
  if (idx >= 2 * Etot) return;
  int br = idx >= Etot;
  int el = idx - br * Etot;
  const int* es = br ? es2 : es1;
  const int* ed = br ? ed2 : ed1;
  int sn, dn;
  if (el < E) { sn = es[el]; dn = ed[el]; } else { sn = dn = el - E; }
  sn += br * N; dn += br * N;
  float* ao = out + 1 + (size_t)br * Etot * 3 + (size_t)el * 3;
#pragma unroll
  for (int h = 0; h < 3; ++h) {
    float v = lrelu(S[sn * 3 + h] + D[dn * 3 + h]);
    ao[h] = __expf(v) * invden[dn * 3 + h];
  }
}

// ---------------- agg2: 2 nodes per block, wave-private staging, inline exp ---------------
__global__ __launch_bounds__(128) void agg2_kernel(const unsigned char* __restrict__ h2c,
                                                   const float* __restrict__ S2,
                                                   const float* __restrict__ D2,
                                                   const int* __restrict__ rowptr,
                                                   const int* __restrict__ csr_src,
                                                   const float* __restrict__ b2,
                                                   float* __restrict__ e2out, int N2) {
  __shared__ int lsrc[2][256];
  __shared__ float la[2][256];
  const unsigned int* H4 = reinterpret_cast<const unsigned int*>(h2c);
  int wv = threadIdx.x >> 6;
  int n = blockIdx.x * 2 + wv;
  if (n >= N2) return;
  int lane = threadIdx.x & 63;
  int half = lane >> 5, t = lane & 31;   // cols 4t..4t+3
  int p0 = rowptr[n], p1 = rowptr[n + 1];
  float dnv = D2[n];

  float dpart = 0.f;
  float acc[4] = {0.f, 0.f, 0.f, 0.f};
  for (int base = p0; base < p1; base += 256) {
    int cnt = min(256, p1 - base);
    for (int i = lane; i < cnt; i += 64) {
      int sn = csr_src[base + i];
      lsrc[wv][i] = sn;
      float ex = __expf(lrelu(S2[sn] + dnv));
      la[wv][i] = ex;
      dpart += ex;
    }
    // wave-private LDS: same-wave RAW ordering is guaranteed via compiler waitcnt
    int i = half;
    for (; i + 14 < cnt; i += 16) {
      unsigned int hv[8];
      float av[8];
#pragma unroll
      for (int u = 0; u < 8; ++u) {
        int e = i + 2 * u;
        int sn = lsrc[wv][e];
        av[u] = la[wv][e];
        hv[u] = H4[(size_t)sn * 32 + t];
      }
#pragma unroll
      for (int u = 0; u < 8; ++u) {
        f32x2 f0 = __builtin_amdgcn_cvt_pk_f32_fp8((int)hv[u], false);
        f32x2 f1 = __builtin_amdgcn_cvt_pk_f32_fp8((int)hv[u], true);
        acc[0] = fmaf(av[u], f0.x, acc[0]);
        acc[1] = fmaf(av[u], f0.y, acc[1]);
        acc[2] = fmaf(av[u], f1.x, acc[2]);
        acc[3] = fmaf(av[u], f1.y, acc[3]);
      }
    }
    for (; i < cnt; i += 2) {
      int sn = lsrc[wv][i];
      float a = la[wv][i];
      unsigned int hv = H4[(size_t)sn * 32 + t];
      f32x2 f0 = __builtin_amdgcn_cvt_pk_f32_fp8((int)hv, false);
      f32x2 f1 = __builtin_amdgcn_cvt_pk_f32_fp8((int)hv, true);
      acc[0] = fmaf(a, f0.x, acc[0]);
      acc[1] = fmaf(a, f0.y, acc[1]);
      acc[2] = fmaf(a, f1.x, acc[2]);
      acc[3] = fmaf(a, f1.y, acc[3]);
    }
  }
  // cross-half reduce via shuffle (lane ^ 32)
#pragma unroll
  for (int k = 0; k < 4; ++k) acc[k] += __shfl_xor(acc[k], 32);
#pragma unroll
  for (int o = 32; o; o >>= 1) dpart += __shfl_down(dpart, o);
  float invden = 1.f / __shfl(dpart, 0);
  if (half == 0) {
    float4 bb = *reinterpret_cast<const float4*>(b2 + 4 * t);
    float4 ov;
    ov.x = acc[0] * invden + bb.x;
    ov.y = acc[1] * invden + bb.y;
    ov.z = acc[2] * invden + bb.z;
    ov.w = acc[3] * invden + bb.w;
    *reinterpret_cast<float4*>(e2out + (size_t)n * 128 + 4 * t) = ov;
  }
}

// ---------------- pooling: g[br] = column mean of e2 (both pooled halves identical) -------
__global__ __launch_bounds__(128) void pool_kernel(const float* __restrict__ e2,
                                                   float* __restrict__ g, int N, float invN) {
  int c = threadIdx.x;
  int br = blockIdx.y;
  int r0 = br * N + blockIdx.x * 128;
  int r1 = min(r0 + 128, br * N + N);
  float acc = 0.f;
  for (int n = r0; n < r1; ++n) acc += e2[(size_t)n * 128 + c];
  atomicAdd(&g[br * 128 + c], acc * invN);
}

// cos([m;m],[m';m']) == cos(m,m') — reduce 128 dims
__global__ __launch_bounds__(128) void sim_kernel(const float* __restrict__ g1,
                                                  const float* __restrict__ g2,
                                                  float* __restrict__ out) {
  int t = threadIdx.x;
  float a = g1[t], b = g2[t];
  __shared__ float sd[128], s1[128], s2[128];
  sd[t] = a * b; s1[t] = a * a; s2[t] = b * b;
  __syncthreads();
  for (int ofs = 64; ofs; ofs >>= 1) {
    if (t < ofs) { sd[t] += sd[t + ofs]; s1[t] += s1[t + ofs]; s2[t] += s2[t + ofs]; }
    __syncthreads();
  }
  if (t == 0) {
    float n1 = fmaxf(sqrtf(s1[0]), 1e-8f);
    float n2 = fmaxf(sqrtf(s2[0]), 1e-8f);
    out[0] = sd[0] / (n1 * n2);
  }
}

// ---------------- host ----------------
extern "C" void kernel_launch(void* const* d_in, const int* in_sizes, int n_in,
                              void* d_out, int out_size, void* d_ws, size_t ws_size,
                              hipStream_t stream) {
  const int N = in_sizes[0] / INDIM;
  const int E = in_sizes[1] / 2;
  const int Etot = E + N;
  const int N2 = 2 * N;

  const float* x1  = (const float*)d_in[0];
  const int*   ei1 = (const int*)d_in[1];
  const float* x2  = (const float*)d_in[2];
  const int*   ei2 = (const int*)d_in[3];
  const float* W1  = (const float*)d_in[4];
  const float* as1 = (const float*)d_in[5];
  const float* ad1 = (const float*)d_in[6];
  const float* b1  = (const float*)d_in[7];
  const float* W2  = (const float*)d_in[8];
  const float* as2 = (const float*)d_in[9];
  const float* ad2 = (const float*)d_in[10];
  const float* b2  = (const float*)d_in[11];
  float* out = (float*)d_out;
  const int* es1 = ei1, *ed1 = ei1 + E;
  const int* es2 = ei2, *ed2 = ei2 + E;

  char* p = (char*)d_ws;
  auto alloc = [&](size_t bytes) -> char* {
    char* q = p;
    p += (bytes + 255) & ~(size_t)255;
    return q;
  };
  unsigned char* h1c = (unsigned char*)alloc((size_t)N2 * 384);
  __hip_bfloat16* e1b = (__hip_bfloat16*)alloc((size_t)N2 * 384 * 2);
  unsigned char* h2c = (unsigned char*)alloc((size_t)N2 * 128);
  float* e2          = (float*)alloc((size_t)N2 * 128 * 4);
  __hip_bfloat16* W1t = (__hip_bfloat16*)alloc((size_t)256 * 384 * 2);
  __hip_bfloat16* W2t = (__hip_bfloat16*)alloc((size_t)384 * 128 * 2);
  float* s1v  = (float*)alloc((size_t)N2 * 3 * 4);
  float* d1v  = (float*)alloc((size_t)N2 * 3 * 4);
  float* s2v  = (float*)alloc((size_t)N2 * 4);
  float* d2v  = (float*)alloc((size_t)N2 * 4);
  float* idn  = (float*)alloc((size_t)N2 * 3 * 4);
  float* g    = (float*)alloc(256 * 4);
  int* deg     = (int*)alloc((size_t)N2 * 4);
  int* rowptr  = (int*)alloc((size_t)(N2 + 1) * 4);
  int* cursor  = (int*)alloc((size_t)N2 * 4);
  int* csr_src = (int*)alloc((size_t)2 * Etot * 4);

  const int EB = 256;
  const int egrid2 = (2 * Etot + EB - 1) / EB;
  const int gmx = (N2 + 63) / 64;

  hipMemsetAsync(g, 0, 256 * 4, stream);
  hipMemsetAsync(deg, 0, (size_t)N2 * 4, stream);
  wprep_kernel<<<(256 * 384 + 384 * 128 + 255) / 256, 256, 0, stream>>>(W1, W1t, W2, W2t);

  deg_kernel<<<egrid2, EB, 0, stream>>>(ed1, ed2, E, Etot, N, deg);
  mfma_gemm<256, false, 3><<<dim3(gmx, 3), 256, 0, stream>>>(x1, x2, N, W1t, as1, ad1,
                                                             h1c, s1v, d1v, N2, 384);
  scan_kernel<<<1, 1024, 0, stream>>>(deg, rowptr, cursor, N2);
  fill_kernel<<<egrid2, EB, 0, stream>>>(es1, ed1, es2, ed2, E, Etot, N, cursor, csr_src);

  agg1_kernel<<<N2, 192, 0, stream>>>(h1c, s1v, d1v, rowptr, csr_src, b1, e1b, idn);

  mfma_gemm<384, true, 1><<<dim3(gmx, 1), 256, 0, stream>>>(e1b, e1b, N2, W2t, as2, ad2,
                                                            h2c, s2v, d2v, N2, 128);
  alpha_kernel<<<egrid2, EB, 0, stream>>>(s1v, d1v, idn, es1, ed1, es2, ed2, E, Etot, N, out);
  agg2_kernel<<<(N2 + 1) / 2, 128, 0, stream>>>(h2c, s2v, d2v, rowptr, csr_src, b2, e2, N2);

  pool_kernel<<<dim3((N + 127) / 128, 2), 128, 0, stream>>>(e2, g, N, 1.f / (float)N);
  sim_kernel<<<1, 128, 0, stream>>>(g, g + 256 / 2, out);
}

// Round 13
// 234.500 us; speedup vs baseline: 1.8533x; 1.0554x over previous
//
#include <hip/hip_runtime.h>
#include <hip/hip_bf16.h>
#include <cstdint>
#include <cstddef>

#define INDIM 256
#define NEG 0.2f

typedef __attribute__((ext_vector_type(8))) short short8v;
typedef __attribute__((ext_vector_type(4))) float f32x4;
typedef __attribute__((ext_vector_type(2))) float f32x2;

__device__ __forceinline__ unsigned short f2bf(float x) {
  __hip_bfloat16 b = __float2bfloat16(x);
  return __builtin_bit_cast(unsigned short, b);
}

// native gfx950 fp8 (OCP E4M3) converts — single VALU instruction each
__device__ __forceinline__ unsigned char f2fp8(float v) {
  int packed = __builtin_amdgcn_cvt_pk_fp8_f32(v, v, 0, false);
  return (unsigned char)(packed & 0xff);
}

__device__ __forceinline__ float lrelu(float v) { return v > 0.f ? v : NEG * v; }

// ---------------- W pre-transpose to bf16 (both weights, one dispatch) --------------------
__global__ void wprep_kernel(const float* __restrict__ W1, __hip_bfloat16* __restrict__ W1t,
                             const float* __restrict__ W2, __hip_bfloat16* __restrict__ W2t) {
  int idx = blockIdx.x * blockDim.x + threadIdx.x;
  const int T1 = 256 * 384;
  if (idx < T1) {
    int k = idx / 384, c = idx - k * 384;
    W1t[(size_t)c * 256 + k] = __float2bfloat16(W1[idx]);
  } else {
    int i = idx - T1;
    if (i < 384 * 128) {
      int k = i / 128, c = i - k * 128;
      W2t[(size_t)c * 384 + k] = __float2bfloat16(W2[i]);
    }
  }
}

// ---------------- MFMA GEMM over 2N batched rows + FUSED attention dots ------------------
// tile 64x128, 4 waves (2x2), wave tile 32x64 = 2x4 fragments of 16x16, BK=32
// writes fp8(e4m3) Yc and per-row S,D dots for head blockIdx.y (stride SST).
template<int K, bool ABF16, int NH>
__global__ __launch_bounds__(256) void mfma_gemm(const void* __restrict__ A0,
                                                 const void* __restrict__ A1, int Nsplit,
                                                 const __hip_bfloat16* __restrict__ Wt,
                                                 const float* __restrict__ att_s,
                                                 const float* __restrict__ att_d,
                                                 unsigned char* __restrict__ Yc,
                                                 float* __restrict__ So,
                                                 float* __restrict__ Do,
                                                 int M, int NC) {
  constexpr int SST = (NH == 3) ? 4 : 1;
  __shared__ short As[64][40];
  __shared__ short Bs[128][40];
  __shared__ float sred[2][64];
  const int tid = threadIdx.x;
  const int row0 = blockIdx.x * 64;
  const int col0 = blockIdx.y * 128;
  const int l = tid & 63, w = tid >> 6;
  const int wr = w >> 1, wc = w & 1;
  const int lr = l & 15, lk = (l >> 4) * 8;

  f32x4 acc[2][4];
#pragma unroll
  for (int m = 0; m < 2; ++m)
#pragma unroll
    for (int n = 0; n < 4; ++n) acc[m][n] = {0.f, 0.f, 0.f, 0.f};

  for (int k0 = 0; k0 < K; k0 += 32) {
    __syncthreads();
    {  // stage A: 64 rows x 32 k
      int r = tid >> 2, kq = (tid & 3) * 8;
      int gr = row0 + r;
      short8v av = {0, 0, 0, 0, 0, 0, 0, 0};
      if (gr < M) {
        const void* Ab = (gr < Nsplit) ? A0 : A1;
        int lrow = (gr < Nsplit) ? gr : gr - Nsplit;
        if (ABF16) {
          av = *(const short8v*)((const short*)Ab + (size_t)lrow * K + k0 + kq);
        } else {
          const float* ap = (const float*)Ab + (size_t)lrow * K + k0 + kq;
          float4 u = *(const float4*)ap;
          float4 v = *(const float4*)(ap + 4);
          av = short8v{(short)f2bf(u.x), (short)f2bf(u.y), (short)f2bf(u.z), (short)f2bf(u.w),
                       (short)f2bf(v.x), (short)f2bf(v.y), (short)f2bf(v.z), (short)f2bf(v.w)};
        }
      }
      *(short8v*)&As[r][kq] = av;
    }
    {  // stage B: 128 cols x 32 k (Wt row-major [NC][K])
      int c = tid >> 1, kq = (tid & 1) * 8;
      const short* wp = (const short*)Wt + (size_t)(col0 + c) * K + k0 + kq;
      *(short8v*)&Bs[c][kq]      = *(const short8v*)wp;
      *(short8v*)&Bs[c][kq + 16] = *(const short8v*)(wp + 16);
    }
    __syncthreads();
    short8v a[2], b[4];
#pragma unroll
    for (int m = 0; m < 2; ++m) a[m] = *(short8v*)&As[wr * 32 + m * 16 + lr][lk];
#pragma unroll
    for (int n = 0; n < 4; ++n) b[n] = *(short8v*)&Bs[wc * 64 + n * 16 + lr][lk];
#pragma unroll
    for (int m = 0; m < 2; ++m)
#pragma unroll
      for (int n = 0; n < 4; ++n)
        acc[m][n] = __builtin_amdgcn_mfma_f32_16x16x32_bf16(a[m], b[n], acc[m][n], 0, 0, 0);
  }
  // epilogue: C/D layout col=lane&15, row=(lane>>4)*4+q — fp8 store
#pragma unroll
  for (int m = 0; m < 2; ++m) {
    int rbase = row0 + wr * 32 + m * 16 + (l >> 4) * 4;
#pragma unroll
    for (int n = 0; n < 4; ++n) {
      int col = col0 + wc * 64 + n * 16 + lr;
#pragma unroll
      for (int q = 0; q < 4; ++q) {
        int row = rbase + q;
        if (row < M) Yc[(size_t)row * NC + col] = f2fp8(acc[m][n][q]);
      }
    }
  }
  // fused attention dots
  float asv[4], adv[4];
#pragma unroll
  for (int n = 0; n < 4; ++n) {
    int col = col0 + wc * 64 + n * 16 + lr;
    asv[n] = att_s[col];
    adv[n] = att_d[col];
  }
  float ps[2][4], pd[2][4];
#pragma unroll
  for (int m = 0; m < 2; ++m)
#pragma unroll
    for (int q = 0; q < 4; ++q) {
      float s = 0.f, d = 0.f;
#pragma unroll
      for (int n = 0; n < 4; ++n) {
        s = fmaf(acc[m][n][q], asv[n], s);
        d = fmaf(acc[m][n][q], adv[n], d);
      }
      ps[m][q] = s; pd[m][q] = d;
    }
#pragma unroll
  for (int o = 1; o < 16; o <<= 1) {
#pragma unroll
    for (int m = 0; m < 2; ++m)
#pragma unroll
      for (int q = 0; q < 4; ++q) {
        ps[m][q] += __shfl_xor(ps[m][q], o);
        pd[m][q] += __shfl_xor(pd[m][q], o);
      }
  }
  __syncthreads();
  if (wc == 1 && lr == 0) {
#pragma unroll
    for (int m = 0; m < 2; ++m)
#pragma unroll
      for (int q = 0; q < 4; ++q) {
        int rl = wr * 32 + m * 16 + (l >> 4) * 4 + q;
        sred[0][rl] = ps[m][q];
        sred[1][rl] = pd[m][q];
      }
  }
  __syncthreads();
  if (wc == 0 && lr == 0) {
#pragma unroll
    for (int m = 0; m < 2; ++m)
#pragma unroll
      for (int q = 0; q < 4; ++q) {
        int rl = wr * 32 + m * 16 + (l >> 4) * 4 + q;
        int row = row0 + rl;
        if (row < M) {
          So[(size_t)row * SST + blockIdx.y] = ps[m][q] + sred[0][rl];
          Do[(size_t)row * SST + blockIdx.y] = pd[m][q] + sred[1][rl];
        }
      }
  }
}

// ---------------- CSR build over 2N virtual nodes (both branches) ----------------
__global__ void deg_kernel(const int* __restrict__ ed1, const int* __restrict__ ed2,
                           int E, int Etot, int N, int* __restrict__ deg) {
  int idx = blockIdx.x * blockDim.x + threadIdx.x;
  if (idx >= 2 * Etot) return;
  int br = idx >= Etot;
  int el = idx - br * Etot;
  const int* ed = br ? ed2 : ed1;
  int dn = ((el < E) ? ed[el] : (el - E)) + br * N;
  atomicAdd(&deg[dn], 1);
}

// scan: thread-serial 20 elements + one block scan (n <= 20480)
__global__ __launch_bounds__(1024) void scan_kernel(const int* __restrict__ deg,
                                                    int* __restrict__ rowptr,
                                                    int* __restrict__ cursor, int n) {
  __shared__ int wsum[16];
  int t = threadIdx.x, lane = t & 63, wid = t >> 6;
  int start = t * 20;
  int v[20];
  int s = 0;
#pragma unroll
  for (int k = 0; k < 20; ++k) {
    int i = start + k;
    int d = (i < n) ? deg[i] : 0;
    s += d;
    v[k] = s;                    // inclusive local prefix
  }
  int x = s;
#pragma unroll
  for (int o = 1; o < 64; o <<= 1) {
    int tm = __shfl_up(x, o);
    if (lane >= o) x += tm;
  }
  if (lane == 63) wsum[wid] = x;
  __syncthreads();
  if (wid == 0) {
    int wv = (lane < 16) ? wsum[lane] : 0;
#pragma unroll
    for (int o = 1; o < 16; o <<= 1) {
      int tm = __shfl_up(wv, o);
      if (lane >= o) wv += tm;
    }
    if (lane < 16) wsum[lane] = wv;
  }
  __syncthreads();
  int excl = (x - s) + (wid ? wsum[wid - 1] : 0);
  if (t == 0) rowptr[0] = 0;
#pragma unroll
  for (int k = 0; k < 20; ++k) {
    int i = start + k;
    if (i < n) {
      rowptr[i + 1] = excl + v[k];
      cursor[i] = excl + (k ? v[k - 1] : 0);
    }
  }
}

// fill: minimal scatter — only csr_src (4 B/edge)
__global__ void fill_kernel(const int* __restrict__ es1, const int* __restrict__ ed1,
                            const int* __restrict__ es2, const int* __restrict__ ed2,
                            int E, int Etot, int N, int* __restrict__ cursor,
                            int* __restrict__ csr_src) {
  int idx = blockIdx.x * blockDim.x + threadIdx.x;
  if (idx >= 2 * Etot) return;
  int br = idx >= Etot;
  int el = idx - br * Etot;
  const int* es = br ? es2 : es1;
  const int* ed = br ? ed2 : ed1;
  int sn, dn;
  if (el < E) { sn = es[el]; dn = ed[el]; } else { sn = dn = el - E; }
  sn += br * N; dn += br * N;
  int pos = atomicAdd(&cursor[dn], 1);
  csr_src[pos] = sn;
}

// ---------------- agg1: ONE WAVE PER NODE, zero barriers --------------------------------
// lane l owns cols {4l..4l+3} (dword fp8) and {256+2l, 257+2l} (ushort fp8).
// chunk<=64 edges staged by lanes into packed {src, a0, a1, a2}; gather row is wave-uniform
// so global loads are a coalesced 256B+128B sweep per edge.
__global__ __launch_bounds__(256) void agg1_kernel(const unsigned char* __restrict__ h1c,
                                                   const float* __restrict__ S4,
                                                   const float* __restrict__ D4,
                                                   const int* __restrict__ rowptr,
                                                   const int* __restrict__ csr_src,
                                                   const float* __restrict__ b1,
                                                   __hip_bfloat16* __restrict__ e1b,
                                                   float* __restrict__ invden, int N2) {
  __shared__ float4 st[4][64];
  int wv = threadIdx.x >> 6;
  int n = blockIdx.x * 4 + wv;
  if (n >= N2) return;
  int l = threadIdx.x & 63;
  int head = l >> 5;                       // head of dword cols (0 or 1)
  const float4* S4v = reinterpret_cast<const float4*>(S4);
  int p0 = rowptr[n], p1 = rowptr[n + 1];
  float d0 = D4[n * 4], d1 = D4[n * 4 + 1], d2 = D4[n * 4 + 2];

  float dp0 = 0.f, dp1 = 0.f, dp2 = 0.f;
  float acc[6] = {0.f, 0.f, 0.f, 0.f, 0.f, 0.f};
  for (int base = p0; base < p1; base += 64) {
    int cnt = min(64, p1 - base);
    if (l < cnt) {
      int sn = csr_src[base + l];
      float4 sv = S4v[sn];
      float e0 = __expf(lrelu(sv.x + d0));
      float e1 = __expf(lrelu(sv.y + d1));
      float e2 = __expf(lrelu(sv.z + d2));
      st[wv][l] = make_float4(__int_as_float(sn), e0, e1, e2);
      dp0 += e0; dp1 += e1; dp2 += e2;
    }
    // same-wave DS ordering: staged entries visible to the gather loop below
    int i = 0;
    for (; i + 4 <= cnt; i += 4) {
      float4 w[4];
      unsigned int hv[4];
      unsigned short gv[4];
#pragma unroll
      for (int u = 0; u < 4; ++u) {
        w[u] = st[wv][i + u];
        int sn = __float_as_int(w[u].x);
        const unsigned char* row = h1c + (size_t)sn * 384;
        hv[u] = *reinterpret_cast<const unsigned int*>(row + 4 * l);
        gv[u] = *reinterpret_cast<const unsigned short*>(row + 256 + 2 * l);
      }
#pragma unroll
      for (int u = 0; u < 4; ++u) {
        float alo = head ? w[u].z : w[u].y;
        float ahi = w[u].w;
        f32x2 f0 = __builtin_amdgcn_cvt_pk_f32_fp8((int)hv[u], false);
        f32x2 f1 = __builtin_amdgcn_cvt_pk_f32_fp8((int)hv[u], true);
        f32x2 g0 = __builtin_amdgcn_cvt_pk_f32_fp8((int)(unsigned int)gv[u], false);
        acc[0] = fmaf(alo, f0.x, acc[0]);
        acc[1] = fmaf(alo, f0.y, acc[1]);
        acc[2] = fmaf(alo, f1.x, acc[2]);
        acc[3] = fmaf(alo, f1.y, acc[3]);
        acc[4] = fmaf(ahi, g0.x, acc[4]);
        acc[5] = fmaf(ahi, g0.y, acc[5]);
      }
    }
    for (; i < cnt; ++i) {
      float4 w = st[wv][i];
      int sn = __float_as_int(w.x);
      const unsigned char* row = h1c + (size_t)sn * 384;
      unsigned int hv = *reinterpret_cast<const unsigned int*>(row + 4 * l);
      unsigned short gv = *reinterpret_cast<const unsigned short*>(row + 256 + 2 * l);
      float alo = head ? w.z : w.y;
      float ahi = w.w;
      f32x2 f0 = __builtin_amdgcn_cvt_pk_f32_fp8((int)hv, false);
      f32x2 f1 = __builtin_amdgcn_cvt_pk_f32_fp8((int)hv, true);
      f32x2 g0 = __builtin_amdgcn_cvt_pk_f32_fp8((int)(unsigned int)gv, false);
      acc[0] = fmaf(alo, f0.x, acc[0]);
      acc[1] = fmaf(alo, f0.y, acc[1]);
      acc[2] = fmaf(alo, f1.x, acc[2]);
      acc[3] = fmaf(alo, f1.y, acc[3]);
      acc[4] = fmaf(ahi, g0.x, acc[4]);
      acc[5] = fmaf(ahi, g0.y, acc[5]);
    }
  }
  // wave reduce denominators + broadcast
#pragma unroll
  for (int o = 32; o; o >>= 1) {
    dp0 += __shfl_down(dp0, o); dp1 += __shfl_down(dp1, o); dp2 += __shfl_down(dp2, o);
  }
  float inv0 = 1.f / __shfl(dp0, 0);
  float inv1 = 1.f / __shfl(dp1, 0);
  float inv2 = 1.f / __shfl(dp2, 0);

  float ilo = head ? inv1 : inv0;
  int c0 = 4 * l;
  float4 bb = *reinterpret_cast<const float4*>(b1 + c0);
  float v0 = acc[0] * ilo + bb.x;
  float v1 = acc[1] * ilo + bb.y;
  float v2 = acc[2] * ilo + bb.z;
  float v3 = acc[3] * ilo + bb.w;
  v0 = v0 > 0.f ? v0 : 0.f; v1 = v1 > 0.f ? v1 : 0.f;
  v2 = v2 > 0.f ? v2 : 0.f; v3 = v3 > 0.f ? v3 : 0.f;
  int ch = 256 + 2 * l;
  float2 bh = *reinterpret_cast<const float2*>(b1 + ch);
  float v4 = acc[4] * inv2 + bh.x;
  float v5 = acc[5] * inv2 + bh.y;
  v4 = v4 > 0.f ? v4 : 0.f; v5 = v5 > 0.f ? v5 : 0.f;
  unsigned short* eb = reinterpret_cast<unsigned short*>(e1b) + (size_t)n * 384;
  uint2 lo;
  lo.x = (unsigned int)f2bf(v0) | ((unsigned int)f2bf(v1) << 16);
  lo.y = (unsigned int)f2bf(v2) | ((unsigned int)f2bf(v3) << 16);
  *reinterpret_cast<uint2*>(eb + c0) = lo;
  *reinterpret_cast<unsigned int*>(eb + ch) =
      (unsigned int)f2bf(v4) | ((unsigned int)f2bf(v5) << 16);
  if (l == 0) invden[n * 3] = inv0;
  else if (l == 1) invden[n * 3 + 1] = inv1;
  else if (l == 2) invden[n * 3 + 2] = inv2;
}

// ---------------- alpha: edge-major, coalesced reads + writes; small gathers --------------
__global__ void alpha_kernel(const float* __restrict__ S4, const float* __restrict__ D4,
                             const float* __restrict__ invden,
                             const int* __restrict__ es1, const int* __restrict__ ed1,
                             const int* __restrict__ es2, const int* __restrict__ ed2,
                             int E, int Etot, int N, float* __restrict__ out) {
  int idx = blockIdx.x * blockDim.x + threadIdx.x;
  if (idx >= 2 * Etot) return;
  int br = idx >= Etot;
  int el = idx - br * Etot;
  const int* es = br ? es2 : es1;
  const int* ed = br ? ed2 : ed1;
  int sn, dn;
  if (el < E) { sn = es[el]; dn = ed[el]; } else { sn = dn = el - E; }
  sn += br * N; dn += br * N;
  float* ao = out + 1 + (size_t)br * Etot * 3 + (size_t)el * 3;
#pragma unroll
  for (int h = 0; h < 3; ++h) {
    float v = lrelu(S4[sn * 4 + h] + D4[dn * 4 + h]);
    ao[h] = __expf(v) * invden[dn * 3 + h];
  }
}

// ---------------- agg2: 4 nodes per block (1 wave each), wave-private staging -------------
__global__ __launch_bounds__(256) void agg2_kernel(const unsigned char* __restrict__ h2c,
                                                   const float* __restrict__ S2,
                                                   const float* __restrict__ D2,
                                                   const int* __restrict__ rowptr,
                                                   const int* __restrict__ csr_src,
                                                   const float* __restrict__ b2,
                                                   float* __restrict__ e2out, int N2) {
  __shared__ int lsrc[4][256];
  __shared__ float la[4][256];
  const unsigned int* H4 = reinterpret_cast<const unsigned int*>(h2c);
  int wv = threadIdx.x >> 6;
  int n = blockIdx.x * 4 + wv;
  if (n >= N2) return;
  int lane = threadIdx.x & 63;
  int half = lane >> 5, t = lane & 31;   // cols 4t..4t+3
  int p0 = rowptr[n], p1 = rowptr[n + 1];
  float dnv = D2[n];

  float dpart = 0.f;
  float acc[4] = {0.f, 0.f, 0.f, 0.f};
  for (int base = p0; base < p1; base += 256) {
    int cnt = min(256, p1 - base);
    for (int i = lane; i < cnt; i += 64) {
      int sn = csr_src[base + i];
      lsrc[wv][i] = sn;
      float ex = __expf(lrelu(S2[sn] + dnv));
      la[wv][i] = ex;
      dpart += ex;
    }
    // wave-private LDS: same-wave ordering
    int i = half;
    for (; i + 14 < cnt; i += 16) {
      unsigned int hv[8];
      float av[8];
#pragma unroll
      for (int u = 0; u < 8; ++u) {
        int e = i + 2 * u;
        int sn = lsrc[wv][e];
        av[u] = la[wv][e];
        hv[u] = H4[(size_t)sn * 32 + t];
      }
#pragma unroll
      for (int u = 0; u < 8; ++u) {
        f32x2 f0 = __builtin_amdgcn_cvt_pk_f32_fp8((int)hv[u], false);
        f32x2 f1 = __builtin_amdgcn_cvt_pk_f32_fp8((int)hv[u], true);
        acc[0] = fmaf(av[u], f0.x, acc[0]);
        acc[1] = fmaf(av[u], f0.y, acc[1]);
        acc[2] = fmaf(av[u], f1.x, acc[2]);
        acc[3] = fmaf(av[u], f1.y, acc[3]);
      }
    }
    for (; i < cnt; i += 2) {
      int sn = lsrc[wv][i];
      float a = la[wv][i];
      unsigned int hv = H4[(size_t)sn * 32 + t];
      f32x2 f0 = __builtin_amdgcn_cvt_pk_f32_fp8((int)hv, false);
      f32x2 f1 = __builtin_amdgcn_cvt_pk_f32_fp8((int)hv, true);
      acc[0] = fmaf(a, f0.x, acc[0]);
      acc[1] = fmaf(a, f0.y, acc[1]);
      acc[2] = fmaf(a, f1.x, acc[2]);
      acc[3] = fmaf(a, f1.y, acc[3]);
    }
  }
#pragma unroll
  for (int k = 0; k < 4; ++k) acc[k] += __shfl_xor(acc[k], 32);
#pragma unroll
  for (int o = 32; o; o >>= 1) dpart += __shfl_down(dpart, o);
  float invden = 1.f / __shfl(dpart, 0);
  if (half == 0) {
    float4 bb = *reinterpret_cast<const float4*>(b2 + 4 * t);
    float4 ov;
    ov.x = acc[0] * invden + bb.x;
    ov.y = acc[1] * invden + bb.y;
    ov.z = acc[2] * invden + bb.z;
    ov.w = acc[3] * invden + bb.w;
    *reinterpret_cast<float4*>(e2out + (size_t)n * 128 + 4 * t) = ov;
  }
}

// ---------------- pooling: g[br] = column mean of e2 ----------------
__global__ __launch_bounds__(128) void pool_kernel(const float* __restrict__ e2,
                                                   float* __restrict__ g, int N, float invN) {
  int c = threadIdx.x;
  int br = blockIdx.y;
  int r0 = br * N + blockIdx.x * 128;
  int r1 = min(r0 + 128, br * N + N);
  float acc = 0.f;
  for (int n = r0; n < r1; ++n) acc += e2[(size_t)n * 128 + c];
  atomicAdd(&g[br * 128 + c], acc * invN);
}

// cos([m;m],[m';m']) == cos(m,m') — reduce 128 dims
__global__ __launch_bounds__(128) void sim_kernel(const float* __restrict__ g1,
                                                  const float* __restrict__ g2,
                                                  float* __restrict__ out) {
  int t = threadIdx.x;
  float a = g1[t], b = g2[t];
  __shared__ float sd[128], s1[128], s2[128];
  sd[t] = a * b; s1[t] = a * a; s2[t] = b * b;
  __syncthreads();
  for (int ofs = 64; ofs; ofs >>= 1) {
    if (t < ofs) { sd[t] += sd[t + ofs]; s1[t] += s1[t + ofs]; s2[t] += s2[t + ofs]; }
    __syncthreads();
  }
  if (t == 0) {
    float n1 = fmaxf(sqrtf(s1[0]), 1e-8f);
    float n2 = fmaxf(sqrtf(s2[0]), 1e-8f);
    out[0] = sd[0] / (n1 * n2);
  }
}

// ---------------- host ----------------
extern "C" void kernel_launch(void* const* d_in, const int* in_sizes, int n_in,
                              void* d_out, int out_size, void* d_ws, size_t ws_size,
                              hipStream_t stream) {
  const int N = in_sizes[0] / INDIM;
  const int E = in_sizes[1] / 2;
  const int Etot = E + N;
  const int N2 = 2 * N;

  const float* x1  = (const float*)d_in[0];
  const int*   ei1 = (const int*)d_in[1];
  const float* x2  = (const float*)d_in[2];
  const int*   ei2 = (const int*)d_in[3];
  const float* W1  = (const float*)d_in[4];
  const float* as1 = (const float*)d_in[5];
  const float* ad1 = (const float*)d_in[6];
  const float* b1  = (const float*)d_in[7];
  const float* W2  = (const float*)d_in[8];
  const float* as2 = (const float*)d_in[9];
  const float* ad2 = (const float*)d_in[10];
  const float* b2  = (const float*)d_in[11];
  float* out = (float*)d_out;
  const int* es1 = ei1, *ed1 = ei1 + E;
  const int* es2 = ei2, *ed2 = ei2 + E;

  char* p = (char*)d_ws;
  auto alloc = [&](size_t bytes) -> char* {
    char* q = p;
    p += (bytes + 255) & ~(size_t)255;
    return q;
  };
  unsigned char* h1c = (unsigned char*)alloc((size_t)N2 * 384);
  __hip_bfloat16* e1b = (__hip_bfloat16*)alloc((size_t)N2 * 384 * 2);
  unsigned char* h2c = (unsigned char*)alloc((size_t)N2 * 128);
  float* e2          = (float*)alloc((size_t)N2 * 128 * 4);
  __hip_bfloat16* W1t = (__hip_bfloat16*)alloc((size_t)256 * 384 * 2);
  __hip_bfloat16* W2t = (__hip_bfloat16*)alloc((size_t)384 * 128 * 2);
  float* s1v  = (float*)alloc((size_t)N2 * 4 * 4);   // stride-4 padded
  float* d1v  = (float*)alloc((size_t)N2 * 4 * 4);   // stride-4 padded
  float* s2v  = (float*)alloc((size_t)N2 * 4);
  float* d2v  = (float*)alloc((size_t)N2 * 4);
  float* idn  = (float*)alloc((size_t)N2 * 3 * 4);
  float* g    = (float*)alloc(256 * 4);
  int* deg     = (int*)alloc((size_t)N2 * 4);
  int* rowptr  = (int*)alloc((size_t)(N2 + 1) * 4);
  int* cursor  = (int*)alloc((size_t)N2 * 4);
  int* csr_src = (int*)alloc((size_t)2 * Etot * 4);

  const int EB = 256;
  const int egrid2 = (2 * Etot + EB - 1) / EB;
  const int gmx = (N2 + 63) / 64;

  hipMemsetAsync(g, 0, 256 * 4, stream);
  hipMemsetAsync(deg, 0, (size_t)N2 * 4, stream);
  wprep_kernel<<<(256 * 384 + 384 * 128 + 255) / 256, 256, 0, stream>>>(W1, W1t, W2, W2t);

  deg_kernel<<<egrid2, EB, 0, stream>>>(ed1, ed2, E, Etot, N, deg);
  mfma_gemm<256, false, 3><<<dim3(gmx, 3), 256, 0, stream>>>(x1, x2, N, W1t, as1, ad1,
                                                             h1c, s1v, d1v, N2, 384);
  scan_kernel<<<1, 1024, 0, stream>>>(deg, rowptr, cursor, N2);
  fill_kernel<<<egrid2, EB, 0, stream>>>(es1, ed1, es2, ed2, E, Etot, N, cursor, csr_src);

  agg1_kernel<<<(N2 + 3) / 4, 256, 0, stream>>>(h1c, s1v, d1v, rowptr, csr_src, b1,
                                                e1b, idn, N2);

  mfma_gemm<384, true, 1><<<dim3(gmx, 1), 256, 0, stream>>>(e1b, e1b, N2, W2t, as2, ad2,
                                                            h2c, s2v, d2v, N2, 128);
  alpha_kernel<<<egrid2, EB, 0, stream>>>(s1v, d1v, idn, es1, ed1, es2, ed2, E, Etot, N, out);
  agg2_kernel<<<(N2 + 3) / 4, 256, 0, stream>>>(h2c, s2v, d2v, rowptr, csr_src, b2, e2, N2);

  pool_kernel<<<dim3((N + 127) / 128, 2), 128, 0, stream>>>(e2, g, N, 1.f / (float)N);
  sim_kernel<<<1, 128, 0, stream>>>(g, g + 128, out);
}

// Round 14
// 220.755 us; speedup vs baseline: 1.9687x; 1.0623x over previous
//
#include <hip/hip_runtime.h>
#include <hip/hip_bf16.h>
#include <cstdint>
#include <cstddef>

#define INDIM 256
#define NEG 0.2f

typedef __attribute__((ext_vector_type(8))) short short8v;
typedef __attribute__((ext_vector_type(4))) float f32x4;
typedef __attribute__((ext_vector_type(2))) float f32x2;

__device__ __forceinline__ unsigned short f2bf(float x) {
  __hip_bfloat16 b = __float2bfloat16(x);
  return __builtin_bit_cast(unsigned short, b);
}

// native gfx950 fp8 (OCP E4M3) converts — single VALU instruction each
__device__ __forceinline__ unsigned char f2fp8(float v) {
  int packed = __builtin_amdgcn_cvt_pk_fp8_f32(v, v, 0, false);
  return (unsigned char)(packed & 0xff);
}

__device__ __forceinline__ float lrelu(float v) { return v > 0.f ? v : NEG * v; }

// ---------------- W pre-transpose to bf16 (both weights, one dispatch) --------------------
__global__ void wprep_kernel(const float* __restrict__ W1, __hip_bfloat16* __restrict__ W1t,
                             const float* __restrict__ W2, __hip_bfloat16* __restrict__ W2t) {
  int idx = blockIdx.x * blockDim.x + threadIdx.x;
  const int T1 = 256 * 384;
  if (idx < T1) {
    int k = idx / 384, c = idx - k * 384;
    W1t[(size_t)c * 256 + k] = __float2bfloat16(W1[idx]);
  } else {
    int i = idx - T1;
    if (i < 384 * 128) {
      int k = i / 128, c = i - k * 128;
      W2t[(size_t)c * 384 + k] = __float2bfloat16(W2[i]);
    }
  }
}

// ---------------- GEMM body (device fn): tile 64x128, 4 waves, fused attention dots ------
template<int K, bool ABF16, int SST>
__device__ __forceinline__ void gemm_body(int bx, int by,
                                          const void* __restrict__ A0,
                                          const void* __restrict__ A1, int Nsplit,
                                          const __hip_bfloat16* __restrict__ Wt,
                                          const float* __restrict__ att_s,
                                          const float* __restrict__ att_d,
                                          unsigned char* __restrict__ Yc,
                                          float* __restrict__ So,
                                          float* __restrict__ Do,
                                          int M, int NC,
                                          short (*As)[40], short (*Bs)[40],
                                          float (*sred)[64]) {
  const int tid = threadIdx.x;
  const int row0 = bx * 64;
  const int col0 = by * 128;
  const int l = tid & 63, w = tid >> 6;
  const int wr = w >> 1, wc = w & 1;
  const int lr = l & 15, lk = (l >> 4) * 8;

  f32x4 acc[2][4];
#pragma unroll
  for (int m = 0; m < 2; ++m)
#pragma unroll
    for (int n = 0; n < 4; ++n) acc[m][n] = {0.f, 0.f, 0.f, 0.f};

  for (int k0 = 0; k0 < K; k0 += 32) {
    __syncthreads();
    {  // stage A: 64 rows x 32 k
      int r = tid >> 2, kq = (tid & 3) * 8;
      int gr = row0 + r;
      short8v av = {0, 0, 0, 0, 0, 0, 0, 0};
      if (gr < M) {
        const void* Ab = (gr < Nsplit) ? A0 : A1;
        int lrow = (gr < Nsplit) ? gr : gr - Nsplit;
        if (ABF16) {
          av = *(const short8v*)((const short*)Ab + (size_t)lrow * K + k0 + kq);
        } else {
          const float* ap = (const float*)Ab + (size_t)lrow * K + k0 + kq;
          float4 u = *(const float4*)ap;
          float4 v = *(const float4*)(ap + 4);
          av = short8v{(short)f2bf(u.x), (short)f2bf(u.y), (short)f2bf(u.z), (short)f2bf(u.w),
                       (short)f2bf(v.x), (short)f2bf(v.y), (short)f2bf(v.z), (short)f2bf(v.w)};
        }
      }
      *(short8v*)&As[r][kq] = av;
    }
    {  // stage B: 128 cols x 32 k (Wt row-major [NC][K])
      int c = tid >> 1, kq = (tid & 1) * 8;
      const short* wp = (const short*)Wt + (size_t)(col0 + c) * K + k0 + kq;
      *(short8v*)&Bs[c][kq]      = *(const short8v*)wp;
      *(short8v*)&Bs[c][kq + 16] = *(const short8v*)(wp + 16);
    }
    __syncthreads();
    short8v a[2], b[4];
#pragma unroll
    for (int m = 0; m < 2; ++m) a[m] = *(short8v*)&As[wr * 32 + m * 16 + lr][lk];
#pragma unroll
    for (int n = 0; n < 4; ++n) b[n] = *(short8v*)&Bs[wc * 64 + n * 16 + lr][lk];
#pragma unroll
    for (int m = 0; m < 2; ++m)
#pragma unroll
      for (int n = 0; n < 4; ++n)
        acc[m][n] = __builtin_amdgcn_mfma_f32_16x16x32_bf16(a[m], b[n], acc[m][n], 0, 0, 0);
  }
  // epilogue: C/D layout col=lane&15, row=(lane>>4)*4+q — fp8 store
#pragma unroll
  for (int m = 0; m < 2; ++m) {
    int rbase = row0 + wr * 32 + m * 16 + (l >> 4) * 4;
#pragma unroll
    for (int n = 0; n < 4; ++n) {
      int col = col0 + wc * 64 + n * 16 + lr;
#pragma unroll
      for (int q = 0; q < 4; ++q) {
        int row = rbase + q;
        if (row < M) Yc[(size_t)row * NC + col] = f2fp8(acc[m][n][q]);
      }
    }
  }
  // fused attention dots
  float asv[4], adv[4];
#pragma unroll
  for (int n = 0; n < 4; ++n) {
    int col = col0 + wc * 64 + n * 16 + lr;
    asv[n] = att_s[col];
    adv[n] = att_d[col];
  }
  float ps[2][4], pd[2][4];
#pragma unroll
  for (int m = 0; m < 2; ++m)
#pragma unroll
    for (int q = 0; q < 4; ++q) {
      float s = 0.f, d = 0.f;
#pragma unroll
      for (int n = 0; n < 4; ++n) {
        s = fmaf(acc[m][n][q], asv[n], s);
        d = fmaf(acc[m][n][q], adv[n], d);
      }
      ps[m][q] = s; pd[m][q] = d;
    }
#pragma unroll
  for (int o = 1; o < 16; o <<= 1) {
#pragma unroll
    for (int m = 0; m < 2; ++m)
#pragma unroll
      for (int q = 0; q < 4; ++q) {
        ps[m][q] += __shfl_xor(ps[m][q], o);
        pd[m][q] += __shfl_xor(pd[m][q], o);
      }
  }
  __syncthreads();
  if (wc == 1 && lr == 0) {
#pragma unroll
    for (int m = 0; m < 2; ++m)
#pragma unroll
      for (int q = 0; q < 4; ++q) {
        int rl = wr * 32 + m * 16 + (l >> 4) * 4 + q;
        sred[0][rl] = ps[m][q];
        sred[1][rl] = pd[m][q];
      }
  }
  __syncthreads();
  if (wc == 0 && lr == 0) {
#pragma unroll
    for (int m = 0; m < 2; ++m)
#pragma unroll
      for (int q = 0; q < 4; ++q) {
        int rl = wr * 32 + m * 16 + (l >> 4) * 4 + q;
        int row = row0 + rl;
        if (row < M) {
          So[(size_t)row * SST + by] = ps[m][q] + sred[0][rl];
          Do[(size_t)row * SST + by] = pd[m][q] + sred[1][rl];
        }
      }
  }
}

// ---------------- gemm1 + deg merged: blocks < gmx*3 do GEMM, rest do deg atomics ---------
__global__ __launch_bounds__(256) void gemm1_deg_kernel(const float* __restrict__ x1,
                                                        const float* __restrict__ x2, int Nsplit,
                                                        const __hip_bfloat16* __restrict__ Wt,
                                                        const float* __restrict__ att_s,
                                                        const float* __restrict__ att_d,
                                                        unsigned char* __restrict__ Yc,
                                                        float* __restrict__ So,
                                                        float* __restrict__ Do,
                                                        int M, int gmx,
                                                        const int* __restrict__ ed1,
                                                        const int* __restrict__ ed2,
                                                        int E, int Etot, int N,
                                                        int* __restrict__ deg) {
  __shared__ short As[64][40];
  __shared__ short Bs[128][40];
  __shared__ float sred[2][64];
  int bid = blockIdx.x;
  if (bid < gmx * 3) {
    gemm_body<256, false, 4>(bid % gmx, bid / gmx, x1, x2, Nsplit, Wt, att_s, att_d,
                             Yc, So, Do, M, 384, As, Bs, sred);
  } else {
    int idx = (bid - gmx * 3) * 256 + threadIdx.x;
    if (idx < 2 * Etot) {
      int br = idx >= Etot;
      int el = idx - br * Etot;
      const int* ed = br ? ed2 : ed1;
      int dn = ((el < E) ? ed[el] : (el - E)) + br * N;
      atomicAdd(&deg[dn], 1);
    }
  }
}

// ---------------- gemm2 + alpha merged: blocks < gmx do GEMM, rest write alpha ------------
__global__ __launch_bounds__(256) void gemm2_alpha_kernel(const __hip_bfloat16* __restrict__ e1b,
                                                          const __hip_bfloat16* __restrict__ Wt,
                                                          const float* __restrict__ att_s,
                                                          const float* __restrict__ att_d,
                                                          unsigned char* __restrict__ Yc,
                                                          float* __restrict__ So,
                                                          float* __restrict__ Do,
                                                          int M, int gmx,
                                                          const float* __restrict__ S4,
                                                          const float* __restrict__ D4,
                                                          const float* __restrict__ invden,
                                                          const int* __restrict__ es1,
                                                          const int* __restrict__ ed1,
                                                          const int* __restrict__ es2,
                                                          const int* __restrict__ ed2,
                                                          int E, int Etot, int N,
                                                          float* __restrict__ out) {
  __shared__ short As[64][40];
  __shared__ short Bs[128][40];
  __shared__ float sred[2][64];
  int bid = blockIdx.x;
  if (bid < gmx) {
    gemm_body<384, true, 1>(bid, 0, e1b, e1b, M, Wt, att_s, att_d,
                            Yc, So, Do, M, 128, As, Bs, sred);
  } else {
    int idx = (bid - gmx) * 256 + threadIdx.x;
    if (idx < 2 * Etot) {
      int br = idx >= Etot;
      int el = idx - br * Etot;
      const int* es = br ? es2 : es1;
      const int* ed = br ? ed2 : ed1;
      int sn, dn;
      if (el < E) { sn = es[el]; dn = ed[el]; } else { sn = dn = el - E; }
      sn += br * N; dn += br * N;
      float* ao = out + 1 + (size_t)br * Etot * 3 + (size_t)el * 3;
#pragma unroll
      for (int h = 0; h < 3; ++h) {
        float v = lrelu(S4[sn * 4 + h] + D4[dn * 4 + h]);
        ao[h] = __expf(v) * invden[dn * 3 + h];
      }
    }
  }
}

// scan: thread-serial 20 elements + one block scan (n <= 20480)
__global__ __launch_bounds__(1024) void scan_kernel(const int* __restrict__ deg,
                                                    int* __restrict__ rowptr,
                                                    int* __restrict__ cursor, int n) {
  __shared__ int wsum[16];
  int t = threadIdx.x, lane = t & 63, wid = t >> 6;
  int start = t * 20;
  int v[20];
  int s = 0;
#pragma unroll
  for (int k = 0; k < 20; ++k) {
    int i = start + k;
    int d = (i < n) ? deg[i] : 0;
    s += d;
    v[k] = s;                    // inclusive local prefix
  }
  int x = s;
#pragma unroll
  for (int o = 1; o < 64; o <<= 1) {
    int tm = __shfl_up(x, o);
    if (lane >= o) x += tm;
  }
  if (lane == 63) wsum[wid] = x;
  __syncthreads();
  if (wid == 0) {
    int wv = (lane < 16) ? wsum[lane] : 0;
#pragma unroll
    for (int o = 1; o < 16; o <<= 1) {
      int tm = __shfl_up(wv, o);
      if (lane >= o) wv += tm;
    }
    if (lane < 16) wsum[lane] = wv;
  }
  __syncthreads();
  int excl = (x - s) + (wid ? wsum[wid - 1] : 0);
  if (t == 0) rowptr[0] = 0;
#pragma unroll
  for (int k = 0; k < 20; ++k) {
    int i = start + k;
    if (i < n) {
      rowptr[i + 1] = excl + v[k];
      cursor[i] = excl + (k ? v[k - 1] : 0);
    }
  }
}

// fill: minimal scatter — only csr_src (4 B/edge)
__global__ void fill_kernel(const int* __restrict__ es1, const int* __restrict__ ed1,
                            const int* __restrict__ es2, const int* __restrict__ ed2,
                            int E, int Etot, int N, int* __restrict__ cursor,
                            int* __restrict__ csr_src) {
  int idx = blockIdx.x * blockDim.x + threadIdx.x;
  if (idx >= 2 * Etot) return;
  int br = idx >= Etot;
  int el = idx - br * Etot;
  const int* es = br ? es2 : es1;
  const int* ed = br ? ed2 : ed1;
  int sn, dn;
  if (el < E) { sn = es[el]; dn = ed[el]; } else { sn = dn = el - E; }
  sn += br * N; dn += br * N;
  int pos = atomicAdd(&cursor[dn], 1);
  csr_src[pos] = sn;
}

// ---------------- agg1: ONE WAVE PER NODE, zero barriers --------------------------------
__global__ __launch_bounds__(256) void agg1_kernel(const unsigned char* __restrict__ h1c,
                                                   const float* __restrict__ S4,
                                                   const float* __restrict__ D4,
                                                   const int* __restrict__ rowptr,
                                                   const int* __restrict__ csr_src,
                                                   const float* __restrict__ b1,
                                                   __hip_bfloat16* __restrict__ e1b,
                                                   float* __restrict__ invden, int N2) {
  __shared__ float4 st[4][64];
  int wv = threadIdx.x >> 6;
  int n = blockIdx.x * 4 + wv;
  if (n >= N2) return;
  int l = threadIdx.x & 63;
  int head = l >> 5;                       // head of dword cols (0 or 1)
  const float4* S4v = reinterpret_cast<const float4*>(S4);
  int p0 = rowptr[n], p1 = rowptr[n + 1];
  float d0 = D4[n * 4], d1 = D4[n * 4 + 1], d2 = D4[n * 4 + 2];

  float dp0 = 0.f, dp1 = 0.f, dp2 = 0.f;
  float acc[6] = {0.f, 0.f, 0.f, 0.f, 0.f, 0.f};
  for (int base = p0; base < p1; base += 64) {
    int cnt = min(64, p1 - base);
    if (l < cnt) {
      int sn = csr_src[base + l];
      float4 sv = S4v[sn];
      float e0 = __expf(lrelu(sv.x + d0));
      float e1 = __expf(lrelu(sv.y + d1));
      float e2 = __expf(lrelu(sv.z + d2));
      st[wv][l] = make_float4(__int_as_float(sn), e0, e1, e2);
      dp0 += e0; dp1 += e1; dp2 += e2;
    }
    int i = 0;
    for (; i + 4 <= cnt; i += 4) {
      float4 w[4];
      unsigned int hv[4];
      unsigned short gv[4];
#pragma unroll
      for (int u = 0; u < 4; ++u) {
        w[u] = st[wv][i + u];
        int sn = __float_as_int(w[u].x);
        const unsigned char* row = h1c + (size_t)sn * 384;
        hv[u] = *reinterpret_cast<const unsigned int*>(row + 4 * l);
        gv[u] = *reinterpret_cast<const unsigned short*>(row + 256 + 2 * l);
      }
#pragma unroll
      for (int u = 0; u < 4; ++u) {
        float alo = head ? w[u].z : w[u].y;
        float ahi = w[u].w;
        f32x2 f0 = __builtin_amdgcn_cvt_pk_f32_fp8((int)hv[u], false);
        f32x2 f1 = __builtin_amdgcn_cvt_pk_f32_fp8((int)hv[u], true);
        f32x2 g0 = __builtin_amdgcn_cvt_pk_f32_fp8((int)(unsigned int)gv[u], false);
        acc[0] = fmaf(alo, f0.x, acc[0]);
        acc[1] = fmaf(alo, f0.y, acc[1]);
        acc[2] = fmaf(alo, f1.x, acc[2]);
        acc[3] = fmaf(alo, f1.y, acc[3]);
        acc[4] = fmaf(ahi, g0.x, acc[4]);
        acc[5] = fmaf(ahi, g0.y, acc[5]);
      }
    }
    for (; i < cnt; ++i) {
      float4 w = st[wv][i];
      int sn = __float_as_int(w.x);
      const unsigned char* row = h1c + (size_t)sn * 384;
      unsigned int hv = *reinterpret_cast<const unsigned int*>(row + 4 * l);
      unsigned short gv = *reinterpret_cast<const unsigned short*>(row + 256 + 2 * l);
      float alo = head ? w.z : w.y;
      float ahi = w.w;
      f32x2 f0 = __builtin_amdgcn_cvt_pk_f32_fp8((int)hv, false);
      f32x2 f1 = __builtin_amdgcn_cvt_pk_f32_fp8((int)hv, true);
      f32x2 g0 = __builtin_amdgcn_cvt_pk_f32_fp8((int)(unsigned int)gv, false);
      acc[0] = fmaf(alo, f0.x, acc[0]);
      acc[1] = fmaf(alo, f0.y, acc[1]);
      acc[2] = fmaf(alo, f1.x, acc[2]);
      acc[3] = fmaf(alo, f1.y, acc[3]);
      acc[4] = fmaf(ahi, g0.x, acc[4]);
      acc[5] = fmaf(ahi, g0.y, acc[5]);
    }
  }
#pragma unroll
  for (int o = 32; o; o >>= 1) {
    dp0 += __shfl_down(dp0, o); dp1 += __shfl_down(dp1, o); dp2 += __shfl_down(dp2, o);
  }
  float inv0 = 1.f / __shfl(dp0, 0);
  float inv1 = 1.f / __shfl(dp1, 0);
  float inv2 = 1.f / __shfl(dp2, 0);

  float ilo = head ? inv1 : inv0;
  int c0 = 4 * l;
  float4 bb = *reinterpret_cast<const float4*>(b1 + c0);
  float v0 = acc[0] * ilo + bb.x;
  float v1 = acc[1] * ilo + bb.y;
  float v2 = acc[2] * ilo + bb.z;
  float v3 = acc[3] * ilo + bb.w;
  v0 = v0 > 0.f ? v0 : 0.f; v1 = v1 > 0.f ? v1 : 0.f;
  v2 = v2 > 0.f ? v2 : 0.f; v3 = v3 > 0.f ? v3 : 0.f;
  int ch = 256 + 2 * l;
  float2 bh = *reinterpret_cast<const float2*>(b1 + ch);
  float v4 = acc[4] * inv2 + bh.x;
  float v5 = acc[5] * inv2 + bh.y;
  v4 = v4 > 0.f ? v4 : 0.f; v5 = v5 > 0.f ? v5 : 0.f;
  unsigned short* eb = reinterpret_cast<unsigned short*>(e1b) + (size_t)n * 384;
  uint2 lo;
  lo.x = (unsigned int)f2bf(v0) | ((unsigned int)f2bf(v1) << 16);
  lo.y = (unsigned int)f2bf(v2) | ((unsigned int)f2bf(v3) << 16);
  *reinterpret_cast<uint2*>(eb + c0) = lo;
  *reinterpret_cast<unsigned int*>(eb + ch) =
      (unsigned int)f2bf(v4) | ((unsigned int)f2bf(v5) << 16);
  if (l == 0) invden[n * 3] = inv0;
  else if (l == 1) invden[n * 3 + 1] = inv1;
  else if (l == 2) invden[n * 3 + 2] = inv2;
}

// ---------------- agg2: 4 nodes per block (1 wave each), wave-private staging -------------
__global__ __launch_bounds__(256) void agg2_kernel(const unsigned char* __restrict__ h2c,
                                                   const float* __restrict__ S2,
                                                   const float* __restrict__ D2,
                                                   const int* __restrict__ rowptr,
                                                   const int* __restrict__ csr_src,
                                                   const float* __restrict__ b2,
                                                   float* __restrict__ e2out, int N2) {
  __shared__ int lsrc[4][256];
  __shared__ float la[4][256];
  const unsigned int* H4 = reinterpret_cast<const unsigned int*>(h2c);
  int wv = threadIdx.x >> 6;
  int n = blockIdx.x * 4 + wv;
  if (n >= N2) return;
  int lane = threadIdx.x & 63;
  int half = lane >> 5, t = lane & 31;   // cols 4t..4t+3
  int p0 = rowptr[n], p1 = rowptr[n + 1];
  float dnv = D2[n];

  float dpart = 0.f;
  float acc[4] = {0.f, 0.f, 0.f, 0.f};
  for (int base = p0; base < p1; base += 256) {
    int cnt = min(256, p1 - base);
    for (int i = lane; i < cnt; i += 64) {
      int sn = csr_src[base + i];
      lsrc[wv][i] = sn;
      float ex = __expf(lrelu(S2[sn] + dnv));
      la[wv][i] = ex;
      dpart += ex;
    }
    int i = half;
    for (; i + 14 < cnt; i += 16) {
      unsigned int hv[8];
      float av[8];
#pragma unroll
      for (int u = 0; u < 8; ++u) {
        int e = i + 2 * u;
        int sn = lsrc[wv][e];
        av[u] = la[wv][e];
        hv[u] = H4[(size_t)sn * 32 + t];
      }
#pragma unroll
      for (int u = 0; u < 8; ++u) {
        f32x2 f0 = __builtin_amdgcn_cvt_pk_f32_fp8((int)hv[u], false);
        f32x2 f1 = __builtin_amdgcn_cvt_pk_f32_fp8((int)hv[u], true);
        acc[0] = fmaf(av[u], f0.x, acc[0]);
        acc[1] = fmaf(av[u], f0.y, acc[1]);
        acc[2] = fmaf(av[u], f1.x, acc[2]);
        acc[3] = fmaf(av[u], f1.y, acc[3]);
      }
    }
    for (; i < cnt; i += 2) {
      int sn = lsrc[wv][i];
      float a = la[wv][i];
      unsigned int hv = H4[(size_t)sn * 32 + t];
      f32x2 f0 = __builtin_amdgcn_cvt_pk_f32_fp8((int)hv, false);
      f32x2 f1 = __builtin_amdgcn_cvt_pk_f32_fp8((int)hv, true);
      acc[0] = fmaf(a, f0.x, acc[0]);
      acc[1] = fmaf(a, f0.y, acc[1]);
      acc[2] = fmaf(a, f1.x, acc[2]);
      acc[3] = fmaf(a, f1.y, acc[3]);
    }
  }
#pragma unroll
  for (int k = 0; k < 4; ++k) acc[k] += __shfl_xor(acc[k], 32);
#pragma unroll
  for (int o = 32; o; o >>= 1) dpart += __shfl_down(dpart, o);
  float invden = 1.f / __shfl(dpart, 0);
  if (half == 0) {
    float4 bb = *reinterpret_cast<const float4*>(b2 + 4 * t);
    float4 ov;
    ov.x = acc[0] * invden + bb.x;
    ov.y = acc[1] * invden + bb.y;
    ov.z = acc[2] * invden + bb.z;
    ov.w = acc[3] * invden + bb.w;
    *reinterpret_cast<float4*>(e2out + (size_t)n * 128 + 4 * t) = ov;
  }
}

// ---------------- pool + sim fused (last-block-done; coherent reads via atomicAdd+0) ------
__global__ __launch_bounds__(128) void pool_sim_kernel(const float* __restrict__ e2,
                                                       float* __restrict__ g,
                                                       int* __restrict__ cnt,
                                                       int N, float invN,
                                                       float* __restrict__ out) {
  int c = threadIdx.x;
  int br = blockIdx.y;
  int r0 = br * N + blockIdx.x * 128;
  int r1 = min(r0 + 128, br * N + N);
  float acc = 0.f;
  for (int n = r0; n < r1; ++n) acc += e2[(size_t)n * 128 + c];
  atomicAdd(&g[br * 128 + c], acc * invN);
  __threadfence();
  __shared__ bool last;
  __shared__ float sd[128], s1[128], s2[128];
  if (c == 0) {
    int total = gridDim.x * gridDim.y;
    last = (atomicAdd(cnt, 1) == total - 1);
  }
  __syncthreads();
  if (!last) return;
  float a = atomicAdd(&g[c], 0.f);         // coherent-point load
  float b = atomicAdd(&g[128 + c], 0.f);
  sd[c] = a * b; s1[c] = a * a; s2[c] = b * b;
  __syncthreads();
  for (int ofs = 64; ofs; ofs >>= 1) {
    if (c < ofs) { sd[c] += sd[c + ofs]; s1[c] += s1[c + ofs]; s2[c] += s2[c + ofs]; }
    __syncthreads();
  }
  if (c == 0) {
    float n1 = fmaxf(sqrtf(s1[0]), 1e-8f);
    float n2 = fmaxf(sqrtf(s2[0]), 1e-8f);
    out[0] = sd[0] / (n1 * n2);
  }
}

// ---------------- host ----------------
extern "C" void kernel_launch(void* const* d_in, const int* in_sizes, int n_in,
                              void* d_out, int out_size, void* d_ws, size_t ws_size,
                              hipStream_t stream) {
  const int N = in_sizes[0] / INDIM;
  const int E = in_sizes[1] / 2;
  const int Etot = E + N;
  const int N2 = 2 * N;

  const float* x1  = (const float*)d_in[0];
  const int*   ei1 = (const int*)d_in[1];
  const float* x2  = (const float*)d_in[2];
  const int*   ei2 = (const int*)d_in[3];
  const float* W1  = (const float*)d_in[4];
  const float* as1 = (const float*)d_in[5];
  const float* ad1 = (const float*)d_in[6];
  const float* b1  = (const float*)d_in[7];
  const float* W2  = (const float*)d_in[8];
  const float* as2 = (const float*)d_in[9];
  const float* ad2 = (const float*)d_in[10];
  const float* b2  = (const float*)d_in[11];
  float* out = (float*)d_out;
  const int* es1 = ei1, *ed1 = ei1 + E;
  const int* es2 = ei2, *ed2 = ei2 + E;

  char* p = (char*)d_ws;
  auto alloc = [&](size_t bytes) -> char* {
    char* q = p;
    p += (bytes + 255) & ~(size_t)255;
    return q;
  };
  // zero region: g (256f) | cnt (pad 256B) | deg (N2 ints) — one memset
  float* g   = (float*)alloc(256 * 4);
  int*   cnt = (int*)alloc(256);
  int*   deg = (int*)alloc((size_t)N2 * 4);
  size_t zero_bytes = (size_t)((char*)deg - (char*)g) + (((size_t)N2 * 4 + 255) & ~(size_t)255);

  unsigned char* h1c = (unsigned char*)alloc((size_t)N2 * 384);
  __hip_bfloat16* e1b = (__hip_bfloat16*)alloc((size_t)N2 * 384 * 2);
  unsigned char* h2c = (unsigned char*)alloc((size_t)N2 * 128);
  float* e2          = (float*)alloc((size_t)N2 * 128 * 4);
  __hip_bfloat16* W1t = (__hip_bfloat16*)alloc((size_t)256 * 384 * 2);
  __hip_bfloat16* W2t = (__hip_bfloat16*)alloc((size_t)384 * 128 * 2);
  float* s1v  = (float*)alloc((size_t)N2 * 4 * 4);   // stride-4 padded
  float* d1v  = (float*)alloc((size_t)N2 * 4 * 4);   // stride-4 padded
  float* s2v  = (float*)alloc((size_t)N2 * 4);
  float* d2v  = (float*)alloc((size_t)N2 * 4);
  float* idn  = (float*)alloc((size_t)N2 * 3 * 4);
  int* rowptr  = (int*)alloc((size_t)(N2 + 1) * 4);
  int* cursor  = (int*)alloc((size_t)N2 * 4);
  int* csr_src = (int*)alloc((size_t)2 * Etot * 4);

  const int EB = 256;
  const int egrid2 = (2 * Etot + EB - 1) / EB;
  const int gmx = (N2 + 63) / 64;

  hipMemsetAsync(g, 0, zero_bytes, stream);
  wprep_kernel<<<(256 * 384 + 384 * 128 + 255) / 256, 256, 0, stream>>>(W1, W1t, W2, W2t);

  gemm1_deg_kernel<<<gmx * 3 + egrid2, 256, 0, stream>>>(x1, x2, N, W1t, as1, ad1,
                                                         h1c, s1v, d1v, N2, gmx,
                                                         ed1, ed2, E, Etot, N, deg);
  scan_kernel<<<1, 1024, 0, stream>>>(deg, rowptr, cursor, N2);
  fill_kernel<<<egrid2, EB, 0, stream>>>(es1, ed1, es2, ed2, E, Etot, N, cursor, csr_src);

  agg1_kernel<<<(N2 + 3) / 4, 256, 0, stream>>>(h1c, s1v, d1v, rowptr, csr_src, b1,
                                                e1b, idn, N2);

  gemm2_alpha_kernel<<<gmx + egrid2, 256, 0, stream>>>(e1b, W2t, as2, ad2,
                                                       h2c, s2v, d2v, N2, gmx,
                                                       s1v, d1v, idn,
                                                       es1, ed1, es2, ed2, E, Etot, N, out);
  agg2_kernel<<<(N2 + 3) / 4, 256, 0, stream>>>(h2c, s2v, d2v, rowptr, csr_src, b2, e2, N2);

  pool_sim_kernel<<<dim3((N + 127) / 128, 2), 128, 0, stream>>>(e2, g, cnt, N,
                                                                1.f / (float)N, out);
}